// Round 2
// baseline (1548.360 us; speedup 1.0000x reference)
//
#include <hip/hip_runtime.h>
#include <hip/hip_bf16.h>

#define N_ 8
#define C_ 64
#define H_ 128
#define W_ 256
#define HW_ (H_*W_)        // 32768
#define CHW_ (C_*H_*W_)    // 2097152

typedef unsigned int u32;
typedef unsigned short u16;

__device__ __forceinline__ float blo(u32 u) { return __uint_as_float(u << 16); }
__device__ __forceinline__ float bhi(u32 u) { return __uint_as_float(u & 0xffff0000u); }
__device__ __forceinline__ u16 f2bf(float f) {
    u32 u = __float_as_uint(f);
    u32 lsb = (u >> 16) & 1u;
    u += 0x7fffu + lsb;
    return (u16)(u >> 16);
}
__device__ __forceinline__ u32 pack2(float a, float b) {
    return (u32)f2bf(a) | ((u32)f2bf(b) << 16);
}

// ---------------------------------------------------------------------------
// K1: LayerNorm + 1x1 conv projections.
// LN folded: Q[o] = rs*(dotA[o] - mu*S[o]) + B[o],  A[o][c]=Wq[o][c]*ln_w[c],
//            S[o]=sum_c A[o][c],  B[o]=sum_c Wq[o][c]*ln_b[c] + bq[o].
// Outputs Q_l, Q_r, V_r bf16 in NHWC-per-scanline layout: [(blk*256+w)*64+o].
// ---------------------------------------------------------------------------
__global__ __launch_bounds__(256) void k_proj(
    const float* __restrict__ xl, const float* __restrict__ xr,
    const float* __restrict__ nlw, const float* __restrict__ nlb,
    const float* __restrict__ nrw, const float* __restrict__ nrb,
    const float* __restrict__ Wql, const float* __restrict__ bql,
    const float* __restrict__ Wqr, const float* __restrict__ bqr,
    const float* __restrict__ Wvr, const float* __restrict__ bvr,
    u32* __restrict__ Ql, u32* __restrict__ Qr, u32* __restrict__ Vr)
{
    __shared__ float Al[4096], Ar[4096], Wv[4096];
    __shared__ float Sl[64], Bl[64], Sr[64], Br[64];
    const int tid = threadIdx.x;
    for (int idx = tid; idx < 4096; idx += 256) {
        int c = idx & 63;
        Al[idx] = Wql[idx] * nlw[c];
        Ar[idx] = Wqr[idx] * nrw[c];
        Wv[idx] = Wvr[idx];
    }
    __syncthreads();
    if (tid < 64) {
        int o = tid;
        float sl = 0.f, bl = bql[o], sr = 0.f, br = bqr[o];
        for (int c = 0; c < 64; ++c) {
            sl += Al[o*64+c];
            bl += Wql[o*64+c] * nlb[c];
            sr += Ar[o*64+c];
            br += Wqr[o*64+c] * nrb[c];
        }
        Sl[o] = sl; Bl[o] = bl; Sr[o] = sr; Br[o] = br;
    }
    __syncthreads();

    const int blk = blockIdx.x;          // scanline = n*128 + h
    const int n = blk >> 7, h = blk & 127;
    const int w = tid;
    const size_t pbase = (size_t)n*CHW_ + (size_t)h*W_ + w;

    float xv[64];
    // ---- left path ----
    float sum = 0.f, ssq = 0.f;
    #pragma unroll
    for (int c = 0; c < 64; ++c) {
        float v = xl[pbase + (size_t)c*HW_];
        xv[c] = v; sum += v; ssq += v*v;
    }
    float mu = sum * (1.f/64.f);
    float var = ssq * (1.f/64.f) - mu*mu;
    float rs = rsqrtf(var + 1e-6f);
    const size_t row32 = ((size_t)blk*256 + w) * 32;   // u32 index of this row
    for (int o = 0; o < 64; o += 2) {
        const float4* a4 = (const float4*)&Al[o*64];
        float d0a=0.f,d0b=0.f,d1a=0.f,d1b=0.f;
        #pragma unroll
        for (int j = 0; j < 16; j += 2) {
            float4 r0 = a4[j],   r1 = a4[j+1];
            float4 s0 = a4[16+j],s1 = a4[16+j+1];
            d0a = fmaf(r0.x,xv[4*j+0],d0a); d0a = fmaf(r0.y,xv[4*j+1],d0a);
            d0a = fmaf(r0.z,xv[4*j+2],d0a); d0a = fmaf(r0.w,xv[4*j+3],d0a);
            d0b = fmaf(r1.x,xv[4*j+4],d0b); d0b = fmaf(r1.y,xv[4*j+5],d0b);
            d0b = fmaf(r1.z,xv[4*j+6],d0b); d0b = fmaf(r1.w,xv[4*j+7],d0b);
            d1a = fmaf(s0.x,xv[4*j+0],d1a); d1a = fmaf(s0.y,xv[4*j+1],d1a);
            d1a = fmaf(s0.z,xv[4*j+2],d1a); d1a = fmaf(s0.w,xv[4*j+3],d1a);
            d1b = fmaf(s1.x,xv[4*j+4],d1b); d1b = fmaf(s1.y,xv[4*j+5],d1b);
            d1b = fmaf(s1.z,xv[4*j+6],d1b); d1b = fmaf(s1.w,xv[4*j+7],d1b);
        }
        float q0 = rs*((d0a+d0b) - mu*Sl[o])   + Bl[o];
        float q1 = rs*((d1a+d1b) - mu*Sl[o+1]) + Bl[o+1];
        Ql[row32 + (o>>1)] = pack2(q0, q1);
    }
    // ---- right path ----
    sum = 0.f; ssq = 0.f;
    #pragma unroll
    for (int c = 0; c < 64; ++c) {
        float v = xr[pbase + (size_t)c*HW_];
        xv[c] = v; sum += v; ssq += v*v;
    }
    mu = sum * (1.f/64.f);
    var = ssq * (1.f/64.f) - mu*mu;
    rs = rsqrtf(var + 1e-6f);
    for (int o = 0; o < 64; o += 2) {
        const float4* a4 = (const float4*)&Ar[o*64];
        const float4* v4 = (const float4*)&Wv[o*64];
        float d0=0.f,d1=0.f,e0=0.f,e1=0.f;
        #pragma unroll
        for (int j = 0; j < 16; ++j) {
            float4 r0 = a4[j], r1 = a4[16+j];
            float4 t0 = v4[j], t1 = v4[16+j];
            float x0 = xv[4*j+0], x1 = xv[4*j+1], x2 = xv[4*j+2], x3 = xv[4*j+3];
            d0 = fmaf(r0.x,x0,d0); d0 = fmaf(r0.y,x1,d0); d0 = fmaf(r0.z,x2,d0); d0 = fmaf(r0.w,x3,d0);
            d1 = fmaf(r1.x,x0,d1); d1 = fmaf(r1.y,x1,d1); d1 = fmaf(r1.z,x2,d1); d1 = fmaf(r1.w,x3,d1);
            e0 = fmaf(t0.x,x0,e0); e0 = fmaf(t0.y,x1,e0); e0 = fmaf(t0.z,x2,e0); e0 = fmaf(t0.w,x3,e0);
            e1 = fmaf(t1.x,x0,e1); e1 = fmaf(t1.y,x1,e1); e1 = fmaf(t1.z,x2,e1); e1 = fmaf(t1.w,x3,e1);
        }
        float q0 = rs*(d0 - mu*Sr[o])   + Br[o];
        float q1 = rs*(d1 - mu*Sr[o+1]) + Br[o+1];
        Qr[row32 + (o>>1)] = pack2(q0, q1);
        Vr[row32 + (o>>1)] = pack2(e0 + bvr[o], e1 + bvr[o+1]);
    }
}

// ---------------------------------------------------------------------------
// K2: per-scanline cross attention.  softmax without max-subtraction (scores
// are bounded ~|s|<2 for these input scales).  Writes out = x_l + beta*F.
// ---------------------------------------------------------------------------
__global__ __launch_bounds__(256) void k_attn(
    const u32* __restrict__ Ql, const u32* __restrict__ Qr, const u32* __restrict__ Vr,
    const float* __restrict__ xl, const float* __restrict__ beta,
    float* __restrict__ out)
{
    __shared__ float QRs[128*64];
    __shared__ float Vs[128*64];
    const int tid = threadIdx.x;
    const int blk = blockIdx.x;
    const int n = blk >> 7, h = blk & 127;

    // load this thread's query row (bf16 -> f32 regs)
    float q[64];
    const uint4* qrow4 = (const uint4*)(Ql + ((size_t)blk*256 + tid)*32);
    #pragma unroll
    for (int j = 0; j < 8; ++j) {
        uint4 u = qrow4[j];
        q[8*j+0] = blo(u.x); q[8*j+1] = bhi(u.x);
        q[8*j+2] = blo(u.y); q[8*j+3] = bhi(u.y);
        q[8*j+4] = blo(u.z); q[8*j+5] = bhi(u.z);
        q[8*j+6] = blo(u.w); q[8*j+7] = bhi(u.w);
    }
    float oacc[64];
    #pragma unroll
    for (int c = 0; c < 64; ++c) oacc[c] = 0.f;
    float l = 0.f;

    for (int tt = 0; tt < 2; ++tt) {
        __syncthreads();
        const uint4* qr4 = (const uint4*)(Qr + ((size_t)blk*256 + tt*128)*32);
        const uint4* vr4 = (const uint4*)(Vr + ((size_t)blk*256 + tt*128)*32);
        for (int j4 = tid; j4 < 1024; j4 += 256) {
            uint4 a = qr4[j4];
            float* d = &QRs[j4*8];
            d[0]=blo(a.x); d[1]=bhi(a.x); d[2]=blo(a.y); d[3]=bhi(a.y);
            d[4]=blo(a.z); d[5]=bhi(a.z); d[6]=blo(a.w); d[7]=bhi(a.w);
            uint4 b = vr4[j4];
            float* e = &Vs[j4*8];
            e[0]=blo(b.x); e[1]=bhi(b.x); e[2]=blo(b.y); e[3]=bhi(b.y);
            e[4]=blo(b.z); e[5]=bhi(b.z); e[6]=blo(b.w); e[7]=bhi(b.w);
        }
        __syncthreads();
        for (int vv = 0; vv < 128; ++vv) {
            const float4* kr4 = (const float4*)&QRs[vv*64];
            float s0=0.f,s1=0.f,s2=0.f,s3=0.f;
            #pragma unroll
            for (int j = 0; j < 16; j += 4) {
                float4 k0 = kr4[j], k1 = kr4[j+1], k2 = kr4[j+2], k3 = kr4[j+3];
                s0 = fmaf(k0.x,q[4*j+0],s0);  s0 = fmaf(k0.y,q[4*j+1],s0);
                s0 = fmaf(k0.z,q[4*j+2],s0);  s0 = fmaf(k0.w,q[4*j+3],s0);
                s1 = fmaf(k1.x,q[4*j+4],s1);  s1 = fmaf(k1.y,q[4*j+5],s1);
                s1 = fmaf(k1.z,q[4*j+6],s1);  s1 = fmaf(k1.w,q[4*j+7],s1);
                s2 = fmaf(k2.x,q[4*j+8],s2);  s2 = fmaf(k2.y,q[4*j+9],s2);
                s2 = fmaf(k2.z,q[4*j+10],s2); s2 = fmaf(k2.w,q[4*j+11],s2);
                s3 = fmaf(k3.x,q[4*j+12],s3); s3 = fmaf(k3.y,q[4*j+13],s3);
                s3 = fmaf(k3.z,q[4*j+14],s3); s3 = fmaf(k3.w,q[4*j+15],s3);
            }
            float s = (s0+s1) + (s2+s3);
            float p = __expf(s * 0.125f);
            l += p;
            const float4* vr = (const float4*)&Vs[vv*64];
            #pragma unroll
            for (int j = 0; j < 16; ++j) {
                float4 vv4 = vr[j];
                oacc[4*j+0] = fmaf(p, vv4.x, oacc[4*j+0]);
                oacc[4*j+1] = fmaf(p, vv4.y, oacc[4*j+1]);
                oacc[4*j+2] = fmaf(p, vv4.z, oacc[4*j+2]);
                oacc[4*j+3] = fmaf(p, vv4.w, oacc[4*j+3]);
            }
        }
    }
    float inv = 1.f / l;
    const size_t obase = (size_t)n*CHW_ + (size_t)h*W_ + tid;
    #pragma unroll
    for (int o = 0; o < 64; ++o) {
        float f = oacc[o] * inv;
        size_t idx = obase + (size_t)o*HW_;
        out[idx] = xl[idx] + beta[o]*f;
    }
}

// ---------------------------------------------------------------------------
// K3: T = x_r - avg_pool3x3(x_r)  (zero pad, always /9), bf16 NCHW.
// ---------------------------------------------------------------------------
__global__ __launch_bounds__(256) void k_hipass(
    const float* __restrict__ xr, u16* __restrict__ T)
{
    const int blk = blockIdx.x;            // (n*64+c)*128 + h
    const int h = blk & 127;
    const int w = threadIdx.x;
    const size_t base = (size_t)blk*256 + w;
    float s = 0.f;
    #pragma unroll
    for (int dy = -1; dy <= 1; ++dy) {
        int hh = h + dy;
        if (hh < 0 || hh > 127) continue;
        const float* row = xr + (base + (size_t)(dy*256));
        float a = (w > 0)   ? row[-1] : 0.f;
        float b = row[0];
        float c = (w < 255) ? row[1]  : 0.f;
        s += a + b + c;
    }
    float t = xr[base] - s*(1.f/9.f);
    T[base] = f2bf(t);
}

// ---------------------------------------------------------------------------
// K4: hf = conv3x3(T) + b_hf ;  out += gamma*hf.   o-split in halves of 32.
// Weights staged in LDS as [i][k][o'] (o' contiguous, broadcast reads).
// ---------------------------------------------------------------------------
__global__ __launch_bounds__(256) void k_conv(
    const u16* __restrict__ T, const float* __restrict__ Whf,
    const float* __restrict__ bhf, const float* __restrict__ gamma,
    float* __restrict__ out)
{
    __shared__ float Wc[64*9*32];   // [i][k][o']  73728 B
    const int tid = threadIdx.x;
    const int blk = blockIdx.x;
    const int scan = blk >> 1, oh = blk & 1;
    const int n = scan >> 7, h = scan & 127;
    for (int g = tid; g < 18432; g += 256) {
        int o = g / 576;
        int rem = g - o*576;            // i*9 + k
        Wc[rem*32 + o] = Whf[(size_t)(oh*32 + o)*576 + rem];
    }
    __syncthreads();

    const int w = tid;
    float acc[32];
    #pragma unroll
    for (int o = 0; o < 32; ++o) acc[o] = 0.f;
    const size_t tbase = ((size_t)n*CHW_ + (size_t)h*W_) + w;  // channel 0

    for (int i = 0; i < 64; ++i) {
        const u16* tp = T + tbase + (size_t)i*HW_;
        float t[9];
        #pragma unroll
        for (int dy = 0; dy < 3; ++dy) {
            int hh = h + dy - 1;
            bool rok = (hh >= 0) && (hh < 128);
            const u16* rp = tp + (dy-1)*256;
            t[dy*3+0] = (rok && w > 0)   ? blo((u32)rp[-1]) : 0.f;
            t[dy*3+1] =  rok             ? blo((u32)rp[0])  : 0.f;
            t[dy*3+2] = (rok && w < 255) ? blo((u32)rp[1])  : 0.f;
        }
        const float* wbase = &Wc[i*288];
        #pragma unroll
        for (int k = 0; k < 9; ++k) {
            float tk = t[k];
            const float4* wk4 = (const float4*)(wbase + k*32);
            #pragma unroll
            for (int o4 = 0; o4 < 8; ++o4) {
                float4 wv = wk4[o4];
                acc[4*o4+0] = fmaf(wv.x, tk, acc[4*o4+0]);
                acc[4*o4+1] = fmaf(wv.y, tk, acc[4*o4+1]);
                acc[4*o4+2] = fmaf(wv.z, tk, acc[4*o4+2]);
                acc[4*o4+3] = fmaf(wv.w, tk, acc[4*o4+3]);
            }
        }
    }
    #pragma unroll
    for (int o2 = 0; o2 < 32; ++o2) {
        int o = oh*32 + o2;
        float hf = acc[o2] + bhf[o];
        size_t idx = ((size_t)n*CHW_ + (size_t)o*HW_ + (size_t)h*W_) + w;
        out[idx] += gamma[o]*hf;
    }
}

extern "C" void kernel_launch(void* const* d_in, const int* in_sizes, int n_in,
                              void* d_out, int out_size, void* d_ws, size_t ws_size,
                              hipStream_t stream)
{
    const float* xl   = (const float*)d_in[0];
    const float* xr   = (const float*)d_in[1];
    const float* nlw  = (const float*)d_in[2];
    const float* nlb  = (const float*)d_in[3];
    const float* nrw  = (const float*)d_in[4];
    const float* nrb  = (const float*)d_in[5];
    const float* Wql  = (const float*)d_in[6];
    const float* bql  = (const float*)d_in[7];
    const float* Wqr  = (const float*)d_in[8];
    const float* bqr  = (const float*)d_in[9];
    const float* Wvr  = (const float*)d_in[10];
    const float* bvr  = (const float*)d_in[11];
    const float* beta = (const float*)d_in[12];
    const float* gam  = (const float*)d_in[13];
    const float* Whf  = (const float*)d_in[14];
    const float* bhf  = (const float*)d_in[15];
    float* out = (float*)d_out;

    // workspace: Ql, Qr, Vr (bf16, 32MB each) + T (bf16, 32MB) = 128 MB
    u32* Ql = (u32*)d_ws;                 // 16777216 bf16 = 8388608 u32
    u32* Qr = Ql + 8388608;
    u32* Vr = Qr + 8388608;
    u16* T  = (u16*)(Vr + 8388608);

    k_proj<<<1024, 256, 0, stream>>>(xl, xr, nlw, nlb, nrw, nrb,
                                     Wql, bql, Wqr, bqr, Wvr, bvr, Ql, Qr, Vr);
    k_hipass<<<8*64*128, 256, 0, stream>>>(xr, T);
    k_attn<<<1024, 256, 0, stream>>>(Ql, Qr, Vr, xl, beta, out);
    k_conv<<<2048, 256, 0, stream>>>(T, Whf, bhf, gam, out);
}

// Round 3
// 1060.998 us; speedup vs baseline: 1.4593x; 1.4593x over previous
//
#include <hip/hip_runtime.h>
#include <hip/hip_bf16.h>

#define N_ 8
#define C_ 64
#define H_ 128
#define W_ 256
#define HW_ (H_*W_)        // 32768
#define CHW_ (C_*H_*W_)    // 2097152

typedef unsigned int u32;
typedef unsigned short u16;
typedef float f32x4 __attribute__((ext_vector_type(4)));
typedef short bf16x8 __attribute__((ext_vector_type(8)));

__device__ __forceinline__ float blo(u32 u) { return __uint_as_float(u << 16); }
__device__ __forceinline__ float bhi(u32 u) { return __uint_as_float(u & 0xffff0000u); }
__device__ __forceinline__ u16 f2bf(float f) {
    u32 u = __float_as_uint(f);
    u32 lsb = (u >> 16) & 1u;
    u += 0x7fffu + lsb;
    return (u16)(u >> 16);
}
__device__ __forceinline__ u32 pack2(float a, float b) {
    return (u32)f2bf(a) | ((u32)f2bf(b) << 16);
}

// ---------------------------------------------------------------------------
// K1: LayerNorm + 1x1 conv projections (unchanged from passing version).
// ---------------------------------------------------------------------------
__global__ __launch_bounds__(256) void k_proj(
    const float* __restrict__ xl, const float* __restrict__ xr,
    const float* __restrict__ nlw, const float* __restrict__ nlb,
    const float* __restrict__ nrw, const float* __restrict__ nrb,
    const float* __restrict__ Wql, const float* __restrict__ bql,
    const float* __restrict__ Wqr, const float* __restrict__ bqr,
    const float* __restrict__ Wvr, const float* __restrict__ bvr,
    u32* __restrict__ Ql, u32* __restrict__ Qr, u32* __restrict__ Vr)
{
    __shared__ float Al[4096], Ar[4096], Wv[4096];
    __shared__ float Sl[64], Bl[64], Sr[64], Br[64];
    const int tid = threadIdx.x;
    for (int idx = tid; idx < 4096; idx += 256) {
        int c = idx & 63;
        Al[idx] = Wql[idx] * nlw[c];
        Ar[idx] = Wqr[idx] * nrw[c];
        Wv[idx] = Wvr[idx];
    }
    __syncthreads();
    if (tid < 64) {
        int o = tid;
        float sl = 0.f, bl = bql[o], sr = 0.f, br = bqr[o];
        for (int c = 0; c < 64; ++c) {
            sl += Al[o*64+c];
            bl += Wql[o*64+c] * nlb[c];
            sr += Ar[o*64+c];
            br += Wqr[o*64+c] * nrb[c];
        }
        Sl[o] = sl; Bl[o] = bl; Sr[o] = sr; Br[o] = br;
    }
    __syncthreads();

    const int blk = blockIdx.x;
    const int n = blk >> 7, h = blk & 127;
    const int w = tid;
    const size_t pbase = (size_t)n*CHW_ + (size_t)h*W_ + w;

    float xv[64];
    float sum = 0.f, ssq = 0.f;
    #pragma unroll
    for (int c = 0; c < 64; ++c) {
        float v = xl[pbase + (size_t)c*HW_];
        xv[c] = v; sum += v; ssq += v*v;
    }
    float mu = sum * (1.f/64.f);
    float var = ssq * (1.f/64.f) - mu*mu;
    float rs = rsqrtf(var + 1e-6f);
    const size_t row32 = ((size_t)blk*256 + w) * 32;
    for (int o = 0; o < 64; o += 2) {
        const float4* a4 = (const float4*)&Al[o*64];
        float d0a=0.f,d0b=0.f,d1a=0.f,d1b=0.f;
        #pragma unroll
        for (int j = 0; j < 16; j += 2) {
            float4 r0 = a4[j],   r1 = a4[j+1];
            float4 s0 = a4[16+j],s1 = a4[16+j+1];
            d0a = fmaf(r0.x,xv[4*j+0],d0a); d0a = fmaf(r0.y,xv[4*j+1],d0a);
            d0a = fmaf(r0.z,xv[4*j+2],d0a); d0a = fmaf(r0.w,xv[4*j+3],d0a);
            d0b = fmaf(r1.x,xv[4*j+4],d0b); d0b = fmaf(r1.y,xv[4*j+5],d0b);
            d0b = fmaf(r1.z,xv[4*j+6],d0b); d0b = fmaf(r1.w,xv[4*j+7],d0b);
            d1a = fmaf(s0.x,xv[4*j+0],d1a); d1a = fmaf(s0.y,xv[4*j+1],d1a);
            d1a = fmaf(s0.z,xv[4*j+2],d1a); d1a = fmaf(s0.w,xv[4*j+3],d1a);
            d1b = fmaf(s1.x,xv[4*j+4],d1b); d1b = fmaf(s1.y,xv[4*j+5],d1b);
            d1b = fmaf(s1.z,xv[4*j+6],d1b); d1b = fmaf(s1.w,xv[4*j+7],d1b);
        }
        float q0 = rs*((d0a+d0b) - mu*Sl[o])   + Bl[o];
        float q1 = rs*((d1a+d1b) - mu*Sl[o+1]) + Bl[o+1];
        Ql[row32 + (o>>1)] = pack2(q0, q1);
    }
    sum = 0.f; ssq = 0.f;
    #pragma unroll
    for (int c = 0; c < 64; ++c) {
        float v = xr[pbase + (size_t)c*HW_];
        xv[c] = v; sum += v; ssq += v*v;
    }
    mu = sum * (1.f/64.f);
    var = ssq * (1.f/64.f) - mu*mu;
    rs = rsqrtf(var + 1e-6f);
    for (int o = 0; o < 64; o += 2) {
        const float4* a4 = (const float4*)&Ar[o*64];
        const float4* v4 = (const float4*)&Wv[o*64];
        float d0=0.f,d1=0.f,e0=0.f,e1=0.f;
        #pragma unroll
        for (int j = 0; j < 16; ++j) {
            float4 r0 = a4[j], r1 = a4[16+j];
            float4 t0 = v4[j], t1 = v4[16+j];
            float x0 = xv[4*j+0], x1 = xv[4*j+1], x2 = xv[4*j+2], x3 = xv[4*j+3];
            d0 = fmaf(r0.x,x0,d0); d0 = fmaf(r0.y,x1,d0); d0 = fmaf(r0.z,x2,d0); d0 = fmaf(r0.w,x3,d0);
            d1 = fmaf(r1.x,x0,d1); d1 = fmaf(r1.y,x1,d1); d1 = fmaf(r1.z,x2,d1); d1 = fmaf(r1.w,x3,d1);
            e0 = fmaf(t0.x,x0,e0); e0 = fmaf(t0.y,x1,e0); e0 = fmaf(t0.z,x2,e0); e0 = fmaf(t0.w,x3,e0);
            e1 = fmaf(t1.x,x0,e1); e1 = fmaf(t1.y,x1,e1); e1 = fmaf(t1.z,x2,e1); e1 = fmaf(t1.w,x3,e1);
        }
        float q0 = rs*(d0 - mu*Sr[o])   + Br[o];
        float q1 = rs*(d1 - mu*Sr[o+1]) + Br[o+1];
        Qr[row32 + (o>>1)] = pack2(q0, q1);
        Vr[row32 + (o>>1)] = pack2(e0 + bvr[o], e1 + bvr[o+1]);
    }
}

// ---------------------------------------------------------------------------
// K2: per-scanline cross attention (unchanged from passing version).
// ---------------------------------------------------------------------------
__global__ __launch_bounds__(256) void k_attn(
    const u32* __restrict__ Ql, const u32* __restrict__ Qr, const u32* __restrict__ Vr,
    const float* __restrict__ xl, const float* __restrict__ beta,
    float* __restrict__ out)
{
    __shared__ float QRs[128*64];
    __shared__ float Vs[128*64];
    const int tid = threadIdx.x;
    const int blk = blockIdx.x;
    const int n = blk >> 7, h = blk & 127;

    float q[64];
    const uint4* qrow4 = (const uint4*)(Ql + ((size_t)blk*256 + tid)*32);
    #pragma unroll
    for (int j = 0; j < 8; ++j) {
        uint4 u = qrow4[j];
        q[8*j+0] = blo(u.x); q[8*j+1] = bhi(u.x);
        q[8*j+2] = blo(u.y); q[8*j+3] = bhi(u.y);
        q[8*j+4] = blo(u.z); q[8*j+5] = bhi(u.z);
        q[8*j+6] = blo(u.w); q[8*j+7] = bhi(u.w);
    }
    float oacc[64];
    #pragma unroll
    for (int c = 0; c < 64; ++c) oacc[c] = 0.f;
    float l = 0.f;

    for (int tt = 0; tt < 2; ++tt) {
        __syncthreads();
        const uint4* qr4 = (const uint4*)(Qr + ((size_t)blk*256 + tt*128)*32);
        const uint4* vr4 = (const uint4*)(Vr + ((size_t)blk*256 + tt*128)*32);
        for (int j4 = tid; j4 < 1024; j4 += 256) {
            uint4 a = qr4[j4];
            float* d = &QRs[j4*8];
            d[0]=blo(a.x); d[1]=bhi(a.x); d[2]=blo(a.y); d[3]=bhi(a.y);
            d[4]=blo(a.z); d[5]=bhi(a.z); d[6]=blo(a.w); d[7]=bhi(a.w);
            uint4 b = vr4[j4];
            float* e = &Vs[j4*8];
            e[0]=blo(b.x); e[1]=bhi(b.x); e[2]=blo(b.y); e[3]=bhi(b.y);
            e[4]=blo(b.z); e[5]=bhi(b.z); e[6]=blo(b.w); e[7]=bhi(b.w);
        }
        __syncthreads();
        for (int vv = 0; vv < 128; ++vv) {
            const float4* kr4 = (const float4*)&QRs[vv*64];
            float s0=0.f,s1=0.f,s2=0.f,s3=0.f;
            #pragma unroll
            for (int j = 0; j < 16; j += 4) {
                float4 k0 = kr4[j], k1 = kr4[j+1], k2 = kr4[j+2], k3 = kr4[j+3];
                s0 = fmaf(k0.x,q[4*j+0],s0);  s0 = fmaf(k0.y,q[4*j+1],s0);
                s0 = fmaf(k0.z,q[4*j+2],s0);  s0 = fmaf(k0.w,q[4*j+3],s0);
                s1 = fmaf(k1.x,q[4*j+4],s1);  s1 = fmaf(k1.y,q[4*j+5],s1);
                s1 = fmaf(k1.z,q[4*j+6],s1);  s1 = fmaf(k1.w,q[4*j+7],s1);
                s2 = fmaf(k2.x,q[4*j+8],s2);  s2 = fmaf(k2.y,q[4*j+9],s2);
                s2 = fmaf(k2.z,q[4*j+10],s2); s2 = fmaf(k2.w,q[4*j+11],s2);
                s3 = fmaf(k3.x,q[4*j+12],s3); s3 = fmaf(k3.y,q[4*j+13],s3);
                s3 = fmaf(k3.z,q[4*j+14],s3); s3 = fmaf(k3.w,q[4*j+15],s3);
            }
            float s = (s0+s1) + (s2+s3);
            float p = __expf(s * 0.125f);
            l += p;
            const float4* vr = (const float4*)&Vs[vv*64];
            #pragma unroll
            for (int j = 0; j < 16; ++j) {
                float4 vv4 = vr[j];
                oacc[4*j+0] = fmaf(p, vv4.x, oacc[4*j+0]);
                oacc[4*j+1] = fmaf(p, vv4.y, oacc[4*j+1]);
                oacc[4*j+2] = fmaf(p, vv4.z, oacc[4*j+2]);
                oacc[4*j+3] = fmaf(p, vv4.w, oacc[4*j+3]);
            }
        }
    }
    float inv = 1.f / l;
    const size_t obase = (size_t)n*CHW_ + (size_t)h*W_ + tid;
    #pragma unroll
    for (int o = 0; o < 64; ++o) {
        float f = oacc[o] * inv;
        size_t idx = obase + (size_t)o*HW_;
        out[idx] = xl[idx] + beta[o]*f;
    }
}

// ---------------------------------------------------------------------------
// K3: T_t[n][h][w][c] = highpass(x_r), bf16, channel-contiguous.
// Block = one (n,h) row; thread = w; loops c, 9 predicated loads per c
// (overlapping reads served by L1; distinct-HBM ~196KB/block).
// Writes 16B (8 channels) per store.
// ---------------------------------------------------------------------------
__global__ __launch_bounds__(256) void k_hipass(
    const float* __restrict__ xr, u16* __restrict__ Tt)
{
    const int blk = blockIdx.x;            // n*128 + h
    const int n = blk >> 7, h = blk & 127;
    const int w = threadIdx.x;
    const bool wok0 = (w > 0), wok1 = (w < 255);
    const size_t base = (size_t)n*CHW_ + (size_t)h*W_ + w;
    uint4* outp = (uint4*)(Tt + ((size_t)blk*256 + w)*64);

    for (int c0 = 0; c0 < 64; c0 += 8) {
        u32 pk[4];
        #pragma unroll
        for (int cp = 0; cp < 4; ++cp) {
            float tv[2];
            #pragma unroll
            for (int cc = 0; cc < 2; ++cc) {
                const float* p = xr + base + (size_t)(c0 + cp*2 + cc)*HW_;
                float s = 0.f, ctr = 0.f;
                #pragma unroll
                for (int dy = -1; dy <= 1; ++dy) {
                    int hh = h + dy;
                    if (hh < 0 || hh > 127) continue;
                    const float* row = p + dy*256;
                    float a = wok0 ? row[-1] : 0.f;
                    float b = row[0];
                    float c = wok1 ? row[1]  : 0.f;
                    if (dy == 0) ctr = b;
                    s += a + b + c;
                }
                tv[cc] = ctr - s*(1.f/9.f);
            }
            pk[cp] = pack2(tv[0], tv[1]);
        }
        uint4 v; v.x = pk[0]; v.y = pk[1]; v.z = pk[2]; v.w = pk[3];
        outp[c0 >> 3] = v;
    }
}

// ---------------------------------------------------------------------------
// K4: conv3x3 as MFMA GEMM.  M=64 (o), K=576 (k = q*64 + i, q=3*dy+dx),
// N=pixels.  Block = one scanline row, 4 tiles of 64px.  Wave mt owns
// 16 output channels; A (weights bf16) in registers (18 frags); B from
// XOR-swizzled LDS tile [3][66][64ch].  out += gamma*(conv + b_hf).
// ---------------------------------------------------------------------------
__global__ __launch_bounds__(256) void k_conv(
    const u16* __restrict__ Tt, const float* __restrict__ Whf,
    const float* __restrict__ bhf, const float* __restrict__ gam,
    float* __restrict__ out)
{
    __shared__ uint4 Xs[3*66*8];           // 25344 B, [dy][wt][chunk^(wt&7)]
    const int tid  = threadIdx.x;
    const int lane = tid & 63;
    const int mt   = tid >> 6;             // wave id = m-tile (16 channels)
    const int l15  = lane & 15;
    const int kg   = lane >> 4;            // k-group 0..3
    const int blk  = blockIdx.x;           // n*128 + h
    const int n = blk >> 7, h = blk & 127;

    // ---- A preload: A[o][k] = bf16(W_hf[o][i][q]), k = q*64+i ----
    const int oa = mt*16 + l15;
    bf16x8 A[18];
    #pragma unroll
    for (int s = 0; s < 18; ++s) {
        const int q  = s >> 1;
        const int ib = (s & 1)*32 + kg*8;
        bf16x8 a;
        #pragma unroll
        for (int j = 0; j < 8; ++j) {
            float wv = Whf[(size_t)(oa*64 + ib + j)*9 + q];
            a[j] = (short)f2bf(wv);
        }
        A[s] = a;
    }
    // per-lane output channels for the epilogue
    float gv[4], bv[4];
    #pragma unroll
    for (int r = 0; r < 4; ++r) {
        int oo = mt*16 + kg*4 + r;
        gv[r] = gam[oo];
        bv[r] = bhf[oo];
    }

    for (int t4 = 0; t4 < 4; ++t4) {
        const int w0 = t4*64;
        __syncthreads();
        // stage tile: 3 rows x 66 px x 8 chunks of 8 channels
        for (int it = tid; it < 1584; it += 256) {
            int dy    = it / 528;
            int rem   = it - dy*528;
            int wt    = rem >> 3;
            int chunk = rem & 7;
            int hh = h + dy - 1;
            int wg = w0 + wt - 1;
            uint4 v = {0,0,0,0};
            if (hh >= 0 && hh < 128 && wg >= 0 && wg < 256)
                v = *(const uint4*)(Tt + (((size_t)(n*128 + hh)*256 + wg)*64 + chunk*8));
            Xs[(dy*66 + wt)*8 + (chunk ^ (wt & 7))] = v;
        }
        __syncthreads();

        f32x4 acc[4] = {{0,0,0,0},{0,0,0,0},{0,0,0,0},{0,0,0,0}};
        #pragma unroll
        for (int s = 0; s < 18; ++s) {
            const int q  = s >> 1;
            const int dy = q / 3, dx = q % 3;
            const int c0 = (s & 1)*4 + kg;
            #pragma unroll
            for (int nt = 0; nt < 4; ++nt) {
                const int wt = nt*16 + l15 + dx;      // halo-adjusted index
                bf16x8 b = *(const bf16x8*)&Xs[(dy*66 + wt)*8 + (c0 ^ (wt & 7))];
                acc[nt] = __builtin_amdgcn_mfma_f32_16x16x32_bf16(A[s], b, acc[nt], 0, 0, 0);
            }
        }
        // epilogue: out += gamma*(acc + b_hf)
        #pragma unroll
        for (int nt = 0; nt < 4; ++nt) {
            const int px = w0 + nt*16 + l15;
            #pragma unroll
            for (int r = 0; r < 4; ++r) {
                const int oo = mt*16 + kg*4 + r;
                size_t idx = (size_t)(n*64 + oo)*HW_ + (size_t)h*W_ + px;
                out[idx] += gv[r]*(acc[nt][r] + bv[r]);
            }
        }
    }
}

extern "C" void kernel_launch(void* const* d_in, const int* in_sizes, int n_in,
                              void* d_out, int out_size, void* d_ws, size_t ws_size,
                              hipStream_t stream)
{
    const float* xl   = (const float*)d_in[0];
    const float* xr   = (const float*)d_in[1];
    const float* nlw  = (const float*)d_in[2];
    const float* nlb  = (const float*)d_in[3];
    const float* nrw  = (const float*)d_in[4];
    const float* nrb  = (const float*)d_in[5];
    const float* Wql  = (const float*)d_in[6];
    const float* bql  = (const float*)d_in[7];
    const float* Wqr  = (const float*)d_in[8];
    const float* bqr  = (const float*)d_in[9];
    const float* Wvr  = (const float*)d_in[10];
    const float* bvr  = (const float*)d_in[11];
    const float* beta = (const float*)d_in[12];
    const float* gam  = (const float*)d_in[13];
    const float* Whf  = (const float*)d_in[14];
    const float* bhf  = (const float*)d_in[15];
    float* out = (float*)d_out;

    // workspace: Ql, Qr, Vr (bf16, 32MB each) + T_t (bf16, 32MB) = 128 MB
    u32* Ql = (u32*)d_ws;
    u32* Qr = Ql + 8388608;
    u32* Vr = Qr + 8388608;
    u16* Tt = (u16*)(Vr + 8388608);

    k_proj<<<1024, 256, 0, stream>>>(xl, xr, nlw, nlb, nrw, nrb,
                                     Wql, bql, Wqr, bqr, Wvr, bvr, Ql, Qr, Vr);
    k_hipass<<<1024, 256, 0, stream>>>(xr, Tt);
    k_attn<<<1024, 256, 0, stream>>>(Ql, Qr, Vr, xl, beta, out);
    k_conv<<<1024, 256, 0, stream>>>(Tt, Whf, bhf, gam, out);
}

// Round 4
// 614.416 us; speedup vs baseline: 2.5201x; 1.7268x over previous
//
#include <hip/hip_runtime.h>
#include <hip/hip_bf16.h>

#define N_ 8
#define C_ 64
#define H_ 128
#define W_ 256
#define HW_ (H_*W_)        // 32768
#define CHW_ (C_*H_*W_)    // 2097152

typedef unsigned int u32;
typedef unsigned short u16;
typedef float f32x4 __attribute__((ext_vector_type(4)));
typedef short bf16x8 __attribute__((ext_vector_type(8)));

__device__ __forceinline__ float blo(u32 u) { return __uint_as_float(u << 16); }
__device__ __forceinline__ float bhi(u32 u) { return __uint_as_float(u & 0xffff0000u); }
__device__ __forceinline__ u16 f2bf(float f) {
    u32 u = __float_as_uint(f);
    u32 lsb = (u >> 16) & 1u;
    u += 0x7fffu + lsb;
    return (u16)(u >> 16);
}
__device__ __forceinline__ u32 pack2(float a, float b) {
    return (u32)f2bf(a) | ((u32)f2bf(b) << 16);
}

// ---------------------------------------------------------------------------
// K1: LayerNorm + 1x1 conv projections (unchanged, validated).
// ---------------------------------------------------------------------------
__global__ __launch_bounds__(256) void k_proj(
    const float* __restrict__ xl, const float* __restrict__ xr,
    const float* __restrict__ nlw, const float* __restrict__ nlb,
    const float* __restrict__ nrw, const float* __restrict__ nrb,
    const float* __restrict__ Wql, const float* __restrict__ bql,
    const float* __restrict__ Wqr, const float* __restrict__ bqr,
    const float* __restrict__ Wvr, const float* __restrict__ bvr,
    u32* __restrict__ Ql, u32* __restrict__ Qr, u32* __restrict__ Vr)
{
    __shared__ float Al[4096], Ar[4096], Wv[4096];
    __shared__ float Sl[64], Bl[64], Sr[64], Br[64];
    const int tid = threadIdx.x;
    for (int idx = tid; idx < 4096; idx += 256) {
        int c = idx & 63;
        Al[idx] = Wql[idx] * nlw[c];
        Ar[idx] = Wqr[idx] * nrw[c];
        Wv[idx] = Wvr[idx];
    }
    __syncthreads();
    if (tid < 64) {
        int o = tid;
        float sl = 0.f, bl = bql[o], sr = 0.f, br = bqr[o];
        for (int c = 0; c < 64; ++c) {
            sl += Al[o*64+c];
            bl += Wql[o*64+c] * nlb[c];
            sr += Ar[o*64+c];
            br += Wqr[o*64+c] * nrb[c];
        }
        Sl[o] = sl; Bl[o] = bl; Sr[o] = sr; Br[o] = br;
    }
    __syncthreads();

    const int blk = blockIdx.x;
    const int n = blk >> 7, h = blk & 127;
    const int w = tid;
    const size_t pbase = (size_t)n*CHW_ + (size_t)h*W_ + w;

    float xv[64];
    float sum = 0.f, ssq = 0.f;
    #pragma unroll
    for (int c = 0; c < 64; ++c) {
        float v = xl[pbase + (size_t)c*HW_];
        xv[c] = v; sum += v; ssq += v*v;
    }
    float mu = sum * (1.f/64.f);
    float var = ssq * (1.f/64.f) - mu*mu;
    float rs = rsqrtf(var + 1e-6f);
    const size_t row32 = ((size_t)blk*256 + w) * 32;
    for (int o = 0; o < 64; o += 2) {
        const float4* a4 = (const float4*)&Al[o*64];
        float d0a=0.f,d0b=0.f,d1a=0.f,d1b=0.f;
        #pragma unroll
        for (int j = 0; j < 16; j += 2) {
            float4 r0 = a4[j],   r1 = a4[j+1];
            float4 s0 = a4[16+j],s1 = a4[16+j+1];
            d0a = fmaf(r0.x,xv[4*j+0],d0a); d0a = fmaf(r0.y,xv[4*j+1],d0a);
            d0a = fmaf(r0.z,xv[4*j+2],d0a); d0a = fmaf(r0.w,xv[4*j+3],d0a);
            d0b = fmaf(r1.x,xv[4*j+4],d0b); d0b = fmaf(r1.y,xv[4*j+5],d0b);
            d0b = fmaf(r1.z,xv[4*j+6],d0b); d0b = fmaf(r1.w,xv[4*j+7],d0b);
            d1a = fmaf(s0.x,xv[4*j+0],d1a); d1a = fmaf(s0.y,xv[4*j+1],d1a);
            d1a = fmaf(s0.z,xv[4*j+2],d1a); d1a = fmaf(s0.w,xv[4*j+3],d1a);
            d1b = fmaf(s1.x,xv[4*j+4],d1b); d1b = fmaf(s1.y,xv[4*j+5],d1b);
            d1b = fmaf(s1.z,xv[4*j+6],d1b); d1b = fmaf(s1.w,xv[4*j+7],d1b);
        }
        float q0 = rs*((d0a+d0b) - mu*Sl[o])   + Bl[o];
        float q1 = rs*((d1a+d1b) - mu*Sl[o+1]) + Bl[o+1];
        Ql[row32 + (o>>1)] = pack2(q0, q1);
    }
    sum = 0.f; ssq = 0.f;
    #pragma unroll
    for (int c = 0; c < 64; ++c) {
        float v = xr[pbase + (size_t)c*HW_];
        xv[c] = v; sum += v; ssq += v*v;
    }
    mu = sum * (1.f/64.f);
    var = ssq * (1.f/64.f) - mu*mu;
    rs = rsqrtf(var + 1e-6f);
    for (int o = 0; o < 64; o += 2) {
        const float4* a4 = (const float4*)&Ar[o*64];
        const float4* v4 = (const float4*)&Wv[o*64];
        float d0=0.f,d1=0.f,e0=0.f,e1=0.f;
        #pragma unroll
        for (int j = 0; j < 16; ++j) {
            float4 r0 = a4[j], r1 = a4[16+j];
            float4 t0 = v4[j], t1 = v4[16+j];
            float x0 = xv[4*j+0], x1 = xv[4*j+1], x2 = xv[4*j+2], x3 = xv[4*j+3];
            d0 = fmaf(r0.x,x0,d0); d0 = fmaf(r0.y,x1,d0); d0 = fmaf(r0.z,x2,d0); d0 = fmaf(r0.w,x3,d0);
            d1 = fmaf(r1.x,x0,d1); d1 = fmaf(r1.y,x1,d1); d1 = fmaf(r1.z,x2,d1); d1 = fmaf(r1.w,x3,d1);
            e0 = fmaf(t0.x,x0,e0); e0 = fmaf(t0.y,x1,e0); e0 = fmaf(t0.z,x2,e0); e0 = fmaf(t0.w,x3,e0);
            e1 = fmaf(t1.x,x0,e1); e1 = fmaf(t1.y,x1,e1); e1 = fmaf(t1.z,x2,e1); e1 = fmaf(t1.w,x3,e1);
        }
        float q0 = rs*(d0 - mu*Sr[o])   + Br[o];
        float q1 = rs*(d1 - mu*Sr[o+1]) + Br[o+1];
        Qr[row32 + (o>>1)] = pack2(q0, q1);
        Vr[row32 + (o>>1)] = pack2(e0 + bvr[o], e1 + bvr[o+1]);
    }
}

// ---------------------------------------------------------------------------
// K2: per-scanline cross attention via MFMA.
// Block = scanline (n,h); 4 waves, wave owns 64 queries.
// LDS: K rows [key][64ch] bf16 (swizzled), V^T [ch][256key] bf16 (swizzled),
// per-wave P scratch (bf16 P tile, reused as f32 O-transpose buffer).
// S^T = K·Q^T (m=key) -> exp -> cvt_pk -> P LDS -> O += P·V.
// Softmax without max subtraction (validated numerically in scalar version).
// ---------------------------------------------------------------------------
__global__ __launch_bounds__(256, 2) void k_attn(
    const u32* __restrict__ Ql, const u32* __restrict__ Qr, const u32* __restrict__ Vr,
    const float* __restrict__ xl, const float* __restrict__ beta,
    float* __restrict__ out)
{
    __shared__ uint4 Ks[2048];      // 32 KB  [key][chunk16 ^ (key&7)]
    __shared__ u16  Vts[16384];     // 32 KB  V^T [ch][key], chunk ^ (ch&7)
    __shared__ u32  Pscr[4096];     // 16 KB  per-wave 1024 u32
    const int tid  = threadIdx.x;
    const int lane = tid & 63, wv = tid >> 6;
    const int l15  = lane & 15, kg = lane >> 4;
    const int blk  = blockIdx.x;
    const int n = blk >> 7, h = blk & 127;
    const size_t rowb = (size_t)blk*256;

    // ---- stage K = Q_r rows ----
    for (int it = tid; it < 2048; it += 256) {
        int key = it >> 3, c = it & 7;
        uint4 v = *(const uint4*)(Qr + (rowb + key)*32 + c*4);
        Ks[key*8 + (c ^ (key & 7))] = v;
    }
    // ---- stage V^T (transpose scatter) ----
    for (int it = tid; it < 2048; it += 256) {
        int key = it & 255, j = it >> 8;
        uint4 v = *(const uint4*)(Vr + (rowb + key)*32 + j*4);
        const u32* vw = (const u32*)&v;
        #pragma unroll
        for (int t = 0; t < 8; ++t) {
            int ch = j*8 + t;
            u32 wd = vw[t >> 1];
            u16 hv = (t & 1) ? (u16)(wd >> 16) : (u16)(wd & 0xffffu);
            Vts[ch*256 + ((key >> 3) ^ (ch & 7))*8 + (key & 7)] = hv;
        }
    }

    // ---- Q fragments (B operand), register resident ----
    const int q0 = wv*64;
    bf16x8 qf[4][2];
    #pragma unroll
    for (int nt = 0; nt < 4; ++nt)
        #pragma unroll
        for (int ci = 0; ci < 2; ++ci)
            qf[nt][ci] = *(const bf16x8*)(Ql + (rowb + q0 + nt*16 + l15)*32 + ci*16 + kg*4);

    f32x4 oacc[4][4];
    #pragma unroll
    for (int a = 0; a < 4; ++a)
        #pragma unroll
        for (int b = 0; b < 4; ++b)
            oacc[a][b] = (f32x4){0.f,0.f,0.f,0.f};
    float lsum[4] = {0.f,0.f,0.f,0.f};
    u32* Pw = &Pscr[wv*1024];

    __syncthreads();

    for (int kb = 0; kb < 8; ++kb) {
        // ---- S^T = K · Q^T ----
        f32x4 st[2][4];
        #pragma unroll
        for (int mt = 0; mt < 2; ++mt)
            #pragma unroll
            for (int nt = 0; nt < 4; ++nt)
                st[mt][nt] = (f32x4){0.f,0.f,0.f,0.f};
        #pragma unroll
        for (int ci = 0; ci < 2; ++ci) {
            bf16x8 a0 = *(const bf16x8*)&Ks[(kb*32 +      l15)*8 + ((ci*4 + kg) ^ (l15 & 7))];
            bf16x8 a1 = *(const bf16x8*)&Ks[(kb*32 + 16 + l15)*8 + ((ci*4 + kg) ^ (l15 & 7))];
            #pragma unroll
            for (int nt = 0; nt < 4; ++nt) {
                st[0][nt] = __builtin_amdgcn_mfma_f32_16x16x32_bf16(a0, qf[nt][ci], st[0][nt], 0, 0, 0);
                st[1][nt] = __builtin_amdgcn_mfma_f32_16x16x32_bf16(a1, qf[nt][ci], st[1][nt], 0, 0, 0);
            }
        }
        // ---- exp, pack bf16 pairs, store P tile ----
        #pragma unroll
        for (int nt = 0; nt < 4; ++nt) {
            const int q = nt*16 + l15;
            #pragma unroll
            for (int mt = 0; mt < 2; ++mt) {
                float p0 = __expf(st[mt][nt][0]*0.125f);
                float p1 = __expf(st[mt][nt][1]*0.125f);
                float p2 = __expf(st[mt][nt][2]*0.125f);
                float p3 = __expf(st[mt][nt][3]*0.125f);
                lsum[nt] += (p0+p1)+(p2+p3);
                u32 pr0, pr1;
                asm("v_cvt_pk_bf16_f32 %0, %1, %2" : "=v"(pr0) : "v"(p0), "v"(p1));
                asm("v_cvt_pk_bf16_f32 %0, %1, %2" : "=v"(pr1) : "v"(p2), "v"(p3));
                const int c16 = (2*mt + (kg >> 1)) ^ (q & 3);
                uint2 pv; pv.x = pr0; pv.y = pr1;
                *(uint2*)&Pw[q*16 + c16*4 + (kg & 1)*2] = pv;
            }
        }
        asm volatile("s_waitcnt lgkmcnt(0)" ::: "memory");
        // ---- O += P · V ----
        bf16x8 vb[4];
        #pragma unroll
        for (int nc = 0; nc < 4; ++nc)
            vb[nc] = *(const bf16x8*)&Vts[(nc*16 + l15)*256 + ((kb*4 + kg) ^ (l15 & 7))*8];
        #pragma unroll
        for (int qt = 0; qt < 4; ++qt) {
            const int q = qt*16 + l15;
            bf16x8 pa = *(const bf16x8*)&Pw[q*16 + (kg ^ (q & 3))*4];
            #pragma unroll
            for (int nc = 0; nc < 4; ++nc)
                oacc[qt][nc] = __builtin_amdgcn_mfma_f32_16x16x32_bf16(pa, vb[nc], oacc[qt][nc], 0, 0, 0);
        }
    }

    // ---- denominator: reduce over kg groups, redistribute by D-row q ----
    #pragma unroll
    for (int nt = 0; nt < 4; ++nt) {
        float s = lsum[nt];
        s += __shfl_xor(s, 16, 64);
        s += __shfl_xor(s, 32, 64);
        lsum[nt] = s;
    }
    float linv[4][4];
    #pragma unroll
    for (int qt = 0; qt < 4; ++qt)
        #pragma unroll
        for (int r = 0; r < 4; ++r)
            linv[qt][r] = 1.0f / __shfl(lsum[qt], kg*4 + r, 64);

    // ---- epilogue: transpose O through P scratch, coalesced out writes ----
    float* PwF = (float*)Pw;
    const size_t obase = (size_t)n*CHW_ + (size_t)h*W_ + q0;
    #pragma unroll
    for (int nc = 0; nc < 4; ++nc) {
        asm volatile("s_waitcnt lgkmcnt(0)" ::: "memory");
        #pragma unroll
        for (int qt = 0; qt < 4; ++qt) {
            f32x4 vals;
            vals[0] = oacc[qt][nc][0]*linv[qt][0];
            vals[1] = oacc[qt][nc][1]*linv[qt][1];
            vals[2] = oacc[qt][nc][2]*linv[qt][2];
            vals[3] = oacc[qt][nc][3]*linv[qt][3];
            *(f32x4*)&PwF[l15*64 + ((qt*4 + kg) ^ l15)*4] = vals;
        }
        asm volatile("s_waitcnt lgkmcnt(0)" ::: "memory");
        #pragma unroll
        for (int chl = 0; chl < 16; ++chl) {
            const int ch = nc*16 + chl;
            float v = PwF[chl*64 + ((lane >> 2) ^ chl)*4 + (lane & 3)];
            size_t gidx = obase + (size_t)ch*HW_ + lane;
            out[gidx] = xl[gidx] + beta[ch]*v;
        }
    }
}

// ---------------------------------------------------------------------------
// K3: T_t[n][h][w][c] = highpass(x_r), bf16, channel-contiguous (unchanged).
// ---------------------------------------------------------------------------
__global__ __launch_bounds__(256) void k_hipass(
    const float* __restrict__ xr, u16* __restrict__ Tt)
{
    const int blk = blockIdx.x;            // n*128 + h
    const int n = blk >> 7, h = blk & 127;
    const int w = threadIdx.x;
    const bool wok0 = (w > 0), wok1 = (w < 255);
    const size_t base = (size_t)n*CHW_ + (size_t)h*W_ + w;
    uint4* outp = (uint4*)(Tt + ((size_t)blk*256 + w)*64);

    for (int c0 = 0; c0 < 64; c0 += 8) {
        u32 pk[4];
        #pragma unroll
        for (int cp = 0; cp < 4; ++cp) {
            float tv[2];
            #pragma unroll
            for (int cc = 0; cc < 2; ++cc) {
                const float* p = xr + base + (size_t)(c0 + cp*2 + cc)*HW_;
                float s = 0.f, ctr = 0.f;
                #pragma unroll
                for (int dy = -1; dy <= 1; ++dy) {
                    int hh = h + dy;
                    if (hh < 0 || hh > 127) continue;
                    const float* row = p + dy*256;
                    float a = wok0 ? row[-1] : 0.f;
                    float b = row[0];
                    float c = wok1 ? row[1]  : 0.f;
                    if (dy == 0) ctr = b;
                    s += a + b + c;
                }
                tv[cc] = ctr - s*(1.f/9.f);
            }
            pk[cp] = pack2(tv[0], tv[1]);
        }
        uint4 v; v.x = pk[0]; v.y = pk[1]; v.z = pk[2]; v.w = pk[3];
        outp[c0 >> 3] = v;
    }
}

// ---------------------------------------------------------------------------
// K4: conv3x3 as MFMA GEMM (unchanged, validated).
// ---------------------------------------------------------------------------
__global__ __launch_bounds__(256) void k_conv(
    const u16* __restrict__ Tt, const float* __restrict__ Whf,
    const float* __restrict__ bhf, const float* __restrict__ gam,
    float* __restrict__ out)
{
    __shared__ uint4 Xs[3*66*8];           // 25344 B, [dy][wt][chunk^(wt&7)]
    const int tid  = threadIdx.x;
    const int lane = tid & 63;
    const int mt   = tid >> 6;
    const int l15  = lane & 15;
    const int kg   = lane >> 4;
    const int blk  = blockIdx.x;           // n*128 + h
    const int n = blk >> 7, h = blk & 127;

    const int oa = mt*16 + l15;
    bf16x8 A[18];
    #pragma unroll
    for (int s = 0; s < 18; ++s) {
        const int q  = s >> 1;
        const int ib = (s & 1)*32 + kg*8;
        bf16x8 a;
        #pragma unroll
        for (int j = 0; j < 8; ++j) {
            float wv = Whf[(size_t)(oa*64 + ib + j)*9 + q];
            a[j] = (short)f2bf(wv);
        }
        A[s] = a;
    }
    float gv[4], bv[4];
    #pragma unroll
    for (int r = 0; r < 4; ++r) {
        int oo = mt*16 + kg*4 + r;
        gv[r] = gam[oo];
        bv[r] = bhf[oo];
    }

    for (int t4 = 0; t4 < 4; ++t4) {
        const int w0 = t4*64;
        __syncthreads();
        for (int it = tid; it < 1584; it += 256) {
            int dy    = it / 528;
            int rem   = it - dy*528;
            int wt    = rem >> 3;
            int chunk = rem & 7;
            int hh = h + dy - 1;
            int wg = w0 + wt - 1;
            uint4 v = {0,0,0,0};
            if (hh >= 0 && hh < 128 && wg >= 0 && wg < 256)
                v = *(const uint4*)(Tt + (((size_t)(n*128 + hh)*256 + wg)*64 + chunk*8));
            Xs[(dy*66 + wt)*8 + (chunk ^ (wt & 7))] = v;
        }
        __syncthreads();

        f32x4 acc[4] = {{0,0,0,0},{0,0,0,0},{0,0,0,0},{0,0,0,0}};
        #pragma unroll
        for (int s = 0; s < 18; ++s) {
            const int q  = s >> 1;
            const int dy = q / 3, dx = q % 3;
            const int c0 = (s & 1)*4 + kg;
            #pragma unroll
            for (int nt = 0; nt < 4; ++nt) {
                const int wt = nt*16 + l15 + dx;
                bf16x8 b = *(const bf16x8*)&Xs[(dy*66 + wt)*8 + (c0 ^ (wt & 7))];
                acc[nt] = __builtin_amdgcn_mfma_f32_16x16x32_bf16(A[s], b, acc[nt], 0, 0, 0);
            }
        }
        #pragma unroll
        for (int nt = 0; nt < 4; ++nt) {
            const int px = w0 + nt*16 + l15;
            #pragma unroll
            for (int r = 0; r < 4; ++r) {
                const int oo = mt*16 + kg*4 + r;
                size_t idx = (size_t)(n*64 + oo)*HW_ + (size_t)h*W_ + px;
                out[idx] += gv[r]*(acc[nt][r] + bv[r]);
            }
        }
    }
}

extern "C" void kernel_launch(void* const* d_in, const int* in_sizes, int n_in,
                              void* d_out, int out_size, void* d_ws, size_t ws_size,
                              hipStream_t stream)
{
    const float* xl   = (const float*)d_in[0];
    const float* xr   = (const float*)d_in[1];
    const float* nlw  = (const float*)d_in[2];
    const float* nlb  = (const float*)d_in[3];
    const float* nrw  = (const float*)d_in[4];
    const float* nrb  = (const float*)d_in[5];
    const float* Wql  = (const float*)d_in[6];
    const float* bql  = (const float*)d_in[7];
    const float* Wqr  = (const float*)d_in[8];
    const float* bqr  = (const float*)d_in[9];
    const float* Wvr  = (const float*)d_in[10];
    const float* bvr  = (const float*)d_in[11];
    const float* beta = (const float*)d_in[12];
    const float* gam  = (const float*)d_in[13];
    const float* Whf  = (const float*)d_in[14];
    const float* bhf  = (const float*)d_in[15];
    float* out = (float*)d_out;

    u32* Ql = (u32*)d_ws;
    u32* Qr = Ql + 8388608;
    u32* Vr = Qr + 8388608;
    u16* Tt = (u16*)(Vr + 8388608);

    k_proj<<<1024, 256, 0, stream>>>(xl, xr, nlw, nlb, nrw, nrb,
                                     Wql, bql, Wqr, bqr, Wvr, bvr, Ql, Qr, Vr);
    k_hipass<<<1024, 256, 0, stream>>>(xr, Tt);
    k_attn<<<1024, 256, 0, stream>>>(Ql, Qr, Vr, xl, beta, out);
    k_conv<<<1024, 256, 0, stream>>>(Tt, Whf, bhf, gam, out);
}

// Round 5
// 321.505 us; speedup vs baseline: 4.8160x; 1.9111x over previous
//
#include <hip/hip_runtime.h>
#include <hip/hip_bf16.h>

#define N_ 8
#define C_ 64
#define H_ 128
#define W_ 256
#define HW_ (H_*W_)        // 32768
#define CHW_ (C_*H_*W_)    // 2097152

typedef unsigned int u32;
typedef unsigned short u16;
typedef float f32x4 __attribute__((ext_vector_type(4)));
typedef short bf16x8 __attribute__((ext_vector_type(8)));

__device__ __forceinline__ float blo(u32 u) { return __uint_as_float(u << 16); }
__device__ __forceinline__ float bhi(u32 u) { return __uint_as_float(u & 0xffff0000u); }
__device__ __forceinline__ u16 f2bf(float f) {
    u32 u = __float_as_uint(f);
    u32 lsb = (u >> 16) & 1u;
    u += 0x7fffu + lsb;
    return (u16)(u >> 16);
}
__device__ __forceinline__ u32 pack2(float a, float b) {
    return (u32)f2bf(a) | ((u32)f2bf(b) << 16);
}

// ---------------------------------------------------------------------------
// K1: LayerNorm + 1x1 conv projections via MFMA.
// Block = scanline (n,h); 4 waves.  LDS tile Xs[px][64ch] bf16, chunk-swizzled
// (chunk ^ (px&7)).  Per-px LN stats from LDS; GEMM D[m=o][n=px] with LN
// folded: Q[o][px] = rs[px]*(dot[o][px] - mu[px]*S[o]) + B[o].
// V = raw conv1x1 + bias (no LN).  Outputs [row][64ch] bf16 (uint2 stores).
// ---------------------------------------------------------------------------
__global__ __launch_bounds__(256) void k_proj(
    const float* __restrict__ xl, const float* __restrict__ xr,
    const float* __restrict__ nlw, const float* __restrict__ nlb,
    const float* __restrict__ nrw, const float* __restrict__ nrb,
    const float* __restrict__ Wql, const float* __restrict__ bql,
    const float* __restrict__ Wqr, const float* __restrict__ bqr,
    const float* __restrict__ Wvr, const float* __restrict__ bvr,
    u32* __restrict__ Ql, u32* __restrict__ Qr, u32* __restrict__ Vr)
{
    __shared__ u32 Xs32[256*32];       // 32 KB  [px][cpair], 16B-chunk swizzled
    __shared__ float muA[256], rsA[256];
    __shared__ float SlA[64], BlA[64], SrA[64], BrA[64], BvA[64];
    const int tid  = threadIdx.x;
    const int lane = tid & 63, wv = tid >> 6;
    const int l15  = lane & 15, kg = lane >> 4;
    const int blk  = blockIdx.x;       // n*128 + h
    const int n = blk >> 7, h = blk & 127;
    const size_t gbase = (size_t)n*CHW_ + (size_t)h*W_;   // + c*HW_ + px
    const size_t rowb  = (size_t)blk*256;

    // ---- per-o affine folds (S, B) ----
    if (tid < 64) {
        const int o = tid;
        float sl = 0.f, bl = bql[o], sr = 0.f, br = bqr[o];
        for (int c = 0; c < 64; ++c) {
            float wl = Wql[o*64+c], wr = Wqr[o*64+c];
            sl += wl * nlw[c];
            bl += wl * nlb[c];
            sr += wr * nrw[c];
            br += wr * nrb[c];
        }
        SlA[o] = sl; BlA[o] = bl; SrA[o] = sr; BrA[o] = br; BvA[o] = bvr[o];
    }

    // ---- A fragments: left (Wql*nlw), right (Wqr*nrw), V (Wvr) ----
    const int oA = wv*16 + l15;
    bf16x8 aL[2], aR[2], aV[2];
    #pragma unroll
    for (int hf = 0; hf < 2; ++hf) {
        bf16x8 tl, tr, tv;
        #pragma unroll
        for (int j = 0; j < 8; ++j) {
            const int c = hf*32 + kg*8 + j;
            tl[j] = (short)f2bf(Wql[oA*64+c] * nlw[c]);
            tr[j] = (short)f2bf(Wqr[oA*64+c] * nrw[c]);
            tv[j] = (short)f2bf(Wvr[oA*64+c]);
        }
        aL[hf] = tl; aR[hf] = tr; aV[hf] = tv;
    }

    // ================= LEFT =================
    // stage xl tile: [px][c] bf16, pack channel pairs
    for (int idx = tid; idx < 2048; idx += 256) {
        const int cpair = idx >> 6, j = idx & 63;     // j = uint4 within row
        const float4 va = *(const float4*)(xl + gbase + (size_t)(2*cpair  )*HW_ + j*4);
        const float4 vb = *(const float4*)(xl + gbase + (size_t)(2*cpair+1)*HW_ + j*4);
        const float* fa = (const float*)&va;
        const float* fb = (const float*)&vb;
        #pragma unroll
        for (int t = 0; t < 4; ++t) {
            const int px = j*4 + t;
            Xs32[px*32 + (((cpair>>2) ^ (px&7))<<2) + (cpair&3)] = pack2(fa[t], fb[t]);
        }
    }
    __syncthreads();
    {   // stats for px = tid
        const int px = tid;
        float sum = 0.f, ssq = 0.f;
        #pragma unroll
        for (int c8 = 0; c8 < 8; ++c8) {
            const u32* wp = &Xs32[px*32 + ((c8 ^ (px&7))<<2)];
            #pragma unroll
            for (int q = 0; q < 4; ++q) {
                float a = blo(wp[q]), b = bhi(wp[q]);
                sum += a + b; ssq += a*a + b*b;
            }
        }
        float mu = sum * (1.f/64.f);
        float var = ssq * (1.f/64.f) - mu*mu;
        muA[px] = mu;
        rsA[px] = rsqrtf(var + 1e-6f);
    }
    __syncthreads();
    {   // GEMM left: D[o][px], o = wv*16 + (kg*4+r), px = nt*16+l15
        float Sv[4], Bv[4];
        #pragma unroll
        for (int r = 0; r < 4; ++r) {
            Sv[r] = SlA[wv*16 + kg*4 + r];
            Bv[r] = BlA[wv*16 + kg*4 + r];
        }
        #pragma unroll
        for (int nt = 0; nt < 16; ++nt) {
            const int px = nt*16 + l15;
            f32x4 d = {0.f,0.f,0.f,0.f};
            #pragma unroll
            for (int hf = 0; hf < 2; ++hf) {
                bf16x8 b = *(const bf16x8*)&Xs32[px*32 + (((hf*4+kg) ^ (px&7))<<2)];
                d = __builtin_amdgcn_mfma_f32_16x16x32_bf16(aL[hf], b, d, 0, 0, 0);
            }
            const float mu = muA[px], rs = rsA[px];
            uint2 pv;
            pv.x = pack2(rs*(d[0] - mu*Sv[0]) + Bv[0], rs*(d[1] - mu*Sv[1]) + Bv[1]);
            pv.y = pack2(rs*(d[2] - mu*Sv[2]) + Bv[2], rs*(d[3] - mu*Sv[3]) + Bv[3]);
            *(uint2*)&Ql[(rowb + px)*32 + wv*8 + kg*2] = pv;
        }
    }
    __syncthreads();

    // ================= RIGHT =================
    for (int idx = tid; idx < 2048; idx += 256) {
        const int cpair = idx >> 6, j = idx & 63;
        const float4 va = *(const float4*)(xr + gbase + (size_t)(2*cpair  )*HW_ + j*4);
        const float4 vb = *(const float4*)(xr + gbase + (size_t)(2*cpair+1)*HW_ + j*4);
        const float* fa = (const float*)&va;
        const float* fb = (const float*)&vb;
        #pragma unroll
        for (int t = 0; t < 4; ++t) {
            const int px = j*4 + t;
            Xs32[px*32 + (((cpair>>2) ^ (px&7))<<2) + (cpair&3)] = pack2(fa[t], fb[t]);
        }
    }
    __syncthreads();
    {
        const int px = tid;
        float sum = 0.f, ssq = 0.f;
        #pragma unroll
        for (int c8 = 0; c8 < 8; ++c8) {
            const u32* wp = &Xs32[px*32 + ((c8 ^ (px&7))<<2)];
            #pragma unroll
            for (int q = 0; q < 4; ++q) {
                float a = blo(wp[q]), b = bhi(wp[q]);
                sum += a + b; ssq += a*a + b*b;
            }
        }
        float mu = sum * (1.f/64.f);
        float var = ssq * (1.f/64.f) - mu*mu;
        muA[px] = mu;
        rsA[px] = rsqrtf(var + 1e-6f);
    }
    __syncthreads();
    {   // GEMM right: Qr (LN-folded) and Vr (raw + bias), shared B-frags
        float Sv[4], Bv[4], Vb[4];
        #pragma unroll
        for (int r = 0; r < 4; ++r) {
            Sv[r] = SrA[wv*16 + kg*4 + r];
            Bv[r] = BrA[wv*16 + kg*4 + r];
            Vb[r] = BvA[wv*16 + kg*4 + r];
        }
        #pragma unroll
        for (int nt = 0; nt < 16; ++nt) {
            const int px = nt*16 + l15;
            f32x4 dq = {0.f,0.f,0.f,0.f};
            f32x4 dv = {0.f,0.f,0.f,0.f};
            #pragma unroll
            for (int hf = 0; hf < 2; ++hf) {
                bf16x8 b = *(const bf16x8*)&Xs32[px*32 + (((hf*4+kg) ^ (px&7))<<2)];
                dq = __builtin_amdgcn_mfma_f32_16x16x32_bf16(aR[hf], b, dq, 0, 0, 0);
                dv = __builtin_amdgcn_mfma_f32_16x16x32_bf16(aV[hf], b, dv, 0, 0, 0);
            }
            const float mu = muA[px], rs = rsA[px];
            uint2 pq, pw;
            pq.x = pack2(rs*(dq[0] - mu*Sv[0]) + Bv[0], rs*(dq[1] - mu*Sv[1]) + Bv[1]);
            pq.y = pack2(rs*(dq[2] - mu*Sv[2]) + Bv[2], rs*(dq[3] - mu*Sv[3]) + Bv[3]);
            pw.x = pack2(dv[0] + Vb[0], dv[1] + Vb[1]);
            pw.y = pack2(dv[2] + Vb[2], dv[3] + Vb[3]);
            *(uint2*)&Qr[(rowb + px)*32 + wv*8 + kg*2] = pq;
            *(uint2*)&Vr[(rowb + px)*32 + wv*8 + kg*2] = pw;
        }
    }
}

// ---------------------------------------------------------------------------
// K2: per-scanline cross attention via MFMA (unchanged, validated).
// ---------------------------------------------------------------------------
__global__ __launch_bounds__(256, 2) void k_attn(
    const u32* __restrict__ Ql, const u32* __restrict__ Qr, const u32* __restrict__ Vr,
    const float* __restrict__ xl, const float* __restrict__ beta,
    float* __restrict__ out)
{
    __shared__ uint4 Ks[2048];      // 32 KB  [key][chunk16 ^ (key&7)]
    __shared__ u16  Vts[16384];     // 32 KB  V^T [ch][key], chunk ^ (ch&7)
    __shared__ u32  Pscr[4096];     // 16 KB  per-wave 1024 u32
    const int tid  = threadIdx.x;
    const int lane = tid & 63, wv = tid >> 6;
    const int l15  = lane & 15, kg = lane >> 4;
    const int blk  = blockIdx.x;
    const int n = blk >> 7, h = blk & 127;
    const size_t rowb = (size_t)blk*256;

    for (int it = tid; it < 2048; it += 256) {
        int key = it >> 3, c = it & 7;
        uint4 v = *(const uint4*)(Qr + (rowb + key)*32 + c*4);
        Ks[key*8 + (c ^ (key & 7))] = v;
    }
    for (int it = tid; it < 2048; it += 256) {
        int key = it & 255, j = it >> 8;
        uint4 v = *(const uint4*)(Vr + (rowb + key)*32 + j*4);
        const u32* vw = (const u32*)&v;
        #pragma unroll
        for (int t = 0; t < 8; ++t) {
            int ch = j*8 + t;
            u32 wd = vw[t >> 1];
            u16 hv = (t & 1) ? (u16)(wd >> 16) : (u16)(wd & 0xffffu);
            Vts[ch*256 + ((key >> 3) ^ (ch & 7))*8 + (key & 7)] = hv;
        }
    }

    const int q0 = wv*64;
    bf16x8 qf[4][2];
    #pragma unroll
    for (int nt = 0; nt < 4; ++nt)
        #pragma unroll
        for (int ci = 0; ci < 2; ++ci)
            qf[nt][ci] = *(const bf16x8*)(Ql + (rowb + q0 + nt*16 + l15)*32 + ci*16 + kg*4);

    f32x4 oacc[4][4];
    #pragma unroll
    for (int a = 0; a < 4; ++a)
        #pragma unroll
        for (int b = 0; b < 4; ++b)
            oacc[a][b] = (f32x4){0.f,0.f,0.f,0.f};
    float lsum[4] = {0.f,0.f,0.f,0.f};
    u32* Pw = &Pscr[wv*1024];

    __syncthreads();

    for (int kb = 0; kb < 8; ++kb) {
        f32x4 st[2][4];
        #pragma unroll
        for (int mt = 0; mt < 2; ++mt)
            #pragma unroll
            for (int nt = 0; nt < 4; ++nt)
                st[mt][nt] = (f32x4){0.f,0.f,0.f,0.f};
        #pragma unroll
        for (int ci = 0; ci < 2; ++ci) {
            bf16x8 a0 = *(const bf16x8*)&Ks[(kb*32 +      l15)*8 + ((ci*4 + kg) ^ (l15 & 7))];
            bf16x8 a1 = *(const bf16x8*)&Ks[(kb*32 + 16 + l15)*8 + ((ci*4 + kg) ^ (l15 & 7))];
            #pragma unroll
            for (int nt = 0; nt < 4; ++nt) {
                st[0][nt] = __builtin_amdgcn_mfma_f32_16x16x32_bf16(a0, qf[nt][ci], st[0][nt], 0, 0, 0);
                st[1][nt] = __builtin_amdgcn_mfma_f32_16x16x32_bf16(a1, qf[nt][ci], st[1][nt], 0, 0, 0);
            }
        }
        #pragma unroll
        for (int nt = 0; nt < 4; ++nt) {
            const int q = nt*16 + l15;
            #pragma unroll
            for (int mt = 0; mt < 2; ++mt) {
                float p0 = __expf(st[mt][nt][0]*0.125f);
                float p1 = __expf(st[mt][nt][1]*0.125f);
                float p2 = __expf(st[mt][nt][2]*0.125f);
                float p3 = __expf(st[mt][nt][3]*0.125f);
                lsum[nt] += (p0+p1)+(p2+p3);
                u32 pr0, pr1;
                asm("v_cvt_pk_bf16_f32 %0, %1, %2" : "=v"(pr0) : "v"(p0), "v"(p1));
                asm("v_cvt_pk_bf16_f32 %0, %1, %2" : "=v"(pr1) : "v"(p2), "v"(p3));
                const int c16 = (2*mt + (kg >> 1)) ^ (q & 3);
                uint2 pv; pv.x = pr0; pv.y = pr1;
                *(uint2*)&Pw[q*16 + c16*4 + (kg & 1)*2] = pv;
            }
        }
        asm volatile("s_waitcnt lgkmcnt(0)" ::: "memory");
        bf16x8 vb[4];
        #pragma unroll
        for (int nc = 0; nc < 4; ++nc)
            vb[nc] = *(const bf16x8*)&Vts[(nc*16 + l15)*256 + ((kb*4 + kg) ^ (l15 & 7))*8];
        #pragma unroll
        for (int qt = 0; qt < 4; ++qt) {
            const int q = qt*16 + l15;
            bf16x8 pa = *(const bf16x8*)&Pw[q*16 + (kg ^ (q & 3))*4];
            #pragma unroll
            for (int nc = 0; nc < 4; ++nc)
                oacc[qt][nc] = __builtin_amdgcn_mfma_f32_16x16x32_bf16(pa, vb[nc], oacc[qt][nc], 0, 0, 0);
        }
    }

    #pragma unroll
    for (int nt = 0; nt < 4; ++nt) {
        float s = lsum[nt];
        s += __shfl_xor(s, 16, 64);
        s += __shfl_xor(s, 32, 64);
        lsum[nt] = s;
    }
    float linv[4][4];
    #pragma unroll
    for (int qt = 0; qt < 4; ++qt)
        #pragma unroll
        for (int r = 0; r < 4; ++r)
            linv[qt][r] = 1.0f / __shfl(lsum[qt], kg*4 + r, 64);

    float* PwF = (float*)Pw;
    const size_t obase = (size_t)n*CHW_ + (size_t)h*W_ + q0;
    #pragma unroll
    for (int nc = 0; nc < 4; ++nc) {
        asm volatile("s_waitcnt lgkmcnt(0)" ::: "memory");
        #pragma unroll
        for (int qt = 0; qt < 4; ++qt) {
            f32x4 vals;
            vals[0] = oacc[qt][nc][0]*linv[qt][0];
            vals[1] = oacc[qt][nc][1]*linv[qt][1];
            vals[2] = oacc[qt][nc][2]*linv[qt][2];
            vals[3] = oacc[qt][nc][3]*linv[qt][3];
            *(f32x4*)&PwF[l15*64 + ((qt*4 + kg) ^ l15)*4] = vals;
        }
        asm volatile("s_waitcnt lgkmcnt(0)" ::: "memory");
        #pragma unroll
        for (int chl = 0; chl < 16; ++chl) {
            const int ch = nc*16 + chl;
            float v = PwF[chl*64 + ((lane >> 2) ^ chl)*4 + (lane & 3)];
            size_t gidx = obase + (size_t)ch*HW_ + lane;
            out[gidx] = xl[gidx] + beta[ch]*v;
        }
    }
}

// ---------------------------------------------------------------------------
// K3: T_t[n][h][w][c] = highpass(x_r), bf16, channel-contiguous (unchanged).
// ---------------------------------------------------------------------------
__global__ __launch_bounds__(256) void k_hipass(
    const float* __restrict__ xr, u16* __restrict__ Tt)
{
    const int blk = blockIdx.x;            // n*128 + h
    const int n = blk >> 7, h = blk & 127;
    const int w = threadIdx.x;
    const bool wok0 = (w > 0), wok1 = (w < 255);
    const size_t base = (size_t)n*CHW_ + (size_t)h*W_ + w;
    uint4* outp = (uint4*)(Tt + ((size_t)blk*256 + w)*64);

    for (int c0 = 0; c0 < 64; c0 += 8) {
        u32 pk[4];
        #pragma unroll
        for (int cp = 0; cp < 4; ++cp) {
            float tv[2];
            #pragma unroll
            for (int cc = 0; cc < 2; ++cc) {
                const float* p = xr + base + (size_t)(c0 + cp*2 + cc)*HW_;
                float s = 0.f, ctr = 0.f;
                #pragma unroll
                for (int dy = -1; dy <= 1; ++dy) {
                    int hh = h + dy;
                    if (hh < 0 || hh > 127) continue;
                    const float* row = p + dy*256;
                    float a = wok0 ? row[-1] : 0.f;
                    float b = row[0];
                    float c = wok1 ? row[1]  : 0.f;
                    if (dy == 0) ctr = b;
                    s += a + b + c;
                }
                tv[cc] = ctr - s*(1.f/9.f);
            }
            pk[cp] = pack2(tv[0], tv[1]);
        }
        uint4 v; v.x = pk[0]; v.y = pk[1]; v.z = pk[2]; v.w = pk[3];
        outp[c0 >> 3] = v;
    }
}

// ---------------------------------------------------------------------------
// K4: conv3x3 as MFMA GEMM (unchanged, validated).
// ---------------------------------------------------------------------------
__global__ __launch_bounds__(256) void k_conv(
    const u16* __restrict__ Tt, const float* __restrict__ Whf,
    const float* __restrict__ bhf, const float* __restrict__ gam,
    float* __restrict__ out)
{
    __shared__ uint4 Xs[3*66*8];           // 25344 B, [dy][wt][chunk^(wt&7)]
    const int tid  = threadIdx.x;
    const int lane = tid & 63;
    const int mt   = tid >> 6;
    const int l15  = lane & 15;
    const int kg   = lane >> 4;
    const int blk  = blockIdx.x;           // n*128 + h
    const int n = blk >> 7, h = blk & 127;

    const int oa = mt*16 + l15;
    bf16x8 A[18];
    #pragma unroll
    for (int s = 0; s < 18; ++s) {
        const int q  = s >> 1;
        const int ib = (s & 1)*32 + kg*8;
        bf16x8 a;
        #pragma unroll
        for (int j = 0; j < 8; ++j) {
            float wv = Whf[(size_t)(oa*64 + ib + j)*9 + q];
            a[j] = (short)f2bf(wv);
        }
        A[s] = a;
    }
    float gv[4], bv[4];
    #pragma unroll
    for (int r = 0; r < 4; ++r) {
        int oo = mt*16 + kg*4 + r;
        gv[r] = gam[oo];
        bv[r] = bhf[oo];
    }

    for (int t4 = 0; t4 < 4; ++t4) {
        const int w0 = t4*64;
        __syncthreads();
        for (int it = tid; it < 1584; it += 256) {
            int dy    = it / 528;
            int rem   = it - dy*528;
            int wt    = rem >> 3;
            int chunk = rem & 7;
            int hh = h + dy - 1;
            int wg = w0 + wt - 1;
            uint4 v = {0,0,0,0};
            if (hh >= 0 && hh < 128 && wg >= 0 && wg < 256)
                v = *(const uint4*)(Tt + (((size_t)(n*128 + hh)*256 + wg)*64 + chunk*8));
            Xs[(dy*66 + wt)*8 + (chunk ^ (wt & 7))] = v;
        }
        __syncthreads();

        f32x4 acc[4] = {{0,0,0,0},{0,0,0,0},{0,0,0,0},{0,0,0,0}};
        #pragma unroll
        for (int s = 0; s < 18; ++s) {
            const int q  = s >> 1;
            const int dy = q / 3, dx = q % 3;
            const int c0 = (s & 1)*4 + kg;
            #pragma unroll
            for (int nt = 0; nt < 4; ++nt) {
                const int wt = nt*16 + l15 + dx;
                bf16x8 b = *(const bf16x8*)&Xs[(dy*66 + wt)*8 + (c0 ^ (wt & 7))];
                acc[nt] = __builtin_amdgcn_mfma_f32_16x16x32_bf16(A[s], b, acc[nt], 0, 0, 0);
            }
        }
        #pragma unroll
        for (int nt = 0; nt < 4; ++nt) {
            const int px = w0 + nt*16 + l15;
            #pragma unroll
            for (int r = 0; r < 4; ++r) {
                const int oo = mt*16 + kg*4 + r;
                size_t idx = (size_t)(n*64 + oo)*HW_ + (size_t)h*W_ + px;
                out[idx] += gv[r]*(acc[nt][r] + bv[r]);
            }
        }
    }
}

extern "C" void kernel_launch(void* const* d_in, const int* in_sizes, int n_in,
                              void* d_out, int out_size, void* d_ws, size_t ws_size,
                              hipStream_t stream)
{
    const float* xl   = (const float*)d_in[0];
    const float* xr   = (const float*)d_in[1];
    const float* nlw  = (const float*)d_in[2];
    const float* nlb  = (const float*)d_in[3];
    const float* nrw  = (const float*)d_in[4];
    const float* nrb  = (const float*)d_in[5];
    const float* Wql  = (const float*)d_in[6];
    const float* bql  = (const float*)d_in[7];
    const float* Wqr  = (const float*)d_in[8];
    const float* bqr  = (const float*)d_in[9];
    const float* Wvr  = (const float*)d_in[10];
    const float* bvr  = (const float*)d_in[11];
    const float* beta = (const float*)d_in[12];
    const float* gam  = (const float*)d_in[13];
    const float* Whf  = (const float*)d_in[14];
    const float* bhf  = (const float*)d_in[15];
    float* out = (float*)d_out;

    u32* Ql = (u32*)d_ws;
    u32* Qr = Ql + 8388608;
    u32* Vr = Qr + 8388608;
    u16* Tt = (u16*)(Vr + 8388608);

    k_proj<<<1024, 256, 0, stream>>>(xl, xr, nlw, nlb, nrw, nrb,
                                     Wql, bql, Wqr, bqr, Wvr, bvr, Ql, Qr, Vr);
    k_hipass<<<1024, 256, 0, stream>>>(xr, Tt);
    k_attn<<<1024, 256, 0, stream>>>(Ql, Qr, Vr, xl, beta, out);
    k_conv<<<1024, 256, 0, stream>>>(Tt, Whf, bhf, gam, out);
}

// Round 6
// 303.140 us; speedup vs baseline: 5.1077x; 1.0606x over previous
//
#include <hip/hip_runtime.h>
#include <hip/hip_bf16.h>

#define N_ 8
#define C_ 64
#define H_ 128
#define W_ 256
#define HW_ (H_*W_)        // 32768
#define CHW_ (C_*H_*W_)    // 2097152

typedef unsigned int u32;
typedef unsigned short u16;
typedef float f32x4 __attribute__((ext_vector_type(4)));
typedef short bf16x8 __attribute__((ext_vector_type(8)));

__device__ __forceinline__ float blo(u32 u) { return __uint_as_float(u << 16); }
__device__ __forceinline__ float bhi(u32 u) { return __uint_as_float(u & 0xffff0000u); }
__device__ __forceinline__ u16 f2bf(float f) {
    u32 u = __float_as_uint(f);
    u32 lsb = (u >> 16) & 1u;
    u += 0x7fffu + lsb;
    return (u16)(u >> 16);
}
__device__ __forceinline__ u32 pack2(float a, float b) {
    return (u32)f2bf(a) | ((u32)f2bf(b) << 16);
}

// ---------------------------------------------------------------------------
// K1: LayerNorm + 1x1 conv projections via MFMA (unchanged, validated).
// ---------------------------------------------------------------------------
__global__ __launch_bounds__(256) void k_proj(
    const float* __restrict__ xl, const float* __restrict__ xr,
    const float* __restrict__ nlw, const float* __restrict__ nlb,
    const float* __restrict__ nrw, const float* __restrict__ nrb,
    const float* __restrict__ Wql, const float* __restrict__ bql,
    const float* __restrict__ Wqr, const float* __restrict__ bqr,
    const float* __restrict__ Wvr, const float* __restrict__ bvr,
    u32* __restrict__ Ql, u32* __restrict__ Qr, u32* __restrict__ Vr)
{
    __shared__ u32 Xs32[256*32];       // 32 KB  [px][cpair], 16B-chunk swizzled
    __shared__ float muA[256], rsA[256];
    __shared__ float SlA[64], BlA[64], SrA[64], BrA[64], BvA[64];
    const int tid  = threadIdx.x;
    const int lane = tid & 63, wv = tid >> 6;
    const int l15  = lane & 15, kg = lane >> 4;
    const int blk  = blockIdx.x;       // n*128 + h
    const int n = blk >> 7, h = blk & 127;
    const size_t gbase = (size_t)n*CHW_ + (size_t)h*W_;   // + c*HW_ + px
    const size_t rowb  = (size_t)blk*256;

    if (tid < 64) {
        const int o = tid;
        float sl = 0.f, bl = bql[o], sr = 0.f, br = bqr[o];
        for (int c = 0; c < 64; ++c) {
            float wl = Wql[o*64+c], wr = Wqr[o*64+c];
            sl += wl * nlw[c];
            bl += wl * nlb[c];
            sr += wr * nrw[c];
            br += wr * nrb[c];
        }
        SlA[o] = sl; BlA[o] = bl; SrA[o] = sr; BrA[o] = br; BvA[o] = bvr[o];
    }

    const int oA = wv*16 + l15;
    bf16x8 aL[2], aR[2], aV[2];
    #pragma unroll
    for (int hf = 0; hf < 2; ++hf) {
        bf16x8 tl, tr, tv;
        #pragma unroll
        for (int j = 0; j < 8; ++j) {
            const int c = hf*32 + kg*8 + j;
            tl[j] = (short)f2bf(Wql[oA*64+c] * nlw[c]);
            tr[j] = (short)f2bf(Wqr[oA*64+c] * nrw[c]);
            tv[j] = (short)f2bf(Wvr[oA*64+c]);
        }
        aL[hf] = tl; aR[hf] = tr; aV[hf] = tv;
    }

    // ================= LEFT =================
    for (int idx = tid; idx < 2048; idx += 256) {
        const int cpair = idx >> 6, j = idx & 63;
        const float4 va = *(const float4*)(xl + gbase + (size_t)(2*cpair  )*HW_ + j*4);
        const float4 vb = *(const float4*)(xl + gbase + (size_t)(2*cpair+1)*HW_ + j*4);
        const float* fa = (const float*)&va;
        const float* fb = (const float*)&vb;
        #pragma unroll
        for (int t = 0; t < 4; ++t) {
            const int px = j*4 + t;
            Xs32[px*32 + (((cpair>>2) ^ (px&7))<<2) + (cpair&3)] = pack2(fa[t], fb[t]);
        }
    }
    __syncthreads();
    {
        const int px = tid;
        float sum = 0.f, ssq = 0.f;
        #pragma unroll
        for (int c8 = 0; c8 < 8; ++c8) {
            const u32* wp = &Xs32[px*32 + ((c8 ^ (px&7))<<2)];
            #pragma unroll
            for (int q = 0; q < 4; ++q) {
                float a = blo(wp[q]), b = bhi(wp[q]);
                sum += a + b; ssq += a*a + b*b;
            }
        }
        float mu = sum * (1.f/64.f);
        float var = ssq * (1.f/64.f) - mu*mu;
        muA[px] = mu;
        rsA[px] = rsqrtf(var + 1e-6f);
    }
    __syncthreads();
    {
        float Sv[4], Bv[4];
        #pragma unroll
        for (int r = 0; r < 4; ++r) {
            Sv[r] = SlA[wv*16 + kg*4 + r];
            Bv[r] = BlA[wv*16 + kg*4 + r];
        }
        #pragma unroll
        for (int nt = 0; nt < 16; ++nt) {
            const int px = nt*16 + l15;
            f32x4 d = {0.f,0.f,0.f,0.f};
            #pragma unroll
            for (int hf = 0; hf < 2; ++hf) {
                bf16x8 b = *(const bf16x8*)&Xs32[px*32 + (((hf*4+kg) ^ (px&7))<<2)];
                d = __builtin_amdgcn_mfma_f32_16x16x32_bf16(aL[hf], b, d, 0, 0, 0);
            }
            const float mu = muA[px], rs = rsA[px];
            uint2 pv;
            pv.x = pack2(rs*(d[0] - mu*Sv[0]) + Bv[0], rs*(d[1] - mu*Sv[1]) + Bv[1]);
            pv.y = pack2(rs*(d[2] - mu*Sv[2]) + Bv[2], rs*(d[3] - mu*Sv[3]) + Bv[3]);
            *(uint2*)&Ql[(rowb + px)*32 + wv*8 + kg*2] = pv;
        }
    }
    __syncthreads();

    // ================= RIGHT =================
    for (int idx = tid; idx < 2048; idx += 256) {
        const int cpair = idx >> 6, j = idx & 63;
        const float4 va = *(const float4*)(xr + gbase + (size_t)(2*cpair  )*HW_ + j*4);
        const float4 vb = *(const float4*)(xr + gbase + (size_t)(2*cpair+1)*HW_ + j*4);
        const float* fa = (const float*)&va;
        const float* fb = (const float*)&vb;
        #pragma unroll
        for (int t = 0; t < 4; ++t) {
            const int px = j*4 + t;
            Xs32[px*32 + (((cpair>>2) ^ (px&7))<<2) + (cpair&3)] = pack2(fa[t], fb[t]);
        }
    }
    __syncthreads();
    {
        const int px = tid;
        float sum = 0.f, ssq = 0.f;
        #pragma unroll
        for (int c8 = 0; c8 < 8; ++c8) {
            const u32* wp = &Xs32[px*32 + ((c8 ^ (px&7))<<2)];
            #pragma unroll
            for (int q = 0; q < 4; ++q) {
                float a = blo(wp[q]), b = bhi(wp[q]);
                sum += a + b; ssq += a*a + b*b;
            }
        }
        float mu = sum * (1.f/64.f);
        float var = ssq * (1.f/64.f) - mu*mu;
        muA[px] = mu;
        rsA[px] = rsqrtf(var + 1e-6f);
    }
    __syncthreads();
    {
        float Sv[4], Bv[4], Vb[4];
        #pragma unroll
        for (int r = 0; r < 4; ++r) {
            Sv[r] = SrA[wv*16 + kg*4 + r];
            Bv[r] = BrA[wv*16 + kg*4 + r];
            Vb[r] = BvA[wv*16 + kg*4 + r];
        }
        #pragma unroll
        for (int nt = 0; nt < 16; ++nt) {
            const int px = nt*16 + l15;
            f32x4 dq = {0.f,0.f,0.f,0.f};
            f32x4 dv = {0.f,0.f,0.f,0.f};
            #pragma unroll
            for (int hf = 0; hf < 2; ++hf) {
                bf16x8 b = *(const bf16x8*)&Xs32[px*32 + (((hf*4+kg) ^ (px&7))<<2)];
                dq = __builtin_amdgcn_mfma_f32_16x16x32_bf16(aR[hf], b, dq, 0, 0, 0);
                dv = __builtin_amdgcn_mfma_f32_16x16x32_bf16(aV[hf], b, dv, 0, 0, 0);
            }
            const float mu = muA[px], rs = rsA[px];
            uint2 pq, pw;
            pq.x = pack2(rs*(dq[0] - mu*Sv[0]) + Bv[0], rs*(dq[1] - mu*Sv[1]) + Bv[1]);
            pq.y = pack2(rs*(dq[2] - mu*Sv[2]) + Bv[2], rs*(dq[3] - mu*Sv[3]) + Bv[3]);
            pw.x = pack2(dv[0] + Vb[0], dv[1] + Vb[1]);
            pw.y = pack2(dv[2] + Vb[2], dv[3] + Vb[3]);
            *(uint2*)&Qr[(rowb + px)*32 + wv*8 + kg*2] = pq;
            *(uint2*)&Vr[(rowb + px)*32 + wv*8 + kg*2] = pw;
        }
    }
}

// ---------------------------------------------------------------------------
// K2: per-scanline cross attention via MFMA (unchanged, validated).
// ---------------------------------------------------------------------------
__global__ __launch_bounds__(256, 2) void k_attn(
    const u32* __restrict__ Ql, const u32* __restrict__ Qr, const u32* __restrict__ Vr,
    const float* __restrict__ xl, const float* __restrict__ beta,
    float* __restrict__ out)
{
    __shared__ uint4 Ks[2048];      // 32 KB  [key][chunk16 ^ (key&7)]
    __shared__ u16  Vts[16384];     // 32 KB  V^T [ch][key], chunk ^ (ch&7)
    __shared__ u32  Pscr[4096];     // 16 KB  per-wave 1024 u32
    const int tid  = threadIdx.x;
    const int lane = tid & 63, wv = tid >> 6;
    const int l15  = lane & 15, kg = lane >> 4;
    const int blk  = blockIdx.x;
    const int n = blk >> 7, h = blk & 127;
    const size_t rowb = (size_t)blk*256;

    for (int it = tid; it < 2048; it += 256) {
        int key = it >> 3, c = it & 7;
        uint4 v = *(const uint4*)(Qr + (rowb + key)*32 + c*4);
        Ks[key*8 + (c ^ (key & 7))] = v;
    }
    for (int it = tid; it < 2048; it += 256) {
        int key = it & 255, j = it >> 8;
        uint4 v = *(const uint4*)(Vr + (rowb + key)*32 + j*4);
        const u32* vw = (const u32*)&v;
        #pragma unroll
        for (int t = 0; t < 8; ++t) {
            int ch = j*8 + t;
            u32 wd = vw[t >> 1];
            u16 hv = (t & 1) ? (u16)(wd >> 16) : (u16)(wd & 0xffffu);
            Vts[ch*256 + ((key >> 3) ^ (ch & 7))*8 + (key & 7)] = hv;
        }
    }

    const int q0 = wv*64;
    bf16x8 qf[4][2];
    #pragma unroll
    for (int nt = 0; nt < 4; ++nt)
        #pragma unroll
        for (int ci = 0; ci < 2; ++ci)
            qf[nt][ci] = *(const bf16x8*)(Ql + (rowb + q0 + nt*16 + l15)*32 + ci*16 + kg*4);

    f32x4 oacc[4][4];
    #pragma unroll
    for (int a = 0; a < 4; ++a)
        #pragma unroll
        for (int b = 0; b < 4; ++b)
            oacc[a][b] = (f32x4){0.f,0.f,0.f,0.f};
    float lsum[4] = {0.f,0.f,0.f,0.f};
    u32* Pw = &Pscr[wv*1024];

    __syncthreads();

    for (int kb = 0; kb < 8; ++kb) {
        f32x4 st[2][4];
        #pragma unroll
        for (int mt = 0; mt < 2; ++mt)
            #pragma unroll
            for (int nt = 0; nt < 4; ++nt)
                st[mt][nt] = (f32x4){0.f,0.f,0.f,0.f};
        #pragma unroll
        for (int ci = 0; ci < 2; ++ci) {
            bf16x8 a0 = *(const bf16x8*)&Ks[(kb*32 +      l15)*8 + ((ci*4 + kg) ^ (l15 & 7))];
            bf16x8 a1 = *(const bf16x8*)&Ks[(kb*32 + 16 + l15)*8 + ((ci*4 + kg) ^ (l15 & 7))];
            #pragma unroll
            for (int nt = 0; nt < 4; ++nt) {
                st[0][nt] = __builtin_amdgcn_mfma_f32_16x16x32_bf16(a0, qf[nt][ci], st[0][nt], 0, 0, 0);
                st[1][nt] = __builtin_amdgcn_mfma_f32_16x16x32_bf16(a1, qf[nt][ci], st[1][nt], 0, 0, 0);
            }
        }
        #pragma unroll
        for (int nt = 0; nt < 4; ++nt) {
            const int q = nt*16 + l15;
            #pragma unroll
            for (int mt = 0; mt < 2; ++mt) {
                float p0 = __expf(st[mt][nt][0]*0.125f);
                float p1 = __expf(st[mt][nt][1]*0.125f);
                float p2 = __expf(st[mt][nt][2]*0.125f);
                float p3 = __expf(st[mt][nt][3]*0.125f);
                lsum[nt] += (p0+p1)+(p2+p3);
                u32 pr0, pr1;
                asm("v_cvt_pk_bf16_f32 %0, %1, %2" : "=v"(pr0) : "v"(p0), "v"(p1));
                asm("v_cvt_pk_bf16_f32 %0, %1, %2" : "=v"(pr1) : "v"(p2), "v"(p3));
                const int c16 = (2*mt + (kg >> 1)) ^ (q & 3);
                uint2 pv; pv.x = pr0; pv.y = pr1;
                *(uint2*)&Pw[q*16 + c16*4 + (kg & 1)*2] = pv;
            }
        }
        asm volatile("s_waitcnt lgkmcnt(0)" ::: "memory");
        bf16x8 vb[4];
        #pragma unroll
        for (int nc = 0; nc < 4; ++nc)
            vb[nc] = *(const bf16x8*)&Vts[(nc*16 + l15)*256 + ((kb*4 + kg) ^ (l15 & 7))*8];
        #pragma unroll
        for (int qt = 0; qt < 4; ++qt) {
            const int q = qt*16 + l15;
            bf16x8 pa = *(const bf16x8*)&Pw[q*16 + (kg ^ (q & 3))*4];
            #pragma unroll
            for (int nc = 0; nc < 4; ++nc)
                oacc[qt][nc] = __builtin_amdgcn_mfma_f32_16x16x32_bf16(pa, vb[nc], oacc[qt][nc], 0, 0, 0);
        }
    }

    #pragma unroll
    for (int nt = 0; nt < 4; ++nt) {
        float s = lsum[nt];
        s += __shfl_xor(s, 16, 64);
        s += __shfl_xor(s, 32, 64);
        lsum[nt] = s;
    }
    float linv[4][4];
    #pragma unroll
    for (int qt = 0; qt < 4; ++qt)
        #pragma unroll
        for (int r = 0; r < 4; ++r)
            linv[qt][r] = 1.0f / __shfl(lsum[qt], kg*4 + r, 64);

    float* PwF = (float*)Pw;
    const size_t obase = (size_t)n*CHW_ + (size_t)h*W_ + q0;
    #pragma unroll
    for (int nc = 0; nc < 4; ++nc) {
        asm volatile("s_waitcnt lgkmcnt(0)" ::: "memory");
        #pragma unroll
        for (int qt = 0; qt < 4; ++qt) {
            f32x4 vals;
            vals[0] = oacc[qt][nc][0]*linv[qt][0];
            vals[1] = oacc[qt][nc][1]*linv[qt][1];
            vals[2] = oacc[qt][nc][2]*linv[qt][2];
            vals[3] = oacc[qt][nc][3]*linv[qt][3];
            *(f32x4*)&PwF[l15*64 + ((qt*4 + kg) ^ l15)*4] = vals;
        }
        asm volatile("s_waitcnt lgkmcnt(0)" ::: "memory");
        #pragma unroll
        for (int chl = 0; chl < 16; ++chl) {
            const int ch = nc*16 + chl;
            float v = PwF[chl*64 + ((lane >> 2) ^ chl)*4 + (lane & 3)];
            size_t gidx = obase + (size_t)ch*HW_ + lane;
            out[gidx] = xl[gidx] + beta[ch]*v;
        }
    }
}

// ---------------------------------------------------------------------------
// K3: T_t[n][h][w][c] = highpass(x_r), bf16, channel-contiguous.
// Coalesced output via 32KB LDS round-trip (XOR-swizzled 16B chunks);
// XCD-chunked block swizzle so halo rows are same-XCD L2 hits.
// ---------------------------------------------------------------------------
__global__ __launch_bounds__(256) void k_hipass(
    const float* __restrict__ xr, u16* __restrict__ Tt)
{
    __shared__ uint4 Ts[256*8];            // 32 KB [px][chunk ^ (px&7)]
    const int bid = blockIdx.x;
    const int blk = (bid & 7)*128 + (bid >> 3);   // XCD chunk: 128 rows/XCD
    const int h = blk & 127;
    const int tid = threadIdx.x;
    const int w = tid;
    const bool wok0 = (w > 0), wok1 = (w < 255);
    const size_t base = (size_t)blk*256 + w;      // == n*CHW + h*W + w (C folded: blk=(n*128+h), c stride HW_)

    for (int c0 = 0; c0 < 64; c0 += 8) {
        u32 pk[4];
        #pragma unroll
        for (int cp = 0; cp < 4; ++cp) {
            float tv[2];
            #pragma unroll
            for (int cc = 0; cc < 2; ++cc) {
                const float* p = xr + ((size_t)(blk >> 7)*CHW_ + (size_t)(blk & 127)*W_ + w) + (size_t)(c0 + cp*2 + cc)*HW_;
                float s = 0.f, ctr = 0.f;
                #pragma unroll
                for (int dy = -1; dy <= 1; ++dy) {
                    int hh = h + dy;
                    if (hh < 0 || hh > 127) continue;
                    const float* row = p + dy*256;
                    float a = wok0 ? row[-1] : 0.f;
                    float b = row[0];
                    float c = wok1 ? row[1]  : 0.f;
                    if (dy == 0) ctr = b;
                    s += a + b + c;
                }
                tv[cc] = ctr - s*(1.f/9.f);
            }
            pk[cp] = pack2(tv[0], tv[1]);
        }
        uint4 v; v.x = pk[0]; v.y = pk[1]; v.z = pk[2]; v.w = pk[3];
        Ts[w*8 + ((c0 >> 3) ^ (w & 7))] = v;
    }
    __syncthreads();
    // coalesced copy-out: consecutive tid -> consecutive 16B
    uint4* gout = (uint4*)(Tt + (size_t)blk*256*64);
    #pragma unroll
    for (int iter = 0; iter < 8; ++iter) {
        int lin = iter*256 + tid;
        int px = lin >> 3, ch = lin & 7;
        gout[lin] = Ts[px*8 + (ch ^ (px & 7))];
    }
}

// ---------------------------------------------------------------------------
// K4: conv3x3 as MFMA GEMM (validated) + XCD-chunked block swizzle.
// ---------------------------------------------------------------------------
__global__ __launch_bounds__(256) void k_conv(
    const u16* __restrict__ Tt, const float* __restrict__ Whf,
    const float* __restrict__ bhf, const float* __restrict__ gam,
    float* __restrict__ out)
{
    __shared__ uint4 Xs[3*66*8];           // 25344 B, [dy][wt][chunk^(wt&7)]
    const int tid  = threadIdx.x;
    const int lane = tid & 63;
    const int mt   = tid >> 6;
    const int l15  = lane & 15;
    const int kg   = lane >> 4;
    const int bid  = blockIdx.x;
    const int blk  = (bid & 7)*128 + (bid >> 3);   // XCD chunk swizzle
    const int n = blk >> 7, h = blk & 127;

    const int oa = mt*16 + l15;
    bf16x8 A[18];
    #pragma unroll
    for (int s = 0; s < 18; ++s) {
        const int q  = s >> 1;
        const int ib = (s & 1)*32 + kg*8;
        bf16x8 a;
        #pragma unroll
        for (int j = 0; j < 8; ++j) {
            float wv = Whf[(size_t)(oa*64 + ib + j)*9 + q];
            a[j] = (short)f2bf(wv);
        }
        A[s] = a;
    }
    float gv[4], bv[4];
    #pragma unroll
    for (int r = 0; r < 4; ++r) {
        int oo = mt*16 + kg*4 + r;
        gv[r] = gam[oo];
        bv[r] = bhf[oo];
    }

    for (int t4 = 0; t4 < 4; ++t4) {
        const int w0 = t4*64;
        __syncthreads();
        for (int it = tid; it < 1584; it += 256) {
            int dy    = it / 528;
            int rem   = it - dy*528;
            int wt    = rem >> 3;
            int chunk = rem & 7;
            int hh = h + dy - 1;
            int wg = w0 + wt - 1;
            uint4 v = {0,0,0,0};
            if (hh >= 0 && hh < 128 && wg >= 0 && wg < 256)
                v = *(const uint4*)(Tt + (((size_t)(n*128 + hh)*256 + wg)*64 + chunk*8));
            Xs[(dy*66 + wt)*8 + (chunk ^ (wt & 7))] = v;
        }
        __syncthreads();

        f32x4 acc[4] = {{0,0,0,0},{0,0,0,0},{0,0,0,0},{0,0,0,0}};
        #pragma unroll
        for (int s = 0; s < 18; ++s) {
            const int q  = s >> 1;
            const int dy = q / 3, dx = q % 3;
            const int c0 = (s & 1)*4 + kg;
            #pragma unroll
            for (int nt = 0; nt < 4; ++nt) {
                const int wt = nt*16 + l15 + dx;
                bf16x8 b = *(const bf16x8*)&Xs[(dy*66 + wt)*8 + (c0 ^ (wt & 7))];
                acc[nt] = __builtin_amdgcn_mfma_f32_16x16x32_bf16(A[s], b, acc[nt], 0, 0, 0);
            }
        }
        #pragma unroll
        for (int nt = 0; nt < 4; ++nt) {
            const int px = w0 + nt*16 + l15;
            #pragma unroll
            for (int r = 0; r < 4; ++r) {
                const int oo = mt*16 + kg*4 + r;
                size_t idx = (size_t)(n*64 + oo)*HW_ + (size_t)h*W_ + px;
                out[idx] += gv[r]*(acc[nt][r] + bv[r]);
            }
        }
    }
}

extern "C" void kernel_launch(void* const* d_in, const int* in_sizes, int n_in,
                              void* d_out, int out_size, void* d_ws, size_t ws_size,
                              hipStream_t stream)
{
    const float* xl   = (const float*)d_in[0];
    const float* xr   = (const float*)d_in[1];
    const float* nlw  = (const float*)d_in[2];
    const float* nlb  = (const float*)d_in[3];
    const float* nrw  = (const float*)d_in[4];
    const float* nrb  = (const float*)d_in[5];
    const float* Wql  = (const float*)d_in[6];
    const float* bql  = (const float*)d_in[7];
    const float* Wqr  = (const float*)d_in[8];
    const float* bqr  = (const float*)d_in[9];
    const float* Wvr  = (const float*)d_in[10];
    const float* bvr  = (const float*)d_in[11];
    const float* beta = (const float*)d_in[12];
    const float* gam  = (const float*)d_in[13];
    const float* Whf  = (const float*)d_in[14];
    const float* bhf  = (const float*)d_in[15];
    float* out = (float*)d_out;

    u32* Ql = (u32*)d_ws;
    u32* Qr = Ql + 8388608;
    u32* Vr = Qr + 8388608;
    u16* Tt = (u16*)(Vr + 8388608);

    k_proj<<<1024, 256, 0, stream>>>(xl, xr, nlw, nlb, nrw, nrb,
                                     Wql, bql, Wqr, bqr, Wvr, bvr, Ql, Qr, Vr);
    k_hipass<<<1024, 256, 0, stream>>>(xr, Tt);
    k_attn<<<1024, 256, 0, stream>>>(Ql, Qr, Vr, xl, beta, out);
    k_conv<<<1024, 256, 0, stream>>>(Tt, Whf, bhf, gam, out);
}

// Round 7
// 239.438 us; speedup vs baseline: 6.4666x; 1.2660x over previous
//
#include <hip/hip_runtime.h>
#include <hip/hip_bf16.h>

#define N_ 8
#define C_ 64
#define H_ 128
#define W_ 256
#define HW_ (H_*W_)        // 32768
#define CHW_ (C_*H_*W_)    // 2097152

typedef unsigned int u32;
typedef unsigned short u16;
typedef float f32x4 __attribute__((ext_vector_type(4)));
typedef short bf16x8 __attribute__((ext_vector_type(8)));

__device__ __forceinline__ float blo(u32 u) { return __uint_as_float(u << 16); }
__device__ __forceinline__ float bhi(u32 u) { return __uint_as_float(u & 0xffff0000u); }
__device__ __forceinline__ u16 f2bf(float f) {
    u32 u = __float_as_uint(f);
    u32 lsb = (u >> 16) & 1u;
    u += 0x7fffu + lsb;
    return (u16)(u >> 16);
}
__device__ __forceinline__ u32 pack2(float a, float b) {
    return (u32)f2bf(a) | ((u32)f2bf(b) << 16);
}

// ---------------------------------------------------------------------------
// K1: LayerNorm + 1x1 conv projections via MFMA (unchanged, validated).
// ---------------------------------------------------------------------------
__global__ __launch_bounds__(256) void k_proj(
    const float* __restrict__ xl, const float* __restrict__ xr,
    const float* __restrict__ nlw, const float* __restrict__ nlb,
    const float* __restrict__ nrw, const float* __restrict__ nrb,
    const float* __restrict__ Wql, const float* __restrict__ bql,
    const float* __restrict__ Wqr, const float* __restrict__ bqr,
    const float* __restrict__ Wvr, const float* __restrict__ bvr,
    u32* __restrict__ Ql, u32* __restrict__ Qr, u32* __restrict__ Vr)
{
    __shared__ u32 Xs32[256*32];       // 32 KB  [px][cpair], 16B-chunk swizzled
    __shared__ float muA[256], rsA[256];
    __shared__ float SlA[64], BlA[64], SrA[64], BrA[64], BvA[64];
    const int tid  = threadIdx.x;
    const int lane = tid & 63, wv = tid >> 6;
    const int l15  = lane & 15, kg = lane >> 4;
    const int blk  = blockIdx.x;       // n*128 + h
    const int n = blk >> 7, h = blk & 127;
    const size_t gbase = (size_t)n*CHW_ + (size_t)h*W_;   // + c*HW_ + px
    const size_t rowb  = (size_t)blk*256;

    if (tid < 64) {
        const int o = tid;
        float sl = 0.f, bl = bql[o], sr = 0.f, br = bqr[o];
        for (int c = 0; c < 64; ++c) {
            float wl = Wql[o*64+c], wr = Wqr[o*64+c];
            sl += wl * nlw[c];
            bl += wl * nlb[c];
            sr += wr * nrw[c];
            br += wr * nrb[c];
        }
        SlA[o] = sl; BlA[o] = bl; SrA[o] = sr; BrA[o] = br; BvA[o] = bvr[o];
    }

    const int oA = wv*16 + l15;
    bf16x8 aL[2], aR[2], aV[2];
    #pragma unroll
    for (int hf = 0; hf < 2; ++hf) {
        bf16x8 tl, tr, tv;
        #pragma unroll
        for (int j = 0; j < 8; ++j) {
            const int c = hf*32 + kg*8 + j;
            tl[j] = (short)f2bf(Wql[oA*64+c] * nlw[c]);
            tr[j] = (short)f2bf(Wqr[oA*64+c] * nrw[c]);
            tv[j] = (short)f2bf(Wvr[oA*64+c]);
        }
        aL[hf] = tl; aR[hf] = tr; aV[hf] = tv;
    }

    // ================= LEFT =================
    for (int idx = tid; idx < 2048; idx += 256) {
        const int cpair = idx >> 6, j = idx & 63;
        const float4 va = *(const float4*)(xl + gbase + (size_t)(2*cpair  )*HW_ + j*4);
        const float4 vb = *(const float4*)(xl + gbase + (size_t)(2*cpair+1)*HW_ + j*4);
        const float* fa = (const float*)&va;
        const float* fb = (const float*)&vb;
        #pragma unroll
        for (int t = 0; t < 4; ++t) {
            const int px = j*4 + t;
            Xs32[px*32 + (((cpair>>2) ^ (px&7))<<2) + (cpair&3)] = pack2(fa[t], fb[t]);
        }
    }
    __syncthreads();
    {
        const int px = tid;
        float sum = 0.f, ssq = 0.f;
        #pragma unroll
        for (int c8 = 0; c8 < 8; ++c8) {
            const u32* wp = &Xs32[px*32 + ((c8 ^ (px&7))<<2)];
            #pragma unroll
            for (int q = 0; q < 4; ++q) {
                float a = blo(wp[q]), b = bhi(wp[q]);
                sum += a + b; ssq += a*a + b*b;
            }
        }
        float mu = sum * (1.f/64.f);
        float var = ssq * (1.f/64.f) - mu*mu;
        muA[px] = mu;
        rsA[px] = rsqrtf(var + 1e-6f);
    }
    __syncthreads();
    {
        float Sv[4], Bv[4];
        #pragma unroll
        for (int r = 0; r < 4; ++r) {
            Sv[r] = SlA[wv*16 + kg*4 + r];
            Bv[r] = BlA[wv*16 + kg*4 + r];
        }
        #pragma unroll
        for (int nt = 0; nt < 16; ++nt) {
            const int px = nt*16 + l15;
            f32x4 d = {0.f,0.f,0.f,0.f};
            #pragma unroll
            for (int hf = 0; hf < 2; ++hf) {
                bf16x8 b = *(const bf16x8*)&Xs32[px*32 + (((hf*4+kg) ^ (px&7))<<2)];
                d = __builtin_amdgcn_mfma_f32_16x16x32_bf16(aL[hf], b, d, 0, 0, 0);
            }
            const float mu = muA[px], rs = rsA[px];
            uint2 pv;
            pv.x = pack2(rs*(d[0] - mu*Sv[0]) + Bv[0], rs*(d[1] - mu*Sv[1]) + Bv[1]);
            pv.y = pack2(rs*(d[2] - mu*Sv[2]) + Bv[2], rs*(d[3] - mu*Sv[3]) + Bv[3]);
            *(uint2*)&Ql[(rowb + px)*32 + wv*8 + kg*2] = pv;
        }
    }
    __syncthreads();

    // ================= RIGHT =================
    for (int idx = tid; idx < 2048; idx += 256) {
        const int cpair = idx >> 6, j = idx & 63;
        const float4 va = *(const float4*)(xr + gbase + (size_t)(2*cpair  )*HW_ + j*4);
        const float4 vb = *(const float4*)(xr + gbase + (size_t)(2*cpair+1)*HW_ + j*4);
        const float* fa = (const float*)&va;
        const float* fb = (const float*)&vb;
        #pragma unroll
        for (int t = 0; t < 4; ++t) {
            const int px = j*4 + t;
            Xs32[px*32 + (((cpair>>2) ^ (px&7))<<2) + (cpair&3)] = pack2(fa[t], fb[t]);
        }
    }
    __syncthreads();
    {
        const int px = tid;
        float sum = 0.f, ssq = 0.f;
        #pragma unroll
        for (int c8 = 0; c8 < 8; ++c8) {
            const u32* wp = &Xs32[px*32 + ((c8 ^ (px&7))<<2)];
            #pragma unroll
            for (int q = 0; q < 4; ++q) {
                float a = blo(wp[q]), b = bhi(wp[q]);
                sum += a + b; ssq += a*a + b*b;
            }
        }
        float mu = sum * (1.f/64.f);
        float var = ssq * (1.f/64.f) - mu*mu;
        muA[px] = mu;
        rsA[px] = rsqrtf(var + 1e-6f);
    }
    __syncthreads();
    {
        float Sv[4], Bv[4], Vb[4];
        #pragma unroll
        for (int r = 0; r < 4; ++r) {
            Sv[r] = SrA[wv*16 + kg*4 + r];
            Bv[r] = BrA[wv*16 + kg*4 + r];
            Vb[r] = BvA[wv*16 + kg*4 + r];
        }
        #pragma unroll
        for (int nt = 0; nt < 16; ++nt) {
            const int px = nt*16 + l15;
            f32x4 dq = {0.f,0.f,0.f,0.f};
            f32x4 dv = {0.f,0.f,0.f,0.f};
            #pragma unroll
            for (int hf = 0; hf < 2; ++hf) {
                bf16x8 b = *(const bf16x8*)&Xs32[px*32 + (((hf*4+kg) ^ (px&7))<<2)];
                dq = __builtin_amdgcn_mfma_f32_16x16x32_bf16(aR[hf], b, dq, 0, 0, 0);
                dv = __builtin_amdgcn_mfma_f32_16x16x32_bf16(aV[hf], b, dv, 0, 0, 0);
            }
            const float mu = muA[px], rs = rsA[px];
            uint2 pq, pw;
            pq.x = pack2(rs*(dq[0] - mu*Sv[0]) + Bv[0], rs*(dq[1] - mu*Sv[1]) + Bv[1]);
            pq.y = pack2(rs*(dq[2] - mu*Sv[2]) + Bv[2], rs*(dq[3] - mu*Sv[3]) + Bv[3]);
            pw.x = pack2(dv[0] + Vb[0], dv[1] + Vb[1]);
            pw.y = pack2(dv[2] + Vb[2], dv[3] + Vb[3]);
            *(uint2*)&Qr[(rowb + px)*32 + wv*8 + kg*2] = pq;
            *(uint2*)&Vr[(rowb + px)*32 + wv*8 + kg*2] = pw;
        }
    }
}

// ---------------------------------------------------------------------------
// K2: per-scanline cross attention via MFMA (unchanged, validated).
// ---------------------------------------------------------------------------
__global__ __launch_bounds__(256, 2) void k_attn(
    const u32* __restrict__ Ql, const u32* __restrict__ Qr, const u32* __restrict__ Vr,
    const float* __restrict__ xl, const float* __restrict__ beta,
    float* __restrict__ out)
{
    __shared__ uint4 Ks[2048];      // 32 KB  [key][chunk16 ^ (key&7)]
    __shared__ u16  Vts[16384];     // 32 KB  V^T [ch][key], chunk ^ (ch&7)
    __shared__ u32  Pscr[4096];     // 16 KB  per-wave 1024 u32
    const int tid  = threadIdx.x;
    const int lane = tid & 63, wv = tid >> 6;
    const int l15  = lane & 15, kg = lane >> 4;
    const int blk  = blockIdx.x;
    const int n = blk >> 7, h = blk & 127;
    const size_t rowb = (size_t)blk*256;

    for (int it = tid; it < 2048; it += 256) {
        int key = it >> 3, c = it & 7;
        uint4 v = *(const uint4*)(Qr + (rowb + key)*32 + c*4);
        Ks[key*8 + (c ^ (key & 7))] = v;
    }
    for (int it = tid; it < 2048; it += 256) {
        int key = it & 255, j = it >> 8;
        uint4 v = *(const uint4*)(Vr + (rowb + key)*32 + j*4);
        const u32* vw = (const u32*)&v;
        #pragma unroll
        for (int t = 0; t < 8; ++t) {
            int ch = j*8 + t;
            u32 wd = vw[t >> 1];
            u16 hv = (t & 1) ? (u16)(wd >> 16) : (u16)(wd & 0xffffu);
            Vts[ch*256 + ((key >> 3) ^ (ch & 7))*8 + (key & 7)] = hv;
        }
    }

    const int q0 = wv*64;
    bf16x8 qf[4][2];
    #pragma unroll
    for (int nt = 0; nt < 4; ++nt)
        #pragma unroll
        for (int ci = 0; ci < 2; ++ci)
            qf[nt][ci] = *(const bf16x8*)(Ql + (rowb + q0 + nt*16 + l15)*32 + ci*16 + kg*4);

    f32x4 oacc[4][4];
    #pragma unroll
    for (int a = 0; a < 4; ++a)
        #pragma unroll
        for (int b = 0; b < 4; ++b)
            oacc[a][b] = (f32x4){0.f,0.f,0.f,0.f};
    float lsum[4] = {0.f,0.f,0.f,0.f};
    u32* Pw = &Pscr[wv*1024];

    __syncthreads();

    for (int kb = 0; kb < 8; ++kb) {
        f32x4 st[2][4];
        #pragma unroll
        for (int mt = 0; mt < 2; ++mt)
            #pragma unroll
            for (int nt = 0; nt < 4; ++nt)
                st[mt][nt] = (f32x4){0.f,0.f,0.f,0.f};
        #pragma unroll
        for (int ci = 0; ci < 2; ++ci) {
            bf16x8 a0 = *(const bf16x8*)&Ks[(kb*32 +      l15)*8 + ((ci*4 + kg) ^ (l15 & 7))];
            bf16x8 a1 = *(const bf16x8*)&Ks[(kb*32 + 16 + l15)*8 + ((ci*4 + kg) ^ (l15 & 7))];
            #pragma unroll
            for (int nt = 0; nt < 4; ++nt) {
                st[0][nt] = __builtin_amdgcn_mfma_f32_16x16x32_bf16(a0, qf[nt][ci], st[0][nt], 0, 0, 0);
                st[1][nt] = __builtin_amdgcn_mfma_f32_16x16x32_bf16(a1, qf[nt][ci], st[1][nt], 0, 0, 0);
            }
        }
        #pragma unroll
        for (int nt = 0; nt < 4; ++nt) {
            const int q = nt*16 + l15;
            #pragma unroll
            for (int mt = 0; mt < 2; ++mt) {
                float p0 = __expf(st[mt][nt][0]*0.125f);
                float p1 = __expf(st[mt][nt][1]*0.125f);
                float p2 = __expf(st[mt][nt][2]*0.125f);
                float p3 = __expf(st[mt][nt][3]*0.125f);
                lsum[nt] += (p0+p1)+(p2+p3);
                u32 pr0, pr1;
                asm("v_cvt_pk_bf16_f32 %0, %1, %2" : "=v"(pr0) : "v"(p0), "v"(p1));
                asm("v_cvt_pk_bf16_f32 %0, %1, %2" : "=v"(pr1) : "v"(p2), "v"(p3));
                const int c16 = (2*mt + (kg >> 1)) ^ (q & 3);
                uint2 pv; pv.x = pr0; pv.y = pr1;
                *(uint2*)&Pw[q*16 + c16*4 + (kg & 1)*2] = pv;
            }
        }
        asm volatile("s_waitcnt lgkmcnt(0)" ::: "memory");
        bf16x8 vb[4];
        #pragma unroll
        for (int nc = 0; nc < 4; ++nc)
            vb[nc] = *(const bf16x8*)&Vts[(nc*16 + l15)*256 + ((kb*4 + kg) ^ (l15 & 7))*8];
        #pragma unroll
        for (int qt = 0; qt < 4; ++qt) {
            const int q = qt*16 + l15;
            bf16x8 pa = *(const bf16x8*)&Pw[q*16 + (kg ^ (q & 3))*4];
            #pragma unroll
            for (int nc = 0; nc < 4; ++nc)
                oacc[qt][nc] = __builtin_amdgcn_mfma_f32_16x16x32_bf16(pa, vb[nc], oacc[qt][nc], 0, 0, 0);
        }
    }

    #pragma unroll
    for (int nt = 0; nt < 4; ++nt) {
        float s = lsum[nt];
        s += __shfl_xor(s, 16, 64);
        s += __shfl_xor(s, 32, 64);
        lsum[nt] = s;
    }
    float linv[4][4];
    #pragma unroll
    for (int qt = 0; qt < 4; ++qt)
        #pragma unroll
        for (int r = 0; r < 4; ++r)
            linv[qt][r] = 1.0f / __shfl(lsum[qt], kg*4 + r, 64);

    float* PwF = (float*)Pw;
    const size_t obase = (size_t)n*CHW_ + (size_t)h*W_ + q0;
    #pragma unroll
    for (int nc = 0; nc < 4; ++nc) {
        asm volatile("s_waitcnt lgkmcnt(0)" ::: "memory");
        #pragma unroll
        for (int qt = 0; qt < 4; ++qt) {
            f32x4 vals;
            vals[0] = oacc[qt][nc][0]*linv[qt][0];
            vals[1] = oacc[qt][nc][1]*linv[qt][1];
            vals[2] = oacc[qt][nc][2]*linv[qt][2];
            vals[3] = oacc[qt][nc][3]*linv[qt][3];
            *(f32x4*)&PwF[l15*64 + ((qt*4 + kg) ^ l15)*4] = vals;
        }
        asm volatile("s_waitcnt lgkmcnt(0)" ::: "memory");
        #pragma unroll
        for (int chl = 0; chl < 16; ++chl) {
            const int ch = nc*16 + chl;
            float v = PwF[chl*64 + ((lane >> 2) ^ chl)*4 + (lane & 3)];
            size_t gidx = obase + (size_t)ch*HW_ + lane;
            out[gidx] = xl[gidx] + beta[ch]*v;
        }
    }
}

// ---------------------------------------------------------------------------
// K3: T_t[n][h][w][c] = highpass(x_r), bf16, channel-contiguous.
// Wave = full row (64 lanes x float4 = 256 px).  Per channel: 3 float4 loads,
// horizontal taps via __shfl, vertical sum, 1 ds_write_b64 into swizzled
// [ch][px ^ (chunk<<3)] tile.  Coalesced 16B copy-out (reads 2 lanes/bank).
// XCD-chunked block swizzle keeps halo rows same-XCD L2 hits.
// ---------------------------------------------------------------------------
__global__ __launch_bounds__(256) void k_hipass(
    const float* __restrict__ xr, u16* __restrict__ Tt)
{
    __shared__ u16 Ts[64*256];             // 32 KB
    const int bid = blockIdx.x;
    const int blk = (bid & 7)*128 + (bid >> 3);   // XCD chunk: 128 rows/XCD
    const int n = blk >> 7, h = blk & 127;
    const int tid = threadIdx.x;
    const int lane = tid & 63, wv = tid >> 6;
    const float* rowp = xr + (size_t)n*CHW_ + (size_t)h*W_ + lane*4;

    #pragma unroll
    for (int ci = 0; ci < 16; ++ci) {
        const int c = wv*16 + ci;
        const float* pc = rowp + (size_t)c*HW_;
        float ctr0=0.f, ctr1=0.f, ctr2=0.f, ctr3=0.f;
        float s0=0.f, s1=0.f, s2=0.f, s3=0.f;
        #pragma unroll
        for (int dy = -1; dy <= 1; ++dy) {
            const int hh = h + dy;
            float4 v = {0.f,0.f,0.f,0.f};
            if (hh >= 0 && hh < 128) v = *(const float4*)(pc + dy*W_);
            float lft = __shfl_up(v.w, 1);
            float rgt = __shfl_down(v.x, 1);
            if (lane == 0)  lft = 0.f;
            if (lane == 63) rgt = 0.f;
            s0 += lft + v.x + v.y;
            s1 += v.x + v.y + v.z;
            s2 += v.y + v.z + v.w;
            s3 += v.z + v.w + rgt;
            if (dy == 0) { ctr0=v.x; ctr1=v.y; ctr2=v.z; ctr3=v.w; }
        }
        uint2 pv;
        pv.x = pack2(ctr0 - s0*(1.f/9.f), ctr1 - s1*(1.f/9.f));
        pv.y = pack2(ctr2 - s2*(1.f/9.f), ctr3 - s3*(1.f/9.f));
        const int swz = (c >> 3) << 3;                 // chunk<<3
        *(uint2*)&Ts[c*256 + ((lane*4) ^ swz)] = pv;
    }
    __syncthreads();
    // coalesced copy-out: consecutive tid -> consecutive 16B
    uint4* gout = (uint4*)(Tt + (size_t)blk*256*64);
    #pragma unroll
    for (int iter = 0; iter < 8; ++iter) {
        const int lin = iter*256 + tid;
        const int px = lin >> 3, chunk = lin & 7;
        const int pxs = px ^ (chunk << 3);
        u32 w4[4];
        #pragma unroll
        for (int tp = 0; tp < 4; ++tp) {
            const int c0 = chunk*8 + tp*2;
            u16 a = Ts[(c0    )*256 + pxs];
            u16 b = Ts[(c0 + 1)*256 + pxs];
            w4[tp] = (u32)a | ((u32)b << 16);
        }
        uint4 v; v.x=w4[0]; v.y=w4[1]; v.z=w4[2]; v.w=w4[3];
        gout[lin] = v;
    }
}

// ---------------------------------------------------------------------------
// K4: conv3x3 as MFMA GEMM (validated) + XCD-chunked block swizzle.
// ---------------------------------------------------------------------------
__global__ __launch_bounds__(256) void k_conv(
    const u16* __restrict__ Tt, const float* __restrict__ Whf,
    const float* __restrict__ bhf, const float* __restrict__ gam,
    float* __restrict__ out)
{
    __shared__ uint4 Xs[3*66*8];           // 25344 B, [dy][wt][chunk^(wt&7)]
    const int tid  = threadIdx.x;
    const int lane = tid & 63;
    const int mt   = tid >> 6;
    const int l15  = lane & 15;
    const int kg   = lane >> 4;
    const int bid  = blockIdx.x;
    const int blk  = (bid & 7)*128 + (bid >> 3);   // XCD chunk swizzle
    const int n = blk >> 7, h = blk & 127;

    const int oa = mt*16 + l15;
    bf16x8 A[18];
    #pragma unroll
    for (int s = 0; s < 18; ++s) {
        const int q  = s >> 1;
        const int ib = (s & 1)*32 + kg*8;
        bf16x8 a;
        #pragma unroll
        for (int j = 0; j < 8; ++j) {
            float wv = Whf[(size_t)(oa*64 + ib + j)*9 + q];
            a[j] = (short)f2bf(wv);
        }
        A[s] = a;
    }
    float gv[4], bv[4];
    #pragma unroll
    for (int r = 0; r < 4; ++r) {
        int oo = mt*16 + kg*4 + r;
        gv[r] = gam[oo];
        bv[r] = bhf[oo];
    }

    for (int t4 = 0; t4 < 4; ++t4) {
        const int w0 = t4*64;
        __syncthreads();
        for (int it = tid; it < 1584; it += 256) {
            int dy    = it / 528;
            int rem   = it - dy*528;
            int wt    = rem >> 3;
            int chunk = rem & 7;
            int hh = h + dy - 1;
            int wg = w0 + wt - 1;
            uint4 v = {0,0,0,0};
            if (hh >= 0 && hh < 128 && wg >= 0 && wg < 256)
                v = *(const uint4*)(Tt + (((size_t)(n*128 + hh)*256 + wg)*64 + chunk*8));
            Xs[(dy*66 + wt)*8 + (chunk ^ (wt & 7))] = v;
        }
        __syncthreads();

        f32x4 acc[4] = {{0,0,0,0},{0,0,0,0},{0,0,0,0},{0,0,0,0}};
        #pragma unroll
        for (int s = 0; s < 18; ++s) {
            const int q  = s >> 1;
            const int dy = q / 3, dx = q % 3;
            const int c0 = (s & 1)*4 + kg;
            #pragma unroll
            for (int nt = 0; nt < 4; ++nt) {
                const int wt = nt*16 + l15 + dx;
                bf16x8 b = *(const bf16x8*)&Xs[(dy*66 + wt)*8 + (c0 ^ (wt & 7))];
                acc[nt] = __builtin_amdgcn_mfma_f32_16x16x32_bf16(A[s], b, acc[nt], 0, 0, 0);
            }
        }
        #pragma unroll
        for (int nt = 0; nt < 4; ++nt) {
            const int px = w0 + nt*16 + l15;
            #pragma unroll
            for (int r = 0; r < 4; ++r) {
                const int oo = mt*16 + kg*4 + r;
                size_t idx = (size_t)(n*64 + oo)*HW_ + (size_t)h*W_ + px;
                out[idx] += gv[r]*(acc[nt][r] + bv[r]);
            }
        }
    }
}

extern "C" void kernel_launch(void* const* d_in, const int* in_sizes, int n_in,
                              void* d_out, int out_size, void* d_ws, size_t ws_size,
                              hipStream_t stream)
{
    const float* xl   = (const float*)d_in[0];
    const float* xr   = (const float*)d_in[1];
    const float* nlw  = (const float*)d_in[2];
    const float* nlb  = (const float*)d_in[3];
    const float* nrw  = (const float*)d_in[4];
    const float* nrb  = (const float*)d_in[5];
    const float* Wql  = (const float*)d_in[6];
    const float* bql  = (const float*)d_in[7];
    const float* Wqr  = (const float*)d_in[8];
    const float* bqr  = (const float*)d_in[9];
    const float* Wvr  = (const float*)d_in[10];
    const float* bvr  = (const float*)d_in[11];
    const float* beta = (const float*)d_in[12];
    const float* gam  = (const float*)d_in[13];
    const float* Whf  = (const float*)d_in[14];
    const float* bhf  = (const float*)d_in[15];
    float* out = (float*)d_out;

    u32* Ql = (u32*)d_ws;
    u32* Qr = Ql + 8388608;
    u32* Vr = Qr + 8388608;
    u16* Tt = (u16*)(Vr + 8388608);

    k_proj<<<1024, 256, 0, stream>>>(xl, xr, nlw, nlb, nrw, nrb,
                                     Wql, bql, Wqr, bqr, Wvr, bvr, Ql, Qr, Vr);
    k_hipass<<<1024, 256, 0, stream>>>(xr, Tt);
    k_attn<<<1024, 256, 0, stream>>>(Ql, Qr, Vr, xl, beta, out);
    k_conv<<<1024, 256, 0, stream>>>(Tt, Whf, bhf, gam, out);
}

// Round 8
// 230.731 us; speedup vs baseline: 6.7107x; 1.0377x over previous
//
#include <hip/hip_runtime.h>
#include <hip/hip_bf16.h>

#define N_ 8
#define C_ 64
#define H_ 128
#define W_ 256
#define HW_ (H_*W_)        // 32768
#define CHW_ (C_*H_*W_)    // 2097152

typedef unsigned int u32;
typedef unsigned short u16;
typedef float f32x4 __attribute__((ext_vector_type(4)));
typedef short bf16x8 __attribute__((ext_vector_type(8)));

__device__ __forceinline__ float blo(u32 u) { return __uint_as_float(u << 16); }
__device__ __forceinline__ float bhi(u32 u) { return __uint_as_float(u & 0xffff0000u); }
__device__ __forceinline__ u16 f2bf(float f) {
    u32 u = __float_as_uint(f);
    u32 lsb = (u >> 16) & 1u;
    u += 0x7fffu + lsb;
    return (u16)(u >> 16);
}
__device__ __forceinline__ u32 pack2(float a, float b) {
    return (u32)f2bf(a) | ((u32)f2bf(b) << 16);
}
// bijective row remap: rotates low-3 row bits per 8-row group so that
// lane-groups with px-stride 4 still spread across all 8 chunk slots.
__device__ __forceinline__ int rmap(int px) {
    return (px & 0xF8) | ((px + (px >> 3)) & 7);
}

// ---------------------------------------------------------------------------
// K1: LayerNorm + 1x1 conv projections via MFMA.
// LDS tile Xs32[r(px)][64ch] bf16, chunk-swizzled (chunk ^ (r&7)).
// Staging is chunk-granular: thread loads 8 channels x float4 px, packs with
// v_cvt_pk_bf16_f32, writes ds_write_b128 -> zero excess bank conflicts.
// ---------------------------------------------------------------------------
__global__ __launch_bounds__(256) void k_proj(
    const float* __restrict__ xl, const float* __restrict__ xr,
    const float* __restrict__ nlw, const float* __restrict__ nlb,
    const float* __restrict__ nrw, const float* __restrict__ nrb,
    const float* __restrict__ Wql, const float* __restrict__ bql,
    const float* __restrict__ Wqr, const float* __restrict__ bqr,
    const float* __restrict__ Wvr, const float* __restrict__ bvr,
    u32* __restrict__ Ql, u32* __restrict__ Qr, u32* __restrict__ Vr)
{
    __shared__ u32 Xs32[256*32];       // 32 KB  [r(px)][cpair], 16B-chunk swizzled
    __shared__ float muA[256], rsA[256];
    __shared__ float SlA[64], BlA[64], SrA[64], BrA[64], BvA[64];
    const int tid  = threadIdx.x;
    const int lane = tid & 63, wv = tid >> 6;
    const int l15  = lane & 15, kg = lane >> 4;
    const int blk  = blockIdx.x;       // n*128 + h
    const int n = blk >> 7, h = blk & 127;
    const size_t gbase = (size_t)n*CHW_ + (size_t)h*W_;   // + c*HW_ + px
    const size_t rowb  = (size_t)blk*256;

    if (tid < 64) {
        const int o = tid;
        float sl = 0.f, bl = bql[o], sr = 0.f, br = bqr[o];
        for (int c = 0; c < 64; ++c) {
            float wl = Wql[o*64+c], wr = Wqr[o*64+c];
            sl += wl * nlw[c];
            bl += wl * nlb[c];
            sr += wr * nrw[c];
            br += wr * nrb[c];
        }
        SlA[o] = sl; BlA[o] = bl; SrA[o] = sr; BrA[o] = br; BvA[o] = bvr[o];
    }

    const int oA = wv*16 + l15;
    bf16x8 aL[2], aR[2], aV[2];
    #pragma unroll
    for (int hf = 0; hf < 2; ++hf) {
        bf16x8 tl, tr, tv;
        #pragma unroll
        for (int j = 0; j < 8; ++j) {
            const int c = hf*32 + kg*8 + j;
            tl[j] = (short)f2bf(Wql[oA*64+c] * nlw[c]);
            tr[j] = (short)f2bf(Wqr[oA*64+c] * nrw[c]);
            tv[j] = (short)f2bf(Wvr[oA*64+c]);
        }
        aL[hf] = tl; aR[hf] = tr; aV[hf] = tv;
    }

    // ================= LEFT =================
    #pragma unroll
    for (int it2 = 0; it2 < 2; ++it2) {
        const int g = it2*256 + tid;          // 0..511
        const int chunk = g >> 6;             // 0..7
        const int j = g & 63;                 // px group (4 px)
        const int c0 = chunk*8;
        float4 v[8];
        #pragma unroll
        for (int e = 0; e < 8; ++e)
            v[e] = *(const float4*)(xl + gbase + (size_t)(c0+e)*HW_ + j*4);
        #pragma unroll
        for (int t = 0; t < 4; ++t) {
            const int px = j*4 + t;
            const int r = rmap(px);
            u32 q0,q1,q2,q3;
            const float* f0 = (const float*)&v[0]; const float* f1 = (const float*)&v[1];
            const float* f2 = (const float*)&v[2]; const float* f3 = (const float*)&v[3];
            const float* f4 = (const float*)&v[4]; const float* f5 = (const float*)&v[5];
            const float* f6 = (const float*)&v[6]; const float* f7 = (const float*)&v[7];
            asm("v_cvt_pk_bf16_f32 %0, %1, %2" : "=v"(q0) : "v"(f0[t]), "v"(f1[t]));
            asm("v_cvt_pk_bf16_f32 %0, %1, %2" : "=v"(q1) : "v"(f2[t]), "v"(f3[t]));
            asm("v_cvt_pk_bf16_f32 %0, %1, %2" : "=v"(q2) : "v"(f4[t]), "v"(f5[t]));
            asm("v_cvt_pk_bf16_f32 %0, %1, %2" : "=v"(q3) : "v"(f6[t]), "v"(f7[t]));
            uint4 pv; pv.x=q0; pv.y=q1; pv.z=q2; pv.w=q3;
            *(uint4*)&Xs32[r*32 + ((chunk ^ (r&7))<<2)] = pv;
        }
    }
    __syncthreads();
    {
        const int px = tid & 255;
        const int r = rmap(px);
        float sum = 0.f, ssq = 0.f;
        #pragma unroll
        for (int c8 = 0; c8 < 8; ++c8) {
            uint4 val = *(const uint4*)&Xs32[r*32 + ((c8 ^ (r&7))<<2)];
            const u32* wp = (const u32*)&val;
            #pragma unroll
            for (int q = 0; q < 4; ++q) {
                float a = blo(wp[q]), b = bhi(wp[q]);
                sum += a + b; ssq += a*a + b*b;
            }
        }
        float mu = sum * (1.f/64.f);
        float var = ssq * (1.f/64.f) - mu*mu;
        muA[px] = mu;
        rsA[px] = rsqrtf(var + 1e-6f);
    }
    __syncthreads();
    {
        float Sv[4], Bv[4];
        #pragma unroll
        for (int r4 = 0; r4 < 4; ++r4) {
            Sv[r4] = SlA[wv*16 + kg*4 + r4];
            Bv[r4] = BlA[wv*16 + kg*4 + r4];
        }
        #pragma unroll
        for (int nt = 0; nt < 16; ++nt) {
            const int px = nt*16 + l15;
            const int r = rmap(px);
            f32x4 d = {0.f,0.f,0.f,0.f};
            #pragma unroll
            for (int hf = 0; hf < 2; ++hf) {
                bf16x8 b = *(const bf16x8*)&Xs32[r*32 + (((hf*4+kg) ^ (r&7))<<2)];
                d = __builtin_amdgcn_mfma_f32_16x16x32_bf16(aL[hf], b, d, 0, 0, 0);
            }
            const float mu = muA[px], rs = rsA[px];
            uint2 pv;
            pv.x = pack2(rs*(d[0] - mu*Sv[0]) + Bv[0], rs*(d[1] - mu*Sv[1]) + Bv[1]);
            pv.y = pack2(rs*(d[2] - mu*Sv[2]) + Bv[2], rs*(d[3] - mu*Sv[3]) + Bv[3]);
            *(uint2*)&Ql[(rowb + px)*32 + wv*8 + kg*2] = pv;
        }
    }
    __syncthreads();

    // ================= RIGHT =================
    #pragma unroll
    for (int it2 = 0; it2 < 2; ++it2) {
        const int g = it2*256 + tid;
        const int chunk = g >> 6;
        const int j = g & 63;
        const int c0 = chunk*8;
        float4 v[8];
        #pragma unroll
        for (int e = 0; e < 8; ++e)
            v[e] = *(const float4*)(xr + gbase + (size_t)(c0+e)*HW_ + j*4);
        #pragma unroll
        for (int t = 0; t < 4; ++t) {
            const int px = j*4 + t;
            const int r = rmap(px);
            u32 q0,q1,q2,q3;
            const float* f0 = (const float*)&v[0]; const float* f1 = (const float*)&v[1];
            const float* f2 = (const float*)&v[2]; const float* f3 = (const float*)&v[3];
            const float* f4 = (const float*)&v[4]; const float* f5 = (const float*)&v[5];
            const float* f6 = (const float*)&v[6]; const float* f7 = (const float*)&v[7];
            asm("v_cvt_pk_bf16_f32 %0, %1, %2" : "=v"(q0) : "v"(f0[t]), "v"(f1[t]));
            asm("v_cvt_pk_bf16_f32 %0, %1, %2" : "=v"(q1) : "v"(f2[t]), "v"(f3[t]));
            asm("v_cvt_pk_bf16_f32 %0, %1, %2" : "=v"(q2) : "v"(f4[t]), "v"(f5[t]));
            asm("v_cvt_pk_bf16_f32 %0, %1, %2" : "=v"(q3) : "v"(f6[t]), "v"(f7[t]));
            uint4 pv; pv.x=q0; pv.y=q1; pv.z=q2; pv.w=q3;
            *(uint4*)&Xs32[r*32 + ((chunk ^ (r&7))<<2)] = pv;
        }
    }
    __syncthreads();
    {
        const int px = tid & 255;
        const int r = rmap(px);
        float sum = 0.f, ssq = 0.f;
        #pragma unroll
        for (int c8 = 0; c8 < 8; ++c8) {
            uint4 val = *(const uint4*)&Xs32[r*32 + ((c8 ^ (r&7))<<2)];
            const u32* wp = (const u32*)&val;
            #pragma unroll
            for (int q = 0; q < 4; ++q) {
                float a = blo(wp[q]), b = bhi(wp[q]);
                sum += a + b; ssq += a*a + b*b;
            }
        }
        float mu = sum * (1.f/64.f);
        float var = ssq * (1.f/64.f) - mu*mu;
        muA[px] = mu;
        rsA[px] = rsqrtf(var + 1e-6f);
    }
    __syncthreads();
    {
        float Sv[4], Bv[4], Vb[4];
        #pragma unroll
        for (int r4 = 0; r4 < 4; ++r4) {
            Sv[r4] = SrA[wv*16 + kg*4 + r4];
            Bv[r4] = BrA[wv*16 + kg*4 + r4];
            Vb[r4] = BvA[wv*16 + kg*4 + r4];
        }
        #pragma unroll
        for (int nt = 0; nt < 16; ++nt) {
            const int px = nt*16 + l15;
            const int r = rmap(px);
            f32x4 dq = {0.f,0.f,0.f,0.f};
            f32x4 dv = {0.f,0.f,0.f,0.f};
            #pragma unroll
            for (int hf = 0; hf < 2; ++hf) {
                bf16x8 b = *(const bf16x8*)&Xs32[r*32 + (((hf*4+kg) ^ (r&7))<<2)];
                dq = __builtin_amdgcn_mfma_f32_16x16x32_bf16(aR[hf], b, dq, 0, 0, 0);
                dv = __builtin_amdgcn_mfma_f32_16x16x32_bf16(aV[hf], b, dv, 0, 0, 0);
            }
            const float mu = muA[px], rs = rsA[px];
            uint2 pq, pw;
            pq.x = pack2(rs*(dq[0] - mu*Sv[0]) + Bv[0], rs*(dq[1] - mu*Sv[1]) + Bv[1]);
            pq.y = pack2(rs*(dq[2] - mu*Sv[2]) + Bv[2], rs*(dq[3] - mu*Sv[3]) + Bv[3]);
            pw.x = pack2(dv[0] + Vb[0], dv[1] + Vb[1]);
            pw.y = pack2(dv[2] + Vb[2], dv[3] + Vb[3]);
            *(uint2*)&Qr[(rowb + px)*32 + wv*8 + kg*2] = pq;
            *(uint2*)&Vr[(rowb + px)*32 + wv*8 + kg*2] = pw;
        }
    }
}

// ---------------------------------------------------------------------------
// K2: per-scanline cross attention via MFMA (unchanged, validated).
// ---------------------------------------------------------------------------
__global__ __launch_bounds__(256, 2) void k_attn(
    const u32* __restrict__ Ql, const u32* __restrict__ Qr, const u32* __restrict__ Vr,
    const float* __restrict__ xl, const float* __restrict__ beta,
    float* __restrict__ out)
{
    __shared__ uint4 Ks[2048];      // 32 KB  [key][chunk16 ^ (key&7)]
    __shared__ u16  Vts[16384];     // 32 KB  V^T [ch][key], chunk ^ (ch&7)
    __shared__ u32  Pscr[4096];     // 16 KB  per-wave 1024 u32
    const int tid  = threadIdx.x;
    const int lane = tid & 63, wv = tid >> 6;
    const int l15  = lane & 15, kg = lane >> 4;
    const int blk  = blockIdx.x;
    const int n = blk >> 7, h = blk & 127;
    const size_t rowb = (size_t)blk*256;

    for (int it = tid; it < 2048; it += 256) {
        int key = it >> 3, c = it & 7;
        uint4 v = *(const uint4*)(Qr + (rowb + key)*32 + c*4);
        Ks[key*8 + (c ^ (key & 7))] = v;
    }
    for (int it = tid; it < 2048; it += 256) {
        int key = it & 255, j = it >> 8;
        uint4 v = *(const uint4*)(Vr + (rowb + key)*32 + j*4);
        const u32* vw = (const u32*)&v;
        #pragma unroll
        for (int t = 0; t < 8; ++t) {
            int ch = j*8 + t;
            u32 wd = vw[t >> 1];
            u16 hv = (t & 1) ? (u16)(wd >> 16) : (u16)(wd & 0xffffu);
            Vts[ch*256 + ((key >> 3) ^ (ch & 7))*8 + (key & 7)] = hv;
        }
    }

    const int q0 = wv*64;
    bf16x8 qf[4][2];
    #pragma unroll
    for (int nt = 0; nt < 4; ++nt)
        #pragma unroll
        for (int ci = 0; ci < 2; ++ci)
            qf[nt][ci] = *(const bf16x8*)(Ql + (rowb + q0 + nt*16 + l15)*32 + ci*16 + kg*4);

    f32x4 oacc[4][4];
    #pragma unroll
    for (int a = 0; a < 4; ++a)
        #pragma unroll
        for (int b = 0; b < 4; ++b)
            oacc[a][b] = (f32x4){0.f,0.f,0.f,0.f};
    float lsum[4] = {0.f,0.f,0.f,0.f};
    u32* Pw = &Pscr[wv*1024];

    __syncthreads();

    for (int kb = 0; kb < 8; ++kb) {
        f32x4 st[2][4];
        #pragma unroll
        for (int mt = 0; mt < 2; ++mt)
            #pragma unroll
            for (int nt = 0; nt < 4; ++nt)
                st[mt][nt] = (f32x4){0.f,0.f,0.f,0.f};
        #pragma unroll
        for (int ci = 0; ci < 2; ++ci) {
            bf16x8 a0 = *(const bf16x8*)&Ks[(kb*32 +      l15)*8 + ((ci*4 + kg) ^ (l15 & 7))];
            bf16x8 a1 = *(const bf16x8*)&Ks[(kb*32 + 16 + l15)*8 + ((ci*4 + kg) ^ (l15 & 7))];
            #pragma unroll
            for (int nt = 0; nt < 4; ++nt) {
                st[0][nt] = __builtin_amdgcn_mfma_f32_16x16x32_bf16(a0, qf[nt][ci], st[0][nt], 0, 0, 0);
                st[1][nt] = __builtin_amdgcn_mfma_f32_16x16x32_bf16(a1, qf[nt][ci], st[1][nt], 0, 0, 0);
            }
        }
        #pragma unroll
        for (int nt = 0; nt < 4; ++nt) {
            const int q = nt*16 + l15;
            #pragma unroll
            for (int mt = 0; mt < 2; ++mt) {
                float p0 = __expf(st[mt][nt][0]*0.125f);
                float p1 = __expf(st[mt][nt][1]*0.125f);
                float p2 = __expf(st[mt][nt][2]*0.125f);
                float p3 = __expf(st[mt][nt][3]*0.125f);
                lsum[nt] += (p0+p1)+(p2+p3);
                u32 pr0, pr1;
                asm("v_cvt_pk_bf16_f32 %0, %1, %2" : "=v"(pr0) : "v"(p0), "v"(p1));
                asm("v_cvt_pk_bf16_f32 %0, %1, %2" : "=v"(pr1) : "v"(p2), "v"(p3));
                const int c16 = (2*mt + (kg >> 1)) ^ (q & 3);
                uint2 pv; pv.x = pr0; pv.y = pr1;
                *(uint2*)&Pw[q*16 + c16*4 + (kg & 1)*2] = pv;
            }
        }
        asm volatile("s_waitcnt lgkmcnt(0)" ::: "memory");
        bf16x8 vb[4];
        #pragma unroll
        for (int nc = 0; nc < 4; ++nc)
            vb[nc] = *(const bf16x8*)&Vts[(nc*16 + l15)*256 + ((kb*4 + kg) ^ (l15 & 7))*8];
        #pragma unroll
        for (int qt = 0; qt < 4; ++qt) {
            const int q = qt*16 + l15;
            bf16x8 pa = *(const bf16x8*)&Pw[q*16 + (kg ^ (q & 3))*4];
            #pragma unroll
            for (int nc = 0; nc < 4; ++nc)
                oacc[qt][nc] = __builtin_amdgcn_mfma_f32_16x16x32_bf16(pa, vb[nc], oacc[qt][nc], 0, 0, 0);
        }
    }

    #pragma unroll
    for (int nt = 0; nt < 4; ++nt) {
        float s = lsum[nt];
        s += __shfl_xor(s, 16, 64);
        s += __shfl_xor(s, 32, 64);
        lsum[nt] = s;
    }
    float linv[4][4];
    #pragma unroll
    for (int qt = 0; qt < 4; ++qt)
        #pragma unroll
        for (int r = 0; r < 4; ++r)
            linv[qt][r] = 1.0f / __shfl(lsum[qt], kg*4 + r, 64);

    float* PwF = (float*)Pw;
    const size_t obase = (size_t)n*CHW_ + (size_t)h*W_ + q0;
    #pragma unroll
    for (int nc = 0; nc < 4; ++nc) {
        asm volatile("s_waitcnt lgkmcnt(0)" ::: "memory");
        #pragma unroll
        for (int qt = 0; qt < 4; ++qt) {
            f32x4 vals;
            vals[0] = oacc[qt][nc][0]*linv[qt][0];
            vals[1] = oacc[qt][nc][1]*linv[qt][1];
            vals[2] = oacc[qt][nc][2]*linv[qt][2];
            vals[3] = oacc[qt][nc][3]*linv[qt][3];
            *(f32x4*)&PwF[l15*64 + ((qt*4 + kg) ^ l15)*4] = vals;
        }
        asm volatile("s_waitcnt lgkmcnt(0)" ::: "memory");
        #pragma unroll
        for (int chl = 0; chl < 16; ++chl) {
            const int ch = nc*16 + chl;
            float v = PwF[chl*64 + ((lane >> 2) ^ chl)*4 + (lane & 3)];
            size_t gidx = obase + (size_t)ch*HW_ + lane;
            out[gidx] = xl[gidx] + beta[ch]*v;
        }
    }
}

// ---------------------------------------------------------------------------
// K3: T_t[n][h][w][c] = highpass(x_r), bf16 (unchanged, validated).
// ---------------------------------------------------------------------------
__global__ __launch_bounds__(256) void k_hipass(
    const float* __restrict__ xr, u16* __restrict__ Tt)
{
    __shared__ u16 Ts[64*256];             // 32 KB
    const int bid = blockIdx.x;
    const int blk = (bid & 7)*128 + (bid >> 3);   // XCD chunk: 128 rows/XCD
    const int n = blk >> 7, h = blk & 127;
    const int tid = threadIdx.x;
    const int lane = tid & 63, wv = tid >> 6;
    const float* rowp = xr + (size_t)n*CHW_ + (size_t)h*W_ + lane*4;

    #pragma unroll
    for (int ci = 0; ci < 16; ++ci) {
        const int c = wv*16 + ci;
        const float* pc = rowp + (size_t)c*HW_;
        float ctr0=0.f, ctr1=0.f, ctr2=0.f, ctr3=0.f;
        float s0=0.f, s1=0.f, s2=0.f, s3=0.f;
        #pragma unroll
        for (int dy = -1; dy <= 1; ++dy) {
            const int hh = h + dy;
            float4 v = {0.f,0.f,0.f,0.f};
            if (hh >= 0 && hh < 128) v = *(const float4*)(pc + dy*W_);
            float lft = __shfl_up(v.w, 1);
            float rgt = __shfl_down(v.x, 1);
            if (lane == 0)  lft = 0.f;
            if (lane == 63) rgt = 0.f;
            s0 += lft + v.x + v.y;
            s1 += v.x + v.y + v.z;
            s2 += v.y + v.z + v.w;
            s3 += v.z + v.w + rgt;
            if (dy == 0) { ctr0=v.x; ctr1=v.y; ctr2=v.z; ctr3=v.w; }
        }
        uint2 pv;
        pv.x = pack2(ctr0 - s0*(1.f/9.f), ctr1 - s1*(1.f/9.f));
        pv.y = pack2(ctr2 - s2*(1.f/9.f), ctr3 - s3*(1.f/9.f));
        const int swz = (c >> 3) << 3;                 // chunk<<3
        *(uint2*)&Ts[c*256 + ((lane*4) ^ swz)] = pv;
    }
    __syncthreads();
    uint4* gout = (uint4*)(Tt + (size_t)blk*256*64);
    #pragma unroll
    for (int iter = 0; iter < 8; ++iter) {
        const int lin = iter*256 + tid;
        const int px = lin >> 3, chunk = lin & 7;
        const int pxs = px ^ (chunk << 3);
        u32 w4[4];
        #pragma unroll
        for (int tp = 0; tp < 4; ++tp) {
            const int c0 = chunk*8 + tp*2;
            u16 a = Ts[(c0    )*256 + pxs];
            u16 b = Ts[(c0 + 1)*256 + pxs];
            w4[tp] = (u32)a | ((u32)b << 16);
        }
        uint4 v; v.x=w4[0]; v.y=w4[1]; v.z=w4[2]; v.w=w4[3];
        gout[lin] = v;
    }
}

// ---------------------------------------------------------------------------
// K4: conv3x3 as MFMA GEMM (unchanged, validated) + XCD swizzle.
// ---------------------------------------------------------------------------
__global__ __launch_bounds__(256) void k_conv(
    const u16* __restrict__ Tt, const float* __restrict__ Whf,
    const float* __restrict__ bhf, const float* __restrict__ gam,
    float* __restrict__ out)
{
    __shared__ uint4 Xs[3*66*8];           // 25344 B, [dy][wt][chunk^(wt&7)]
    const int tid  = threadIdx.x;
    const int lane = tid & 63;
    const int mt   = tid >> 6;
    const int l15  = lane & 15;
    const int kg   = lane >> 4;
    const int bid  = blockIdx.x;
    const int blk  = (bid & 7)*128 + (bid >> 3);   // XCD chunk swizzle
    const int n = blk >> 7, h = blk & 127;

    const int oa = mt*16 + l15;
    bf16x8 A[18];
    #pragma unroll
    for (int s = 0; s < 18; ++s) {
        const int q  = s >> 1;
        const int ib = (s & 1)*32 + kg*8;
        bf16x8 a;
        #pragma unroll
        for (int j = 0; j < 8; ++j) {
            float wv = Whf[(size_t)(oa*64 + ib + j)*9 + q];
            a[j] = (short)f2bf(wv);
        }
        A[s] = a;
    }
    float gv[4], bv[4];
    #pragma unroll
    for (int r = 0; r < 4; ++r) {
        int oo = mt*16 + kg*4 + r;
        gv[r] = gam[oo];
        bv[r] = bhf[oo];
    }

    for (int t4 = 0; t4 < 4; ++t4) {
        const int w0 = t4*64;
        __syncthreads();
        for (int it = tid; it < 1584; it += 256) {
            int dy    = it / 528;
            int rem   = it - dy*528;
            int wt    = rem >> 3;
            int chunk = rem & 7;
            int hh = h + dy - 1;
            int wg = w0 + wt - 1;
            uint4 v = {0,0,0,0};
            if (hh >= 0 && hh < 128 && wg >= 0 && wg < 256)
                v = *(const uint4*)(Tt + (((size_t)(n*128 + hh)*256 + wg)*64 + chunk*8));
            Xs[(dy*66 + wt)*8 + (chunk ^ (wt & 7))] = v;
        }
        __syncthreads();

        f32x4 acc[4] = {{0,0,0,0},{0,0,0,0},{0,0,0,0},{0,0,0,0}};
        #pragma unroll
        for (int s = 0; s < 18; ++s) {
            const int q  = s >> 1;
            const int dy = q / 3, dx = q % 3;
            const int c0 = (s & 1)*4 + kg;
            #pragma unroll
            for (int nt = 0; nt < 4; ++nt) {
                const int wt = nt*16 + l15 + dx;
                bf16x8 b = *(const bf16x8*)&Xs[(dy*66 + wt)*8 + (c0 ^ (wt & 7))];
                acc[nt] = __builtin_amdgcn_mfma_f32_16x16x32_bf16(A[s], b, acc[nt], 0, 0, 0);
            }
        }
        #pragma unroll
        for (int nt = 0; nt < 4; ++nt) {
            const int px = w0 + nt*16 + l15;
            #pragma unroll
            for (int r = 0; r < 4; ++r) {
                const int oo = mt*16 + kg*4 + r;
                size_t idx = (size_t)(n*64 + oo)*HW_ + (size_t)h*W_ + px;
                out[idx] += gv[r]*(acc[nt][r] + bv[r]);
            }
        }
    }
}

extern "C" void kernel_launch(void* const* d_in, const int* in_sizes, int n_in,
                              void* d_out, int out_size, void* d_ws, size_t ws_size,
                              hipStream_t stream)
{
    const float* xl   = (const float*)d_in[0];
    const float* xr   = (const float*)d_in[1];
    const float* nlw  = (const float*)d_in[2];
    const float* nlb  = (const float*)d_in[3];
    const float* nrw  = (const float*)d_in[4];
    const float* nrb  = (const float*)d_in[5];
    const float* Wql  = (const float*)d_in[6];
    const float* bql  = (const float*)d_in[7];
    const float* Wqr  = (const float*)d_in[8];
    const float* bqr  = (const float*)d_in[9];
    const float* Wvr  = (const float*)d_in[10];
    const float* bvr  = (const float*)d_in[11];
    const float* beta = (const float*)d_in[12];
    const float* gam  = (const float*)d_in[13];
    const float* Whf  = (const float*)d_in[14];
    const float* bhf  = (const float*)d_in[15];
    float* out = (float*)d_out;

    u32* Ql = (u32*)d_ws;
    u32* Qr = Ql + 8388608;
    u32* Vr = Qr + 8388608;
    u16* Tt = (u16*)(Vr + 8388608);

    k_proj<<<1024, 256, 0, stream>>>(xl, xr, nlw, nlb, nrw, nrb,
                                     Wql, bql, Wqr, bqr, Wvr, bvr, Ql, Qr, Vr);
    k_hipass<<<1024, 256, 0, stream>>>(xr, Tt);
    k_attn<<<1024, 256, 0, stream>>>(Ql, Qr, Vr, xl, beta, out);
    k_conv<<<1024, 256, 0, stream>>>(Tt, Whf, bhf, gam, out);
}

// Round 9
// 215.458 us; speedup vs baseline: 7.1864x; 1.0709x over previous
//
#include <hip/hip_runtime.h>
#include <hip/hip_bf16.h>

#define N_ 8
#define C_ 64
#define H_ 128
#define W_ 256
#define HW_ (H_*W_)        // 32768
#define CHW_ (C_*H_*W_)    // 2097152

typedef unsigned int u32;
typedef unsigned short u16;
typedef float f32x4 __attribute__((ext_vector_type(4)));
typedef short bf16x8 __attribute__((ext_vector_type(8)));

__device__ __forceinline__ float blo(u32 u) { return __uint_as_float(u << 16); }
__device__ __forceinline__ float bhi(u32 u) { return __uint_as_float(u & 0xffff0000u); }
__device__ __forceinline__ u16 f2bf(float f) {
    u32 u = __float_as_uint(f);
    u32 lsb = (u >> 16) & 1u;
    u += 0x7fffu + lsb;
    return (u16)(u >> 16);
}
__device__ __forceinline__ u32 pack2(float a, float b) {
    return (u32)f2bf(a) | ((u32)f2bf(b) << 16);
}
// bijective row remap: rotates low-3 row bits per 8-row group so that
// lane-groups with px-stride 4 still spread across all 8 chunk slots.
__device__ __forceinline__ int rmap(int px) {
    return (px & 0xF8) | ((px + (px >> 3)) & 7);
}

// ---------------------------------------------------------------------------
// K1: LayerNorm + 1x1 conv projections via MFMA (unchanged, validated).
// ---------------------------------------------------------------------------
__global__ __launch_bounds__(256) void k_proj(
    const float* __restrict__ xl, const float* __restrict__ xr,
    const float* __restrict__ nlw, const float* __restrict__ nlb,
    const float* __restrict__ nrw, const float* __restrict__ nrb,
    const float* __restrict__ Wql, const float* __restrict__ bql,
    const float* __restrict__ Wqr, const float* __restrict__ bqr,
    const float* __restrict__ Wvr, const float* __restrict__ bvr,
    u32* __restrict__ Ql, u32* __restrict__ Qr, u32* __restrict__ Vr)
{
    __shared__ u32 Xs32[256*32];       // 32 KB  [r(px)][cpair], 16B-chunk swizzled
    __shared__ float muA[256], rsA[256];
    __shared__ float SlA[64], BlA[64], SrA[64], BrA[64], BvA[64];
    const int tid  = threadIdx.x;
    const int lane = tid & 63, wv = tid >> 6;
    const int l15  = lane & 15, kg = lane >> 4;
    const int blk  = blockIdx.x;       // n*128 + h
    const int n = blk >> 7, h = blk & 127;
    const size_t gbase = (size_t)n*CHW_ + (size_t)h*W_;   // + c*HW_ + px
    const size_t rowb  = (size_t)blk*256;

    if (tid < 64) {
        const int o = tid;
        float sl = 0.f, bl = bql[o], sr = 0.f, br = bqr[o];
        for (int c = 0; c < 64; ++c) {
            float wl = Wql[o*64+c], wr = Wqr[o*64+c];
            sl += wl * nlw[c];
            bl += wl * nlb[c];
            sr += wr * nrw[c];
            br += wr * nrb[c];
        }
        SlA[o] = sl; BlA[o] = bl; SrA[o] = sr; BrA[o] = br; BvA[o] = bvr[o];
    }

    const int oA = wv*16 + l15;
    bf16x8 aL[2], aR[2], aV[2];
    #pragma unroll
    for (int hf = 0; hf < 2; ++hf) {
        bf16x8 tl, tr, tv;
        #pragma unroll
        for (int j = 0; j < 8; ++j) {
            const int c = hf*32 + kg*8 + j;
            tl[j] = (short)f2bf(Wql[oA*64+c] * nlw[c]);
            tr[j] = (short)f2bf(Wqr[oA*64+c] * nrw[c]);
            tv[j] = (short)f2bf(Wvr[oA*64+c]);
        }
        aL[hf] = tl; aR[hf] = tr; aV[hf] = tv;
    }

    // ================= LEFT =================
    #pragma unroll
    for (int it2 = 0; it2 < 2; ++it2) {
        const int g = it2*256 + tid;          // 0..511
        const int chunk = g >> 6;             // 0..7
        const int j = g & 63;                 // px group (4 px)
        const int c0 = chunk*8;
        float4 v[8];
        #pragma unroll
        for (int e = 0; e < 8; ++e)
            v[e] = *(const float4*)(xl + gbase + (size_t)(c0+e)*HW_ + j*4);
        #pragma unroll
        for (int t = 0; t < 4; ++t) {
            const int px = j*4 + t;
            const int r = rmap(px);
            u32 q0,q1,q2,q3;
            const float* f0 = (const float*)&v[0]; const float* f1 = (const float*)&v[1];
            const float* f2 = (const float*)&v[2]; const float* f3 = (const float*)&v[3];
            const float* f4 = (const float*)&v[4]; const float* f5 = (const float*)&v[5];
            const float* f6 = (const float*)&v[6]; const float* f7 = (const float*)&v[7];
            asm("v_cvt_pk_bf16_f32 %0, %1, %2" : "=v"(q0) : "v"(f0[t]), "v"(f1[t]));
            asm("v_cvt_pk_bf16_f32 %0, %1, %2" : "=v"(q1) : "v"(f2[t]), "v"(f3[t]));
            asm("v_cvt_pk_bf16_f32 %0, %1, %2" : "=v"(q2) : "v"(f4[t]), "v"(f5[t]));
            asm("v_cvt_pk_bf16_f32 %0, %1, %2" : "=v"(q3) : "v"(f6[t]), "v"(f7[t]));
            uint4 pv; pv.x=q0; pv.y=q1; pv.z=q2; pv.w=q3;
            *(uint4*)&Xs32[r*32 + ((chunk ^ (r&7))<<2)] = pv;
        }
    }
    __syncthreads();
    {
        const int px = tid & 255;
        const int r = rmap(px);
        float sum = 0.f, ssq = 0.f;
        #pragma unroll
        for (int c8 = 0; c8 < 8; ++c8) {
            uint4 val = *(const uint4*)&Xs32[r*32 + ((c8 ^ (r&7))<<2)];
            const u32* wp = (const u32*)&val;
            #pragma unroll
            for (int q = 0; q < 4; ++q) {
                float a = blo(wp[q]), b = bhi(wp[q]);
                sum += a + b; ssq += a*a + b*b;
            }
        }
        float mu = sum * (1.f/64.f);
        float var = ssq * (1.f/64.f) - mu*mu;
        muA[px] = mu;
        rsA[px] = rsqrtf(var + 1e-6f);
    }
    __syncthreads();
    {
        float Sv[4], Bv[4];
        #pragma unroll
        for (int r4 = 0; r4 < 4; ++r4) {
            Sv[r4] = SlA[wv*16 + kg*4 + r4];
            Bv[r4] = BlA[wv*16 + kg*4 + r4];
        }
        #pragma unroll
        for (int nt = 0; nt < 16; ++nt) {
            const int px = nt*16 + l15;
            const int r = rmap(px);
            f32x4 d = {0.f,0.f,0.f,0.f};
            #pragma unroll
            for (int hf = 0; hf < 2; ++hf) {
                bf16x8 b = *(const bf16x8*)&Xs32[r*32 + (((hf*4+kg) ^ (r&7))<<2)];
                d = __builtin_amdgcn_mfma_f32_16x16x32_bf16(aL[hf], b, d, 0, 0, 0);
            }
            const float mu = muA[px], rs = rsA[px];
            uint2 pv;
            pv.x = pack2(rs*(d[0] - mu*Sv[0]) + Bv[0], rs*(d[1] - mu*Sv[1]) + Bv[1]);
            pv.y = pack2(rs*(d[2] - mu*Sv[2]) + Bv[2], rs*(d[3] - mu*Sv[3]) + Bv[3]);
            *(uint2*)&Ql[(rowb + px)*32 + wv*8 + kg*2] = pv;
        }
    }
    __syncthreads();

    // ================= RIGHT =================
    #pragma unroll
    for (int it2 = 0; it2 < 2; ++it2) {
        const int g = it2*256 + tid;
        const int chunk = g >> 6;
        const int j = g & 63;
        const int c0 = chunk*8;
        float4 v[8];
        #pragma unroll
        for (int e = 0; e < 8; ++e)
            v[e] = *(const float4*)(xr + gbase + (size_t)(c0+e)*HW_ + j*4);
        #pragma unroll
        for (int t = 0; t < 4; ++t) {
            const int px = j*4 + t;
            const int r = rmap(px);
            u32 q0,q1,q2,q3;
            const float* f0 = (const float*)&v[0]; const float* f1 = (const float*)&v[1];
            const float* f2 = (const float*)&v[2]; const float* f3 = (const float*)&v[3];
            const float* f4 = (const float*)&v[4]; const float* f5 = (const float*)&v[5];
            const float* f6 = (const float*)&v[6]; const float* f7 = (const float*)&v[7];
            asm("v_cvt_pk_bf16_f32 %0, %1, %2" : "=v"(q0) : "v"(f0[t]), "v"(f1[t]));
            asm("v_cvt_pk_bf16_f32 %0, %1, %2" : "=v"(q1) : "v"(f2[t]), "v"(f3[t]));
            asm("v_cvt_pk_bf16_f32 %0, %1, %2" : "=v"(q2) : "v"(f4[t]), "v"(f5[t]));
            asm("v_cvt_pk_bf16_f32 %0, %1, %2" : "=v"(q3) : "v"(f6[t]), "v"(f7[t]));
            uint4 pv; pv.x=q0; pv.y=q1; pv.z=q2; pv.w=q3;
            *(uint4*)&Xs32[r*32 + ((chunk ^ (r&7))<<2)] = pv;
        }
    }
    __syncthreads();
    {
        const int px = tid & 255;
        const int r = rmap(px);
        float sum = 0.f, ssq = 0.f;
        #pragma unroll
        for (int c8 = 0; c8 < 8; ++c8) {
            uint4 val = *(const uint4*)&Xs32[r*32 + ((c8 ^ (r&7))<<2)];
            const u32* wp = (const u32*)&val;
            #pragma unroll
            for (int q = 0; q < 4; ++q) {
                float a = blo(wp[q]), b = bhi(wp[q]);
                sum += a + b; ssq += a*a + b*b;
            }
        }
        float mu = sum * (1.f/64.f);
        float var = ssq * (1.f/64.f) - mu*mu;
        muA[px] = mu;
        rsA[px] = rsqrtf(var + 1e-6f);
    }
    __syncthreads();
    {
        float Sv[4], Bv[4], Vb[4];
        #pragma unroll
        for (int r4 = 0; r4 < 4; ++r4) {
            Sv[r4] = SrA[wv*16 + kg*4 + r4];
            Bv[r4] = BrA[wv*16 + kg*4 + r4];
            Vb[r4] = BvA[wv*16 + kg*4 + r4];
        }
        #pragma unroll
        for (int nt = 0; nt < 16; ++nt) {
            const int px = nt*16 + l15;
            const int r = rmap(px);
            f32x4 dq = {0.f,0.f,0.f,0.f};
            f32x4 dv = {0.f,0.f,0.f,0.f};
            #pragma unroll
            for (int hf = 0; hf < 2; ++hf) {
                bf16x8 b = *(const bf16x8*)&Xs32[r*32 + (((hf*4+kg) ^ (r&7))<<2)];
                dq = __builtin_amdgcn_mfma_f32_16x16x32_bf16(aR[hf], b, dq, 0, 0, 0);
                dv = __builtin_amdgcn_mfma_f32_16x16x32_bf16(aV[hf], b, dv, 0, 0, 0);
            }
            const float mu = muA[px], rs = rsA[px];
            uint2 pq, pw;
            pq.x = pack2(rs*(dq[0] - mu*Sv[0]) + Bv[0], rs*(dq[1] - mu*Sv[1]) + Bv[1]);
            pq.y = pack2(rs*(dq[2] - mu*Sv[2]) + Bv[2], rs*(dq[3] - mu*Sv[3]) + Bv[3]);
            pw.x = pack2(dv[0] + Vb[0], dv[1] + Vb[1]);
            pw.y = pack2(dv[2] + Vb[2], dv[3] + Vb[3]);
            *(uint2*)&Qr[(rowb + px)*32 + wv*8 + kg*2] = pq;
            *(uint2*)&Vr[(rowb + px)*32 + wv*8 + kg*2] = pw;
        }
    }
}

// ---------------------------------------------------------------------------
// K2: per-scanline cross attention via MFMA.  Epilogue now ADDS the hf branch
// already stored in out by k_conv:  out = xl + beta*F + out_prev.
// ---------------------------------------------------------------------------
__global__ __launch_bounds__(256, 2) void k_attn(
    const u32* __restrict__ Ql, const u32* __restrict__ Qr, const u32* __restrict__ Vr,
    const float* __restrict__ xl, const float* __restrict__ beta,
    float* __restrict__ out)
{
    __shared__ uint4 Ks[2048];      // 32 KB  [key][chunk16 ^ (key&7)]
    __shared__ u16  Vts[16384];     // 32 KB  V^T [ch][key], chunk ^ (ch&7)
    __shared__ u32  Pscr[4096];     // 16 KB  per-wave 1024 u32
    const int tid  = threadIdx.x;
    const int lane = tid & 63, wv = tid >> 6;
    const int l15  = lane & 15, kg = lane >> 4;
    const int blk  = blockIdx.x;
    const int n = blk >> 7, h = blk & 127;
    const size_t rowb = (size_t)blk*256;

    for (int it = tid; it < 2048; it += 256) {
        int key = it >> 3, c = it & 7;
        uint4 v = *(const uint4*)(Qr + (rowb + key)*32 + c*4);
        Ks[key*8 + (c ^ (key & 7))] = v;
    }
    for (int it = tid; it < 2048; it += 256) {
        int key = it & 255, j = it >> 8;
        uint4 v = *(const uint4*)(Vr + (rowb + key)*32 + j*4);
        const u32* vw = (const u32*)&v;
        #pragma unroll
        for (int t = 0; t < 8; ++t) {
            int ch = j*8 + t;
            u32 wd = vw[t >> 1];
            u16 hv = (t & 1) ? (u16)(wd >> 16) : (u16)(wd & 0xffffu);
            Vts[ch*256 + ((key >> 3) ^ (ch & 7))*8 + (key & 7)] = hv;
        }
    }

    const int q0 = wv*64;
    bf16x8 qf[4][2];
    #pragma unroll
    for (int nt = 0; nt < 4; ++nt)
        #pragma unroll
        for (int ci = 0; ci < 2; ++ci)
            qf[nt][ci] = *(const bf16x8*)(Ql + (rowb + q0 + nt*16 + l15)*32 + ci*16 + kg*4);

    f32x4 oacc[4][4];
    #pragma unroll
    for (int a = 0; a < 4; ++a)
        #pragma unroll
        for (int b = 0; b < 4; ++b)
            oacc[a][b] = (f32x4){0.f,0.f,0.f,0.f};
    float lsum[4] = {0.f,0.f,0.f,0.f};
    u32* Pw = &Pscr[wv*1024];

    __syncthreads();

    for (int kb = 0; kb < 8; ++kb) {
        f32x4 st[2][4];
        #pragma unroll
        for (int mt = 0; mt < 2; ++mt)
            #pragma unroll
            for (int nt = 0; nt < 4; ++nt)
                st[mt][nt] = (f32x4){0.f,0.f,0.f,0.f};
        #pragma unroll
        for (int ci = 0; ci < 2; ++ci) {
            bf16x8 a0 = *(const bf16x8*)&Ks[(kb*32 +      l15)*8 + ((ci*4 + kg) ^ (l15 & 7))];
            bf16x8 a1 = *(const bf16x8*)&Ks[(kb*32 + 16 + l15)*8 + ((ci*4 + kg) ^ (l15 & 7))];
            #pragma unroll
            for (int nt = 0; nt < 4; ++nt) {
                st[0][nt] = __builtin_amdgcn_mfma_f32_16x16x32_bf16(a0, qf[nt][ci], st[0][nt], 0, 0, 0);
                st[1][nt] = __builtin_amdgcn_mfma_f32_16x16x32_bf16(a1, qf[nt][ci], st[1][nt], 0, 0, 0);
            }
        }
        #pragma unroll
        for (int nt = 0; nt < 4; ++nt) {
            const int q = nt*16 + l15;
            #pragma unroll
            for (int mt = 0; mt < 2; ++mt) {
                float p0 = __expf(st[mt][nt][0]*0.125f);
                float p1 = __expf(st[mt][nt][1]*0.125f);
                float p2 = __expf(st[mt][nt][2]*0.125f);
                float p3 = __expf(st[mt][nt][3]*0.125f);
                lsum[nt] += (p0+p1)+(p2+p3);
                u32 pr0, pr1;
                asm("v_cvt_pk_bf16_f32 %0, %1, %2" : "=v"(pr0) : "v"(p0), "v"(p1));
                asm("v_cvt_pk_bf16_f32 %0, %1, %2" : "=v"(pr1) : "v"(p2), "v"(p3));
                const int c16 = (2*mt + (kg >> 1)) ^ (q & 3);
                uint2 pv; pv.x = pr0; pv.y = pr1;
                *(uint2*)&Pw[q*16 + c16*4 + (kg & 1)*2] = pv;
            }
        }
        asm volatile("s_waitcnt lgkmcnt(0)" ::: "memory");
        bf16x8 vb[4];
        #pragma unroll
        for (int nc = 0; nc < 4; ++nc)
            vb[nc] = *(const bf16x8*)&Vts[(nc*16 + l15)*256 + ((kb*4 + kg) ^ (l15 & 7))*8];
        #pragma unroll
        for (int qt = 0; qt < 4; ++qt) {
            const int q = qt*16 + l15;
            bf16x8 pa = *(const bf16x8*)&Pw[q*16 + (kg ^ (q & 3))*4];
            #pragma unroll
            for (int nc = 0; nc < 4; ++nc)
                oacc[qt][nc] = __builtin_amdgcn_mfma_f32_16x16x32_bf16(pa, vb[nc], oacc[qt][nc], 0, 0, 0);
        }
    }

    #pragma unroll
    for (int nt = 0; nt < 4; ++nt) {
        float s = lsum[nt];
        s += __shfl_xor(s, 16, 64);
        s += __shfl_xor(s, 32, 64);
        lsum[nt] = s;
    }
    float linv[4][4];
    #pragma unroll
    for (int qt = 0; qt < 4; ++qt)
        #pragma unroll
        for (int r = 0; r < 4; ++r)
            linv[qt][r] = 1.0f / __shfl(lsum[qt], kg*4 + r, 64);

    float* PwF = (float*)Pw;
    const size_t obase = (size_t)n*CHW_ + (size_t)h*W_ + q0;
    #pragma unroll
    for (int nc = 0; nc < 4; ++nc) {
        asm volatile("s_waitcnt lgkmcnt(0)" ::: "memory");
        #pragma unroll
        for (int qt = 0; qt < 4; ++qt) {
            f32x4 vals;
            vals[0] = oacc[qt][nc][0]*linv[qt][0];
            vals[1] = oacc[qt][nc][1]*linv[qt][1];
            vals[2] = oacc[qt][nc][2]*linv[qt][2];
            vals[3] = oacc[qt][nc][3]*linv[qt][3];
            *(f32x4*)&PwF[l15*64 + ((qt*4 + kg) ^ l15)*4] = vals;
        }
        asm volatile("s_waitcnt lgkmcnt(0)" ::: "memory");
        #pragma unroll
        for (int chl = 0; chl < 16; ++chl) {
            const int ch = nc*16 + chl;
            float v = PwF[chl*64 + ((lane >> 2) ^ chl)*4 + (lane & 3)];
            size_t gidx = obase + (size_t)ch*HW_ + lane;
            float prev = out[gidx];
            out[gidx] = xl[gidx] + beta[ch]*v + prev;
        }
    }
}

// ---------------------------------------------------------------------------
// K3: T_t[n][h][w][c] = highpass(x_r), bf16 (unchanged, validated).
// ---------------------------------------------------------------------------
__global__ __launch_bounds__(256) void k_hipass(
    const float* __restrict__ xr, u16* __restrict__ Tt)
{
    __shared__ u16 Ts[64*256];             // 32 KB
    const int bid = blockIdx.x;
    const int blk = (bid & 7)*128 + (bid >> 3);   // XCD chunk: 128 rows/XCD
    const int n = blk >> 7, h = blk & 127;
    const int tid = threadIdx.x;
    const int lane = tid & 63, wv = tid >> 6;
    const float* rowp = xr + (size_t)n*CHW_ + (size_t)h*W_ + lane*4;

    #pragma unroll
    for (int ci = 0; ci < 16; ++ci) {
        const int c = wv*16 + ci;
        const float* pc = rowp + (size_t)c*HW_;
        float ctr0=0.f, ctr1=0.f, ctr2=0.f, ctr3=0.f;
        float s0=0.f, s1=0.f, s2=0.f, s3=0.f;
        #pragma unroll
        for (int dy = -1; dy <= 1; ++dy) {
            const int hh = h + dy;
            float4 v = {0.f,0.f,0.f,0.f};
            if (hh >= 0 && hh < 128) v = *(const float4*)(pc + dy*W_);
            float lft = __shfl_up(v.w, 1);
            float rgt = __shfl_down(v.x, 1);
            if (lane == 0)  lft = 0.f;
            if (lane == 63) rgt = 0.f;
            s0 += lft + v.x + v.y;
            s1 += v.x + v.y + v.z;
            s2 += v.y + v.z + v.w;
            s3 += v.z + v.w + rgt;
            if (dy == 0) { ctr0=v.x; ctr1=v.y; ctr2=v.z; ctr3=v.w; }
        }
        uint2 pv;
        pv.x = pack2(ctr0 - s0*(1.f/9.f), ctr1 - s1*(1.f/9.f));
        pv.y = pack2(ctr2 - s2*(1.f/9.f), ctr3 - s3*(1.f/9.f));
        const int swz = (c >> 3) << 3;                 // chunk<<3
        *(uint2*)&Ts[c*256 + ((lane*4) ^ swz)] = pv;
    }
    __syncthreads();
    uint4* gout = (uint4*)(Tt + (size_t)blk*256*64);
    #pragma unroll
    for (int iter = 0; iter < 8; ++iter) {
        const int lin = iter*256 + tid;
        const int px = lin >> 3, chunk = lin & 7;
        const int pxs = px ^ (chunk << 3);
        u32 w4[4];
        #pragma unroll
        for (int tp = 0; tp < 4; ++tp) {
            const int c0 = chunk*8 + tp*2;
            u16 a = Ts[(c0    )*256 + pxs];
            u16 b = Ts[(c0 + 1)*256 + pxs];
            w4[tp] = (u32)a | ((u32)b << 16);
        }
        uint4 v; v.x=w4[0]; v.y=w4[1]; v.z=w4[2]; v.w=w4[3];
        gout[lin] = v;
    }
}

// ---------------------------------------------------------------------------
// K4: conv3x3 as MFMA GEMM.  Grid 2048 (half-row per block), double-buffered
// LDS with reg-staged tile-1 prefetch issued under tile-0 compute.  Epilogue
// is a PURE STORE (out = gamma*(hf+b)); k_attn adds the rest afterwards.
// ---------------------------------------------------------------------------
__device__ __forceinline__ void conv_tile(
    const uint4* __restrict__ buf, const bf16x8* A,
    const float* gv, const float* bv,
    int n, int h, int w0, int mt, int l15, int kg,
    float* __restrict__ out)
{
    f32x4 acc[4] = {{0,0,0,0},{0,0,0,0},{0,0,0,0},{0,0,0,0}};
    #pragma unroll
    for (int s = 0; s < 18; ++s) {
        const int q  = s >> 1;
        const int dy = q / 3, dx = q % 3;
        const int c0 = (s & 1)*4 + kg;
        #pragma unroll
        for (int nt = 0; nt < 4; ++nt) {
            const int wt = nt*16 + l15 + dx;
            bf16x8 b = *(const bf16x8*)&buf[(dy*66 + wt)*8 + (c0 ^ (wt & 7))];
            acc[nt] = __builtin_amdgcn_mfma_f32_16x16x32_bf16(A[s], b, acc[nt], 0, 0, 0);
        }
    }
    #pragma unroll
    for (int nt = 0; nt < 4; ++nt) {
        const int px = w0 + nt*16 + l15;
        #pragma unroll
        for (int r = 0; r < 4; ++r) {
            const int oo = mt*16 + kg*4 + r;
            size_t idx = (size_t)(n*64 + oo)*HW_ + (size_t)h*W_ + px;
            out[idx] = gv[r]*(acc[nt][r] + bv[r]);
        }
    }
}

__global__ __launch_bounds__(256) void k_conv(
    const u16* __restrict__ Tt, const float* __restrict__ Whf,
    const float* __restrict__ bhf, const float* __restrict__ gam,
    float* __restrict__ out)
{
    __shared__ uint4 Xs[2][1584];          // 2 x 25344 B double buffer
    const int tid  = threadIdx.x;
    const int lane = tid & 63;
    const int mt   = tid >> 6;
    const int l15  = lane & 15;
    const int kg   = lane >> 4;
    const int bid  = blockIdx.x;
    const int blk2 = (bid & 7)*256 + (bid >> 3);   // XCD chunk swizzle (2048 wgs)
    const int row  = blk2 >> 1, half = blk2 & 1;
    const int n = row >> 7, h = row & 127;
    const int w00 = half*128;
    const int w01 = w00 + 64;

    const int oa = mt*16 + l15;
    bf16x8 A[18];
    #pragma unroll
    for (int s = 0; s < 18; ++s) {
        const int q  = s >> 1;
        const int ib = (s & 1)*32 + kg*8;
        bf16x8 a;
        #pragma unroll
        for (int j = 0; j < 8; ++j) {
            float wv = Whf[(size_t)(oa*64 + ib + j)*9 + q];
            a[j] = (short)f2bf(wv);
        }
        A[s] = a;
    }
    float gv[4], bv[4];
    #pragma unroll
    for (int r = 0; r < 4; ++r) {
        int oo = mt*16 + kg*4 + r;
        gv[r] = gam[oo];
        bv[r] = bhf[oo];
    }

    // ---- stage tile0 directly ----
    for (int it = tid; it < 1584; it += 256) {
        int dy    = it / 528;
        int rem   = it - dy*528;
        int wt    = rem >> 3;
        int chunk = rem & 7;
        int hh = h + dy - 1;
        int wg = w00 + wt - 1;
        uint4 v = {0,0,0,0};
        if (hh >= 0 && hh < 128 && wg >= 0 && wg < 256)
            v = *(const uint4*)(Tt + (((size_t)(n*128 + hh)*256 + wg)*64 + chunk*8));
        Xs[0][(dy*66 + wt)*8 + (chunk ^ (wt & 7))] = v;
    }
    __syncthreads();

    // ---- issue tile1 global loads into regs (overlap with tile0 compute) ----
    uint4 rr[7];
    #pragma unroll
    for (int k = 0; k < 7; ++k) {
        const int it = k*256 + tid;
        if (it < 1584) {
            int dy    = it / 528;
            int rem   = it - dy*528;
            int wt    = rem >> 3;
            int chunk = rem & 7;
            int hh = h + dy - 1;
            int wg = w01 + wt - 1;
            uint4 v = {0,0,0,0};
            if (hh >= 0 && hh < 128 && wg >= 0 && wg < 256)
                v = *(const uint4*)(Tt + (((size_t)(n*128 + hh)*256 + wg)*64 + chunk*8));
            rr[k] = v;
        }
    }

    // ---- compute tile0 (pure store epilogue) ----
    conv_tile(&Xs[0][0], A, gv, bv, n, h, w00, mt, l15, kg, out);

    // ---- write tile1 to LDS, barrier, compute ----
    #pragma unroll
    for (int k = 0; k < 7; ++k) {
        const int it = k*256 + tid;
        if (it < 1584) {
            int dy    = it / 528;
            int rem   = it - dy*528;
            int wt    = rem >> 3;
            int chunk = rem & 7;
            Xs[1][(dy*66 + wt)*8 + (chunk ^ (wt & 7))] = rr[k];
        }
    }
    __syncthreads();
    conv_tile(&Xs[1][0], A, gv, bv, n, h, w01, mt, l15, kg, out);
}

extern "C" void kernel_launch(void* const* d_in, const int* in_sizes, int n_in,
                              void* d_out, int out_size, void* d_ws, size_t ws_size,
                              hipStream_t stream)
{
    const float* xl   = (const float*)d_in[0];
    const float* xr   = (const float*)d_in[1];
    const float* nlw  = (const float*)d_in[2];
    const float* nlb  = (const float*)d_in[3];
    const float* nrw  = (const float*)d_in[4];
    const float* nrb  = (const float*)d_in[5];
    const float* Wql  = (const float*)d_in[6];
    const float* bql  = (const float*)d_in[7];
    const float* Wqr  = (const float*)d_in[8];
    const float* bqr  = (const float*)d_in[9];
    const float* Wvr  = (const float*)d_in[10];
    const float* bvr  = (const float*)d_in[11];
    const float* beta = (const float*)d_in[12];
    const float* gam  = (const float*)d_in[13];
    const float* Whf  = (const float*)d_in[14];
    const float* bhf  = (const float*)d_in[15];
    float* out = (float*)d_out;

    u32* Ql = (u32*)d_ws;
    u32* Qr = Ql + 8388608;
    u32* Vr = Qr + 8388608;
    u16* Tt = (u16*)(Vr + 8388608);

    k_proj<<<1024, 256, 0, stream>>>(xl, xr, nlw, nlb, nrw, nrb,
                                     Wql, bql, Wqr, bqr, Wvr, bvr, Ql, Qr, Vr);
    k_hipass<<<1024, 256, 0, stream>>>(xr, Tt);
    k_conv<<<2048, 256, 0, stream>>>(Tt, Whf, bhf, gam, out);
    k_attn<<<1024, 256, 0, stream>>>(Ql, Qr, Vr, xl, beta, out);
}

// Round 10
// 194.283 us; speedup vs baseline: 7.9696x; 1.1090x over previous
//
#include <hip/hip_runtime.h>
#include <hip/hip_bf16.h>

#define N_ 8
#define C_ 64
#define H_ 128
#define W_ 256
#define HW_ (H_*W_)        // 32768
#define CHW_ (C_*H_*W_)    // 2097152

typedef unsigned int u32;
typedef unsigned short u16;
typedef float f32x4 __attribute__((ext_vector_type(4)));
typedef short bf16x8 __attribute__((ext_vector_type(8)));

__device__ __forceinline__ float blo(u32 u) { return __uint_as_float(u << 16); }
__device__ __forceinline__ float bhi(u32 u) { return __uint_as_float(u & 0xffff0000u); }
__device__ __forceinline__ u16 f2bf(float f) {
    u32 u = __float_as_uint(f);
    u32 lsb = (u >> 16) & 1u;
    u += 0x7fffu + lsb;
    return (u16)(u >> 16);
}
__device__ __forceinline__ u32 pack2(float a, float b) {
    return (u32)f2bf(a) | ((u32)f2bf(b) << 16);
}
// bijective row remap: rotates low-3 row bits per 8-row group so that
// lane-groups with px-stride 4 still spread across all 8 chunk slots.
__device__ __forceinline__ int rmap(int px) {
    return (px & 0xF8) | ((px + (px >> 3)) & 7);
}

// ---------------------------------------------------------------------------
// K_FUSED: LayerNorm + projections + cross-attention, all per scanline.
// Q_l/Q_r/V_r never touch HBM: they are produced by MFMA GEMMs straight into
// LDS in the exact layouts the (validated) attention core consumes.
//   B1: X staging tile (xl, then xr); reused as P scratch in attention.
//   B2: Q_l [row][64ch] swizzled; reused as V^T [ch][key] (operand-swap GEMM).
//   Ks: Q_r [key][64ch] swizzled.
// ---------------------------------------------------------------------------
__global__ __launch_bounds__(256) void k_fused(
    const float* __restrict__ xl, const float* __restrict__ xr,
    const float* __restrict__ nlw, const float* __restrict__ nlb,
    const float* __restrict__ nrw, const float* __restrict__ nrb,
    const float* __restrict__ Wql, const float* __restrict__ bql,
    const float* __restrict__ Wqr, const float* __restrict__ bqr,
    const float* __restrict__ Wvr, const float* __restrict__ bvr,
    const float* __restrict__ beta, float* __restrict__ out)
{
    __shared__ u32 B1[8192];           // 32 KB: X tile [r(px)][cpair]; later Pscr
    __shared__ u32 B2[8192];           // 32 KB: Q_l [row][ch]; later Vts (u16)
    __shared__ uint4 Ks[2048];         // 32 KB: Q_r [key][chunk ^ (key&7)]
    __shared__ float muA[256], rsA[256];
    __shared__ float SlA[64], BlA[64], SrA[64], BrA[64], BvA[64];
    const int tid  = threadIdx.x;
    const int lane = tid & 63, wv = tid >> 6;
    const int l15  = lane & 15, kg = lane >> 4;
    const int blk  = blockIdx.x;       // n*128 + h
    const int n = blk >> 7, h = blk & 127;
    const size_t gbase = (size_t)n*CHW_ + (size_t)h*W_;

    if (tid < 64) {
        const int o = tid;
        float sl = 0.f, bl = bql[o], sr = 0.f, br = bqr[o];
        for (int c = 0; c < 64; ++c) {
            float wl = Wql[o*64+c], wr = Wqr[o*64+c];
            sl += wl * nlw[c];
            bl += wl * nlb[c];
            sr += wr * nrw[c];
            br += wr * nrb[c];
        }
        SlA[o] = sl; BlA[o] = bl; SrA[o] = sr; BrA[o] = br; BvA[o] = bvr[o];
    }

    const int oA = wv*16 + l15;
    bf16x8 aL[2], aR[2], aV[2];
    #pragma unroll
    for (int hf = 0; hf < 2; ++hf) {
        bf16x8 tl, tr, tv;
        #pragma unroll
        for (int j = 0; j < 8; ++j) {
            const int c = hf*32 + kg*8 + j;
            tl[j] = (short)f2bf(Wql[oA*64+c] * nlw[c]);
            tr[j] = (short)f2bf(Wqr[oA*64+c] * nrw[c]);
            tv[j] = (short)f2bf(Wvr[oA*64+c]);
        }
        aL[hf] = tl; aR[hf] = tr; aV[hf] = tv;
    }

    // ================= LEFT: stage xl =================
    #pragma unroll
    for (int it2 = 0; it2 < 2; ++it2) {
        const int g = it2*256 + tid;
        const int chunk = g >> 6;
        const int j = g & 63;
        const int c0 = chunk*8;
        float4 v[8];
        #pragma unroll
        for (int e = 0; e < 8; ++e)
            v[e] = *(const float4*)(xl + gbase + (size_t)(c0+e)*HW_ + j*4);
        #pragma unroll
        for (int t = 0; t < 4; ++t) {
            const int px = j*4 + t;
            const int r = rmap(px);
            u32 q0,q1,q2,q3;
            const float* f0 = (const float*)&v[0]; const float* f1 = (const float*)&v[1];
            const float* f2 = (const float*)&v[2]; const float* f3 = (const float*)&v[3];
            const float* f4 = (const float*)&v[4]; const float* f5 = (const float*)&v[5];
            const float* f6 = (const float*)&v[6]; const float* f7 = (const float*)&v[7];
            asm("v_cvt_pk_bf16_f32 %0, %1, %2" : "=v"(q0) : "v"(f0[t]), "v"(f1[t]));
            asm("v_cvt_pk_bf16_f32 %0, %1, %2" : "=v"(q1) : "v"(f2[t]), "v"(f3[t]));
            asm("v_cvt_pk_bf16_f32 %0, %1, %2" : "=v"(q2) : "v"(f4[t]), "v"(f5[t]));
            asm("v_cvt_pk_bf16_f32 %0, %1, %2" : "=v"(q3) : "v"(f6[t]), "v"(f7[t]));
            uint4 pv; pv.x=q0; pv.y=q1; pv.z=q2; pv.w=q3;
            *(uint4*)&B1[r*32 + ((chunk ^ (r&7))<<2)] = pv;
        }
    }
    __syncthreads();
    {   // LN stats (left)
        const int px = tid & 255;
        const int r = rmap(px);
        float sum = 0.f, ssq = 0.f;
        #pragma unroll
        for (int c8 = 0; c8 < 8; ++c8) {
            uint4 val = *(const uint4*)&B1[r*32 + ((c8 ^ (r&7))<<2)];
            const u32* wp = (const u32*)&val;
            #pragma unroll
            for (int q = 0; q < 4; ++q) {
                float a = blo(wp[q]), b = bhi(wp[q]);
                sum += a + b; ssq += a*a + b*b;
            }
        }
        float mu = sum * (1.f/64.f);
        float var = ssq * (1.f/64.f) - mu*mu;
        muA[px] = mu;
        rsA[px] = rsqrtf(var + 1e-6f);
    }
    __syncthreads();
    {   // GEMM left -> Q_l into B2 [row][ch] swizzled
        float Sv[4], Bv[4];
        #pragma unroll
        for (int r4 = 0; r4 < 4; ++r4) {
            Sv[r4] = SlA[wv*16 + kg*4 + r4];
            Bv[r4] = BlA[wv*16 + kg*4 + r4];
        }
        #pragma unroll
        for (int nt = 0; nt < 16; ++nt) {
            const int px = nt*16 + l15;
            const int r = rmap(px);
            f32x4 d = {0.f,0.f,0.f,0.f};
            #pragma unroll
            for (int hf = 0; hf < 2; ++hf) {
                bf16x8 b = *(const bf16x8*)&B1[r*32 + (((hf*4+kg) ^ (r&7))<<2)];
                d = __builtin_amdgcn_mfma_f32_16x16x32_bf16(aL[hf], b, d, 0, 0, 0);
            }
            const float mu = muA[px], rs = rsA[px];
            uint2 pv;
            pv.x = pack2(rs*(d[0] - mu*Sv[0]) + Bv[0], rs*(d[1] - mu*Sv[1]) + Bv[1]);
            pv.y = pack2(rs*(d[2] - mu*Sv[2]) + Bv[2], rs*(d[3] - mu*Sv[3]) + Bv[3]);
            const int ci = (wv*2 + (kg>>1)) ^ (px & 7);
            *(uint2*)&B2[px*32 + (ci<<2) + (kg&1)*2] = pv;
        }
    }
    __syncthreads();

    // ---- load this wave's Q_l fragments from B2, and stage xr into B1 ----
    bf16x8 qf[4][2];
    #pragma unroll
    for (int ntq = 0; ntq < 4; ++ntq)
        #pragma unroll
        for (int ci = 0; ci < 2; ++ci) {
            const int q = wv*64 + ntq*16 + l15;
            qf[ntq][ci] = *(const bf16x8*)&B2[q*32 + (((ci*4+kg) ^ (q&7))<<2)];
        }
    #pragma unroll
    for (int it2 = 0; it2 < 2; ++it2) {
        const int g = it2*256 + tid;
        const int chunk = g >> 6;
        const int j = g & 63;
        const int c0 = chunk*8;
        float4 v[8];
        #pragma unroll
        for (int e = 0; e < 8; ++e)
            v[e] = *(const float4*)(xr + gbase + (size_t)(c0+e)*HW_ + j*4);
        #pragma unroll
        for (int t = 0; t < 4; ++t) {
            const int px = j*4 + t;
            const int r = rmap(px);
            u32 q0,q1,q2,q3;
            const float* f0 = (const float*)&v[0]; const float* f1 = (const float*)&v[1];
            const float* f2 = (const float*)&v[2]; const float* f3 = (const float*)&v[3];
            const float* f4 = (const float*)&v[4]; const float* f5 = (const float*)&v[5];
            const float* f6 = (const float*)&v[6]; const float* f7 = (const float*)&v[7];
            asm("v_cvt_pk_bf16_f32 %0, %1, %2" : "=v"(q0) : "v"(f0[t]), "v"(f1[t]));
            asm("v_cvt_pk_bf16_f32 %0, %1, %2" : "=v"(q1) : "v"(f2[t]), "v"(f3[t]));
            asm("v_cvt_pk_bf16_f32 %0, %1, %2" : "=v"(q2) : "v"(f4[t]), "v"(f5[t]));
            asm("v_cvt_pk_bf16_f32 %0, %1, %2" : "=v"(q3) : "v"(f6[t]), "v"(f7[t]));
            uint4 pv; pv.x=q0; pv.y=q1; pv.z=q2; pv.w=q3;
            *(uint4*)&B1[r*32 + ((chunk ^ (r&7))<<2)] = pv;
        }
    }
    __syncthreads();
    {   // LN stats (right)
        const int px = tid & 255;
        const int r = rmap(px);
        float sum = 0.f, ssq = 0.f;
        #pragma unroll
        for (int c8 = 0; c8 < 8; ++c8) {
            uint4 val = *(const uint4*)&B1[r*32 + ((c8 ^ (r&7))<<2)];
            const u32* wp = (const u32*)&val;
            #pragma unroll
            for (int q = 0; q < 4; ++q) {
                float a = blo(wp[q]), b = bhi(wp[q]);
                sum += a + b; ssq += a*a + b*b;
            }
        }
        float mu = sum * (1.f/64.f);
        float var = ssq * (1.f/64.f) - mu*mu;
        muA[px] = mu;
        rsA[px] = rsqrtf(var + 1e-6f);
    }
    __syncthreads();
    {   // GEMM right: Qr -> Ks;  V (operand-swap, D[m=px][n=ch]) -> Vts (B2)
        float Sv[4], Bv[4];
        #pragma unroll
        for (int r4 = 0; r4 < 4; ++r4) {
            Sv[r4] = SrA[wv*16 + kg*4 + r4];
            Bv[r4] = BrA[wv*16 + kg*4 + r4];
        }
        const int chv = wv*16 + l15;               // this lane's V channel
        const float vbias = BvA[chv];
        u32* KsW = (u32*)Ks;
        u16* Vts = (u16*)B2;
        #pragma unroll
        for (int nt = 0; nt < 16; ++nt) {
            const int px = nt*16 + l15;
            const int r = rmap(px);
            bf16x8 bX[2];
            #pragma unroll
            for (int hf = 0; hf < 2; ++hf)
                bX[hf] = *(const bf16x8*)&B1[r*32 + (((hf*4+kg) ^ (r&7))<<2)];
            f32x4 dq = {0.f,0.f,0.f,0.f};
            f32x4 dv = {0.f,0.f,0.f,0.f};
            #pragma unroll
            for (int hf = 0; hf < 2; ++hf) {
                dq = __builtin_amdgcn_mfma_f32_16x16x32_bf16(aR[hf], bX[hf], dq, 0, 0, 0);
                dv = __builtin_amdgcn_mfma_f32_16x16x32_bf16(bX[hf], aV[hf], dv, 0, 0, 0);
            }
            // Ks write: key = px, channels wv*16+kg*4..+3
            const float mu = muA[px], rs = rsA[px];
            uint2 pq;
            pq.x = pack2(rs*(dq[0] - mu*Sv[0]) + Bv[0], rs*(dq[1] - mu*Sv[1]) + Bv[1]);
            pq.y = pack2(rs*(dq[2] - mu*Sv[2]) + Bv[2], rs*(dq[3] - mu*Sv[3]) + Bv[3]);
            const int ciq = (wv*2 + (kg>>1)) ^ (px & 7);
            *(uint2*)&KsW[px*32 + (ciq<<2) + (kg&1)*2] = pq;
            // Vts write: ch = chv, keys nt*16 + kg*4 .. +3
            uint2 pw;
            pw.x = pack2(dv[0] + vbias, dv[1] + vbias);
            pw.y = pack2(dv[2] + vbias, dv[3] + vbias);
            const int swz = (nt*2 + (kg>>1)) ^ (chv & 7);
            *(uint2*)&Vts[chv*256 + (swz<<3) + (kg&1)*4] = pw;
        }
    }
    __syncthreads();

    // ================= ATTENTION (validated core) =================
    f32x4 oacc[4][4];
    #pragma unroll
    for (int a = 0; a < 4; ++a)
        #pragma unroll
        for (int b = 0; b < 4; ++b)
            oacc[a][b] = (f32x4){0.f,0.f,0.f,0.f};
    float lsum[4] = {0.f,0.f,0.f,0.f};
    u32* Pw = &B1[wv*1024];
    const u16* Vts = (const u16*)B2;
    const int q0 = wv*64;

    for (int kb = 0; kb < 8; ++kb) {
        f32x4 st[2][4];
        #pragma unroll
        for (int mt = 0; mt < 2; ++mt)
            #pragma unroll
            for (int nt = 0; nt < 4; ++nt)
                st[mt][nt] = (f32x4){0.f,0.f,0.f,0.f};
        #pragma unroll
        for (int ci = 0; ci < 2; ++ci) {
            bf16x8 a0 = *(const bf16x8*)&Ks[(kb*32 +      l15)*8 + ((ci*4 + kg) ^ (l15 & 7))];
            bf16x8 a1 = *(const bf16x8*)&Ks[(kb*32 + 16 + l15)*8 + ((ci*4 + kg) ^ (l15 & 7))];
            #pragma unroll
            for (int nt = 0; nt < 4; ++nt) {
                st[0][nt] = __builtin_amdgcn_mfma_f32_16x16x32_bf16(a0, qf[nt][ci], st[0][nt], 0, 0, 0);
                st[1][nt] = __builtin_amdgcn_mfma_f32_16x16x32_bf16(a1, qf[nt][ci], st[1][nt], 0, 0, 0);
            }
        }
        #pragma unroll
        for (int nt = 0; nt < 4; ++nt) {
            const int q = nt*16 + l15;
            #pragma unroll
            for (int mt = 0; mt < 2; ++mt) {
                float p0 = __expf(st[mt][nt][0]*0.125f);
                float p1 = __expf(st[mt][nt][1]*0.125f);
                float p2 = __expf(st[mt][nt][2]*0.125f);
                float p3 = __expf(st[mt][nt][3]*0.125f);
                lsum[nt] += (p0+p1)+(p2+p3);
                u32 pr0, pr1;
                asm("v_cvt_pk_bf16_f32 %0, %1, %2" : "=v"(pr0) : "v"(p0), "v"(p1));
                asm("v_cvt_pk_bf16_f32 %0, %1, %2" : "=v"(pr1) : "v"(p2), "v"(p3));
                const int c16 = (2*mt + (kg >> 1)) ^ (q & 3);
                uint2 pv; pv.x = pr0; pv.y = pr1;
                *(uint2*)&Pw[q*16 + c16*4 + (kg & 1)*2] = pv;
            }
        }
        asm volatile("s_waitcnt lgkmcnt(0)" ::: "memory");
        bf16x8 vb[4];
        #pragma unroll
        for (int nc = 0; nc < 4; ++nc)
            vb[nc] = *(const bf16x8*)&Vts[(nc*16 + l15)*256 + ((kb*4 + kg) ^ (l15 & 7))*8];
        #pragma unroll
        for (int qt = 0; qt < 4; ++qt) {
            const int q = qt*16 + l15;
            bf16x8 pa = *(const bf16x8*)&Pw[q*16 + (kg ^ (q & 3))*4];
            #pragma unroll
            for (int nc = 0; nc < 4; ++nc)
                oacc[qt][nc] = __builtin_amdgcn_mfma_f32_16x16x32_bf16(pa, vb[nc], oacc[qt][nc], 0, 0, 0);
        }
    }

    #pragma unroll
    for (int nt = 0; nt < 4; ++nt) {
        float s = lsum[nt];
        s += __shfl_xor(s, 16, 64);
        s += __shfl_xor(s, 32, 64);
        lsum[nt] = s;
    }
    float linv[4][4];
    #pragma unroll
    for (int qt = 0; qt < 4; ++qt)
        #pragma unroll
        for (int r = 0; r < 4; ++r)
            linv[qt][r] = 1.0f / __shfl(lsum[qt], kg*4 + r, 64);

    float* PwF = (float*)Pw;
    const size_t obase = (size_t)n*CHW_ + (size_t)h*W_ + q0;
    #pragma unroll
    for (int nc = 0; nc < 4; ++nc) {
        asm volatile("s_waitcnt lgkmcnt(0)" ::: "memory");
        #pragma unroll
        for (int qt = 0; qt < 4; ++qt) {
            f32x4 vals;
            vals[0] = oacc[qt][nc][0]*linv[qt][0];
            vals[1] = oacc[qt][nc][1]*linv[qt][1];
            vals[2] = oacc[qt][nc][2]*linv[qt][2];
            vals[3] = oacc[qt][nc][3]*linv[qt][3];
            *(f32x4*)&PwF[l15*64 + ((qt*4 + kg) ^ l15)*4] = vals;
        }
        asm volatile("s_waitcnt lgkmcnt(0)" ::: "memory");
        #pragma unroll
        for (int chl = 0; chl < 16; ++chl) {
            const int ch = nc*16 + chl;
            float v = PwF[chl*64 + ((lane >> 2) ^ chl)*4 + (lane & 3)];
            size_t gidx = obase + (size_t)ch*HW_ + lane;
            float prev = out[gidx];
            out[gidx] = xl[gidx] + beta[ch]*v + prev;
        }
    }
}

// ---------------------------------------------------------------------------
// K3: T_t[n][h][w][c] = highpass(x_r), bf16 (unchanged, validated).
// ---------------------------------------------------------------------------
__global__ __launch_bounds__(256) void k_hipass(
    const float* __restrict__ xr, u16* __restrict__ Tt)
{
    __shared__ u16 Ts[64*256];             // 32 KB
    const int bid = blockIdx.x;
    const int blk = (bid & 7)*128 + (bid >> 3);   // XCD chunk: 128 rows/XCD
    const int n = blk >> 7, h = blk & 127;
    const int tid = threadIdx.x;
    const int lane = tid & 63, wv = tid >> 6;
    const float* rowp = xr + (size_t)n*CHW_ + (size_t)h*W_ + lane*4;

    #pragma unroll
    for (int ci = 0; ci < 16; ++ci) {
        const int c = wv*16 + ci;
        const float* pc = rowp + (size_t)c*HW_;
        float ctr0=0.f, ctr1=0.f, ctr2=0.f, ctr3=0.f;
        float s0=0.f, s1=0.f, s2=0.f, s3=0.f;
        #pragma unroll
        for (int dy = -1; dy <= 1; ++dy) {
            const int hh = h + dy;
            float4 v = {0.f,0.f,0.f,0.f};
            if (hh >= 0 && hh < 128) v = *(const float4*)(pc + dy*W_);
            float lft = __shfl_up(v.w, 1);
            float rgt = __shfl_down(v.x, 1);
            if (lane == 0)  lft = 0.f;
            if (lane == 63) rgt = 0.f;
            s0 += lft + v.x + v.y;
            s1 += v.x + v.y + v.z;
            s2 += v.y + v.z + v.w;
            s3 += v.z + v.w + rgt;
            if (dy == 0) { ctr0=v.x; ctr1=v.y; ctr2=v.z; ctr3=v.w; }
        }
        uint2 pv;
        pv.x = pack2(ctr0 - s0*(1.f/9.f), ctr1 - s1*(1.f/9.f));
        pv.y = pack2(ctr2 - s2*(1.f/9.f), ctr3 - s3*(1.f/9.f));
        const int swz = (c >> 3) << 3;                 // chunk<<3
        *(uint2*)&Ts[c*256 + ((lane*4) ^ swz)] = pv;
    }
    __syncthreads();
    uint4* gout = (uint4*)(Tt + (size_t)blk*256*64);
    #pragma unroll
    for (int iter = 0; iter < 8; ++iter) {
        const int lin = iter*256 + tid;
        const int px = lin >> 3, chunk = lin & 7;
        const int pxs = px ^ (chunk << 3);
        u32 w4[4];
        #pragma unroll
        for (int tp = 0; tp < 4; ++tp) {
            const int c0 = chunk*8 + tp*2;
            u16 a = Ts[(c0    )*256 + pxs];
            u16 b = Ts[(c0 + 1)*256 + pxs];
            w4[tp] = (u32)a | ((u32)b << 16);
        }
        uint4 v; v.x=w4[0]; v.y=w4[1]; v.z=w4[2]; v.w=w4[3];
        gout[lin] = v;
    }
}

// ---------------------------------------------------------------------------
// K4: conv3x3 as MFMA GEMM (unchanged, validated).
// ---------------------------------------------------------------------------
__device__ __forceinline__ void conv_tile(
    const uint4* __restrict__ buf, const bf16x8* A,
    const float* gv, const float* bv,
    int n, int h, int w0, int mt, int l15, int kg,
    float* __restrict__ out)
{
    f32x4 acc[4] = {{0,0,0,0},{0,0,0,0},{0,0,0,0},{0,0,0,0}};
    #pragma unroll
    for (int s = 0; s < 18; ++s) {
        const int q  = s >> 1;
        const int dy = q / 3, dx = q % 3;
        const int c0 = (s & 1)*4 + kg;
        #pragma unroll
        for (int nt = 0; nt < 4; ++nt) {
            const int wt = nt*16 + l15 + dx;
            bf16x8 b = *(const bf16x8*)&buf[(dy*66 + wt)*8 + (c0 ^ (wt & 7))];
            acc[nt] = __builtin_amdgcn_mfma_f32_16x16x32_bf16(A[s], b, acc[nt], 0, 0, 0);
        }
    }
    #pragma unroll
    for (int nt = 0; nt < 4; ++nt) {
        const int px = w0 + nt*16 + l15;
        #pragma unroll
        for (int r = 0; r < 4; ++r) {
            const int oo = mt*16 + kg*4 + r;
            size_t idx = (size_t)(n*64 + oo)*HW_ + (size_t)h*W_ + px;
            out[idx] = gv[r]*(acc[nt][r] + bv[r]);
        }
    }
}

__global__ __launch_bounds__(256) void k_conv(
    const u16* __restrict__ Tt, const float* __restrict__ Whf,
    const float* __restrict__ bhf, const float* __restrict__ gam,
    float* __restrict__ out)
{
    __shared__ uint4 Xs[2][1584];          // 2 x 25344 B double buffer
    const int tid  = threadIdx.x;
    const int lane = tid & 63;
    const int mt   = tid >> 6;
    const int l15  = lane & 15;
    const int kg   = lane >> 4;
    const int bid  = blockIdx.x;
    const int blk2 = (bid & 7)*256 + (bid >> 3);   // XCD chunk swizzle (2048 wgs)
    const int row  = blk2 >> 1, half = blk2 & 1;
    const int n = row >> 7, h = row & 127;
    const int w00 = half*128;
    const int w01 = w00 + 64;

    const int oa = mt*16 + l15;
    bf16x8 A[18];
    #pragma unroll
    for (int s = 0; s < 18; ++s) {
        const int q  = s >> 1;
        const int ib = (s & 1)*32 + kg*8;
        bf16x8 a;
        #pragma unroll
        for (int j = 0; j < 8; ++j) {
            float wv = Whf[(size_t)(oa*64 + ib + j)*9 + q];
            a[j] = (short)f2bf(wv);
        }
        A[s] = a;
    }
    float gv[4], bv[4];
    #pragma unroll
    for (int r = 0; r < 4; ++r) {
        int oo = mt*16 + kg*4 + r;
        gv[r] = gam[oo];
        bv[r] = bhf[oo];
    }

    for (int it = tid; it < 1584; it += 256) {
        int dy    = it / 528;
        int rem   = it - dy*528;
        int wt    = rem >> 3;
        int chunk = rem & 7;
        int hh = h + dy - 1;
        int wg = w00 + wt - 1;
        uint4 v = {0,0,0,0};
        if (hh >= 0 && hh < 128 && wg >= 0 && wg < 256)
            v = *(const uint4*)(Tt + (((size_t)(n*128 + hh)*256 + wg)*64 + chunk*8));
        Xs[0][(dy*66 + wt)*8 + (chunk ^ (wt & 7))] = v;
    }
    __syncthreads();

    uint4 rr[7];
    #pragma unroll
    for (int k = 0; k < 7; ++k) {
        const int it = k*256 + tid;
        if (it < 1584) {
            int dy    = it / 528;
            int rem   = it - dy*528;
            int wt    = rem >> 3;
            int chunk = rem & 7;
            int hh = h + dy - 1;
            int wg = w01 + wt - 1;
            uint4 v = {0,0,0,0};
            if (hh >= 0 && hh < 128 && wg >= 0 && wg < 256)
                v = *(const uint4*)(Tt + (((size_t)(n*128 + hh)*256 + wg)*64 + chunk*8));
            rr[k] = v;
        }
    }

    conv_tile(&Xs[0][0], A, gv, bv, n, h, w00, mt, l15, kg, out);

    #pragma unroll
    for (int k = 0; k < 7; ++k) {
        const int it = k*256 + tid;
        if (it < 1584) {
            int dy    = it / 528;
            int rem   = it - dy*528;
            int wt    = rem >> 3;
            int chunk = rem & 7;
            Xs[1][(dy*66 + wt)*8 + (chunk ^ (wt & 7))] = rr[k];
        }
    }
    __syncthreads();
    conv_tile(&Xs[1][0], A, gv, bv, n, h, w01, mt, l15, kg, out);
}

extern "C" void kernel_launch(void* const* d_in, const int* in_sizes, int n_in,
                              void* d_out, int out_size, void* d_ws, size_t ws_size,
                              hipStream_t stream)
{
    const float* xl   = (const float*)d_in[0];
    const float* xr   = (const float*)d_in[1];
    const float* nlw  = (const float*)d_in[2];
    const float* nlb  = (const float*)d_in[3];
    const float* nrw  = (const float*)d_in[4];
    const float* nrb  = (const float*)d_in[5];
    const float* Wql  = (const float*)d_in[6];
    const float* bql  = (const float*)d_in[7];
    const float* Wqr  = (const float*)d_in[8];
    const float* bqr  = (const float*)d_in[9];
    const float* Wvr  = (const float*)d_in[10];
    const float* bvr  = (const float*)d_in[11];
    const float* beta = (const float*)d_in[12];
    const float* gam  = (const float*)d_in[13];
    const float* Whf  = (const float*)d_in[14];
    const float* bhf  = (const float*)d_in[15];
    float* out = (float*)d_out;

    u16* Tt = (u16*)d_ws;    // 33 MB; Q/K/V no longer touch HBM

    k_hipass<<<1024, 256, 0, stream>>>(xr, Tt);
    k_conv<<<2048, 256, 0, stream>>>(Tt, Whf, bhf, gam, out);
    k_fused<<<1024, 256, 0, stream>>>(xl, xr, nlw, nlb, nrw, nrb,
                                      Wql, bql, Wqr, bqr, Wvr, bvr,
                                      beta, out);
}

// Round 11
// 176.545 us; speedup vs baseline: 8.7704x; 1.1005x over previous
//
#include <hip/hip_runtime.h>
#include <hip/hip_bf16.h>

#define N_ 8
#define C_ 64
#define H_ 128
#define W_ 256
#define HW_ (H_*W_)        // 32768
#define CHW_ (C_*H_*W_)    // 2097152

typedef unsigned int u32;
typedef unsigned short u16;
typedef float f32x4 __attribute__((ext_vector_type(4)));
typedef short bf16x8 __attribute__((ext_vector_type(8)));

__device__ __forceinline__ float blo(u32 u) { return __uint_as_float(u << 16); }
__device__ __forceinline__ float bhi(u32 u) { return __uint_as_float(u & 0xffff0000u); }
__device__ __forceinline__ u16 f2bf(float f) {
    u32 u = __float_as_uint(f);
    u32 lsb = (u >> 16) & 1u;
    u += 0x7fffu + lsb;
    return (u16)(u >> 16);
}
__device__ __forceinline__ u32 pack2(float a, float b) {
    return (u32)f2bf(a) | ((u32)f2bf(b) << 16);
}
__device__ __forceinline__ int rmap(int px) {
    return (px & 0xF8) | ((px + (px >> 3)) & 7);
}

// ---------------------------------------------------------------------------
// K_FUSED (512 threads / 8 waves): LN + projections + cross-attention per
// scanline.  Wave (mw=wv&3, nh=wv>>2) does GEMM m-tile mw over n-half nh;
// attention wave owns 32 queries.  LDS layouts identical to validated r10.
// ---------------------------------------------------------------------------
__global__ __launch_bounds__(512) void k_fused(
    const float* __restrict__ xl, const float* __restrict__ xr,
    const float* __restrict__ nlw, const float* __restrict__ nlb,
    const float* __restrict__ nrw, const float* __restrict__ nrb,
    const float* __restrict__ Wql, const float* __restrict__ bql,
    const float* __restrict__ Wqr, const float* __restrict__ bqr,
    const float* __restrict__ Wvr, const float* __restrict__ bvr,
    const float* __restrict__ beta, float* __restrict__ out)
{
    __shared__ u32 B1[8192];           // 32 KB: X tile; later P scratch (16KB)
    __shared__ u32 B2[8192];           // 32 KB: Q_l [row][ch]; later Vts
    __shared__ uint4 Ks[2048];         // 32 KB: Q_r [key][chunk ^ (key&7)]
    __shared__ float muA[256], rsA[256];
    __shared__ float SlA[64], BlA[64], SrA[64], BrA[64], BvA[64];
    const int tid  = threadIdx.x;
    const int lane = tid & 63, wv = tid >> 6;
    const int l15  = lane & 15, kg = lane >> 4;
    const int mw   = wv & 3;           // GEMM m-tile
    const int nh   = wv >> 2;          // GEMM n-half (0/1)
    const int blk  = blockIdx.x;       // n*128 + h
    const int n = blk >> 7, h = blk & 127;
    const size_t gbase = (size_t)n*CHW_ + (size_t)h*W_;

    if (tid < 64) {
        const int o = tid;
        float sl = 0.f, bl = bql[o], sr = 0.f, br = bqr[o];
        for (int c = 0; c < 64; ++c) {
            float wl = Wql[o*64+c], wr = Wqr[o*64+c];
            sl += wl * nlw[c];
            bl += wl * nlb[c];
            sr += wr * nrw[c];
            br += wr * nrb[c];
        }
        SlA[o] = sl; BlA[o] = bl; SrA[o] = sr; BrA[o] = br; BvA[o] = bvr[o];
    }

    const int oA = mw*16 + l15;
    bf16x8 aL[2], aR[2], aV[2];
    #pragma unroll
    for (int hf = 0; hf < 2; ++hf) {
        bf16x8 tl, tr, tv;
        #pragma unroll
        for (int j = 0; j < 8; ++j) {
            const int c = hf*32 + kg*8 + j;
            tl[j] = (short)f2bf(Wql[oA*64+c] * nlw[c]);
            tr[j] = (short)f2bf(Wqr[oA*64+c] * nrw[c]);
            tv[j] = (short)f2bf(Wvr[oA*64+c]);
        }
        aL[hf] = tl; aR[hf] = tr; aV[hf] = tv;
    }

    // ================= LEFT: stage xl (one 512-thread pass) =================
    {
        const int chunk = tid >> 6;
        const int j = tid & 63;
        const int c0 = chunk*8;
        float4 v[8];
        #pragma unroll
        for (int e = 0; e < 8; ++e)
            v[e] = *(const float4*)(xl + gbase + (size_t)(c0+e)*HW_ + j*4);
        #pragma unroll
        for (int t = 0; t < 4; ++t) {
            const int px = j*4 + t;
            const int r = rmap(px);
            u32 q0,q1,q2,q3;
            const float* f0 = (const float*)&v[0]; const float* f1 = (const float*)&v[1];
            const float* f2 = (const float*)&v[2]; const float* f3 = (const float*)&v[3];
            const float* f4 = (const float*)&v[4]; const float* f5 = (const float*)&v[5];
            const float* f6 = (const float*)&v[6]; const float* f7 = (const float*)&v[7];
            asm("v_cvt_pk_bf16_f32 %0, %1, %2" : "=v"(q0) : "v"(f0[t]), "v"(f1[t]));
            asm("v_cvt_pk_bf16_f32 %0, %1, %2" : "=v"(q1) : "v"(f2[t]), "v"(f3[t]));
            asm("v_cvt_pk_bf16_f32 %0, %1, %2" : "=v"(q2) : "v"(f4[t]), "v"(f5[t]));
            asm("v_cvt_pk_bf16_f32 %0, %1, %2" : "=v"(q3) : "v"(f6[t]), "v"(f7[t]));
            uint4 pv; pv.x=q0; pv.y=q1; pv.z=q2; pv.w=q3;
            *(uint4*)&B1[r*32 + ((chunk ^ (r&7))<<2)] = pv;
        }
    }
    __syncthreads();
    if (tid < 256) {   // LN stats (left)
        const int px = tid;
        const int r = rmap(px);
        float sum = 0.f, ssq = 0.f;
        #pragma unroll
        for (int c8 = 0; c8 < 8; ++c8) {
            uint4 val = *(const uint4*)&B1[r*32 + ((c8 ^ (r&7))<<2)];
            const u32* wp = (const u32*)&val;
            #pragma unroll
            for (int q = 0; q < 4; ++q) {
                float a = blo(wp[q]), b = bhi(wp[q]);
                sum += a + b; ssq += a*a + b*b;
            }
        }
        float mu = sum * (1.f/64.f);
        float var = ssq * (1.f/64.f) - mu*mu;
        muA[px] = mu;
        rsA[px] = rsqrtf(var + 1e-6f);
    }
    __syncthreads();
    {   // GEMM left -> Q_l into B2 [row][ch] swizzled; 8 nt per wave
        float Sv[4], Bv[4];
        #pragma unroll
        for (int r4 = 0; r4 < 4; ++r4) {
            Sv[r4] = SlA[mw*16 + kg*4 + r4];
            Bv[r4] = BlA[mw*16 + kg*4 + r4];
        }
        #pragma unroll
        for (int nt2 = 0; nt2 < 8; ++nt2) {
            const int nt = nh*8 + nt2;
            const int px = nt*16 + l15;
            const int r = rmap(px);
            f32x4 d = {0.f,0.f,0.f,0.f};
            #pragma unroll
            for (int hf = 0; hf < 2; ++hf) {
                bf16x8 b = *(const bf16x8*)&B1[r*32 + (((hf*4+kg) ^ (r&7))<<2)];
                d = __builtin_amdgcn_mfma_f32_16x16x32_bf16(aL[hf], b, d, 0, 0, 0);
            }
            const float mu = muA[px], rs = rsA[px];
            uint2 pv;
            pv.x = pack2(rs*(d[0] - mu*Sv[0]) + Bv[0], rs*(d[1] - mu*Sv[1]) + Bv[1]);
            pv.y = pack2(rs*(d[2] - mu*Sv[2]) + Bv[2], rs*(d[3] - mu*Sv[3]) + Bv[3]);
            const int ci = (mw*2 + (kg>>1)) ^ (px & 7);
            *(uint2*)&B2[px*32 + (ci<<2) + (kg&1)*2] = pv;
        }
    }
    __syncthreads();

    // ---- this wave's Q_l fragments (32 queries), stage xr into B1 ----
    bf16x8 qf[2][2];
    #pragma unroll
    for (int ntq = 0; ntq < 2; ++ntq)
        #pragma unroll
        for (int ci = 0; ci < 2; ++ci) {
            const int q = wv*32 + ntq*16 + l15;
            qf[ntq][ci] = *(const bf16x8*)&B2[q*32 + (((ci*4+kg) ^ (q&7))<<2)];
        }
    {
        const int chunk = tid >> 6;
        const int j = tid & 63;
        const int c0 = chunk*8;
        float4 v[8];
        #pragma unroll
        for (int e = 0; e < 8; ++e)
            v[e] = *(const float4*)(xr + gbase + (size_t)(c0+e)*HW_ + j*4);
        #pragma unroll
        for (int t = 0; t < 4; ++t) {
            const int px = j*4 + t;
            const int r = rmap(px);
            u32 q0,q1,q2,q3;
            const float* f0 = (const float*)&v[0]; const float* f1 = (const float*)&v[1];
            const float* f2 = (const float*)&v[2]; const float* f3 = (const float*)&v[3];
            const float* f4 = (const float*)&v[4]; const float* f5 = (const float*)&v[5];
            const float* f6 = (const float*)&v[6]; const float* f7 = (const float*)&v[7];
            asm("v_cvt_pk_bf16_f32 %0, %1, %2" : "=v"(q0) : "v"(f0[t]), "v"(f1[t]));
            asm("v_cvt_pk_bf16_f32 %0, %1, %2" : "=v"(q1) : "v"(f2[t]), "v"(f3[t]));
            asm("v_cvt_pk_bf16_f32 %0, %1, %2" : "=v"(q2) : "v"(f4[t]), "v"(f5[t]));
            asm("v_cvt_pk_bf16_f32 %0, %1, %2" : "=v"(q3) : "v"(f6[t]), "v"(f7[t]));
            uint4 pv; pv.x=q0; pv.y=q1; pv.z=q2; pv.w=q3;
            *(uint4*)&B1[r*32 + ((chunk ^ (r&7))<<2)] = pv;
        }
    }
    __syncthreads();
    if (tid < 256) {   // LN stats (right)
        const int px = tid;
        const int r = rmap(px);
        float sum = 0.f, ssq = 0.f;
        #pragma unroll
        for (int c8 = 0; c8 < 8; ++c8) {
            uint4 val = *(const uint4*)&B1[r*32 + ((c8 ^ (r&7))<<2)];
            const u32* wp = (const u32*)&val;
            #pragma unroll
            for (int q = 0; q < 4; ++q) {
                float a = blo(wp[q]), b = bhi(wp[q]);
                sum += a + b; ssq += a*a + b*b;
            }
        }
        float mu = sum * (1.f/64.f);
        float var = ssq * (1.f/64.f) - mu*mu;
        muA[px] = mu;
        rsA[px] = rsqrtf(var + 1e-6f);
    }
    __syncthreads();
    {   // GEMM right: Qr -> Ks; V (operand-swap) -> Vts (B2); 8 nt per wave
        float Sv[4], Bv[4];
        #pragma unroll
        for (int r4 = 0; r4 < 4; ++r4) {
            Sv[r4] = SrA[mw*16 + kg*4 + r4];
            Bv[r4] = BrA[mw*16 + kg*4 + r4];
        }
        const int chv = mw*16 + l15;               // this lane's V channel
        const float vbias = BvA[chv];
        u32* KsW = (u32*)Ks;
        u16* Vts = (u16*)B2;
        #pragma unroll
        for (int nt2 = 0; nt2 < 8; ++nt2) {
            const int nt = nh*8 + nt2;
            const int px = nt*16 + l15;
            const int r = rmap(px);
            bf16x8 bX[2];
            #pragma unroll
            for (int hf = 0; hf < 2; ++hf)
                bX[hf] = *(const bf16x8*)&B1[r*32 + (((hf*4+kg) ^ (r&7))<<2)];
            f32x4 dq = {0.f,0.f,0.f,0.f};
            f32x4 dv = {0.f,0.f,0.f,0.f};
            #pragma unroll
            for (int hf = 0; hf < 2; ++hf) {
                dq = __builtin_amdgcn_mfma_f32_16x16x32_bf16(aR[hf], bX[hf], dq, 0, 0, 0);
                dv = __builtin_amdgcn_mfma_f32_16x16x32_bf16(bX[hf], aV[hf], dv, 0, 0, 0);
            }
            const float mu = muA[px], rs = rsA[px];
            uint2 pq;
            pq.x = pack2(rs*(dq[0] - mu*Sv[0]) + Bv[0], rs*(dq[1] - mu*Sv[1]) + Bv[1]);
            pq.y = pack2(rs*(dq[2] - mu*Sv[2]) + Bv[2], rs*(dq[3] - mu*Sv[3]) + Bv[3]);
            const int ciq = (mw*2 + (kg>>1)) ^ (px & 7);
            *(uint2*)&KsW[px*32 + (ciq<<2) + (kg&1)*2] = pq;
            uint2 pw;
            pw.x = pack2(dv[0] + vbias, dv[1] + vbias);
            pw.y = pack2(dv[2] + vbias, dv[3] + vbias);
            const int swz = (nt*2 + (kg>>1)) ^ (chv & 7);
            *(uint2*)&Vts[chv*256 + (swz<<3) + (kg&1)*4] = pw;
        }
    }
    __syncthreads();

    // ================= ATTENTION: wave owns 32 queries =================
    f32x4 oacc[2][4];
    #pragma unroll
    for (int a = 0; a < 2; ++a)
        #pragma unroll
        for (int b = 0; b < 4; ++b)
            oacc[a][b] = (f32x4){0.f,0.f,0.f,0.f};
    float lsum[2] = {0.f,0.f};
    u32* Pw = &B1[wv*512];             // 2 KB per wave
    const u16* Vts = (const u16*)B2;

    for (int kb = 0; kb < 8; ++kb) {
        f32x4 st[2][2];                 // [mt][ntq]
        #pragma unroll
        for (int mt = 0; mt < 2; ++mt)
            #pragma unroll
            for (int nt = 0; nt < 2; ++nt)
                st[mt][nt] = (f32x4){0.f,0.f,0.f,0.f};
        #pragma unroll
        for (int ci = 0; ci < 2; ++ci) {
            bf16x8 a0 = *(const bf16x8*)&Ks[(kb*32 +      l15)*8 + ((ci*4 + kg) ^ (l15 & 7))];
            bf16x8 a1 = *(const bf16x8*)&Ks[(kb*32 + 16 + l15)*8 + ((ci*4 + kg) ^ (l15 & 7))];
            #pragma unroll
            for (int nt = 0; nt < 2; ++nt) {
                st[0][nt] = __builtin_amdgcn_mfma_f32_16x16x32_bf16(a0, qf[nt][ci], st[0][nt], 0, 0, 0);
                st[1][nt] = __builtin_amdgcn_mfma_f32_16x16x32_bf16(a1, qf[nt][ci], st[1][nt], 0, 0, 0);
            }
        }
        #pragma unroll
        for (int nt = 0; nt < 2; ++nt) {
            const int ql = nt*16 + l15;
            #pragma unroll
            for (int mt = 0; mt < 2; ++mt) {
                float p0 = __expf(st[mt][nt][0]*0.125f);
                float p1 = __expf(st[mt][nt][1]*0.125f);
                float p2 = __expf(st[mt][nt][2]*0.125f);
                float p3 = __expf(st[mt][nt][3]*0.125f);
                lsum[nt] += (p0+p1)+(p2+p3);
                u32 pr0, pr1;
                asm("v_cvt_pk_bf16_f32 %0, %1, %2" : "=v"(pr0) : "v"(p0), "v"(p1));
                asm("v_cvt_pk_bf16_f32 %0, %1, %2" : "=v"(pr1) : "v"(p2), "v"(p3));
                const int c16 = (2*mt + (kg >> 1)) ^ (ql & 3);
                uint2 pv; pv.x = pr0; pv.y = pr1;
                *(uint2*)&Pw[ql*16 + c16*4 + (kg & 1)*2] = pv;
            }
        }
        asm volatile("s_waitcnt lgkmcnt(0)" ::: "memory");
        bf16x8 vb[4];
        #pragma unroll
        for (int nc = 0; nc < 4; ++nc)
            vb[nc] = *(const bf16x8*)&Vts[(nc*16 + l15)*256 + ((kb*4 + kg) ^ (l15 & 7))*8];
        #pragma unroll
        for (int qt = 0; qt < 2; ++qt) {
            const int ql = qt*16 + l15;
            bf16x8 pa = *(const bf16x8*)&Pw[ql*16 + (kg ^ (ql & 3))*4];
            #pragma unroll
            for (int nc = 0; nc < 4; ++nc)
                oacc[qt][nc] = __builtin_amdgcn_mfma_f32_16x16x32_bf16(pa, vb[nc], oacc[qt][nc], 0, 0, 0);
        }
    }

    #pragma unroll
    for (int nt = 0; nt < 2; ++nt) {
        float s = lsum[nt];
        s += __shfl_xor(s, 16, 64);
        s += __shfl_xor(s, 32, 64);
        lsum[nt] = s;
    }
    float linv[2][4];
    #pragma unroll
    for (int qt = 0; qt < 2; ++qt)
        #pragma unroll
        for (int r = 0; r < 4; ++r)
            linv[qt][r] = 1.0f / __shfl(lsum[qt], kg*4 + r, 64);

    // ---- epilogue: transpose 32q x 64ch through per-wave 2KB scratch ----
    float* PwF = (float*)Pw;
    const size_t obase = gbase + wv*32;
    #pragma unroll
    for (int nc = 0; nc < 4; ++nc) {
        asm volatile("s_waitcnt lgkmcnt(0)" ::: "memory");
        #pragma unroll
        for (int qt = 0; qt < 2; ++qt) {
            f32x4 vals;
            vals[0] = oacc[qt][nc][0]*linv[qt][0];
            vals[1] = oacc[qt][nc][1]*linv[qt][1];
            vals[2] = oacc[qt][nc][2]*linv[qt][2];
            vals[3] = oacc[qt][nc][3]*linv[qt][3];
            *(f32x4*)&PwF[l15*32 + (((qt*4 + kg) ^ (l15 & 7))<<2)] = vals;
        }
        asm volatile("s_waitcnt lgkmcnt(0)" ::: "memory");
        #pragma unroll
        for (int it = 0; it < 8; ++it) {
            const int csub = it*2 + (lane >> 5);
            const int qloc = lane & 31;
            float v = PwF[csub*32 + ((((qloc >> 2)) ^ (csub & 7))<<2) + (qloc & 3)];
            const int ch = nc*16 + csub;
            size_t gidx = obase + (size_t)ch*HW_ + qloc;
            out[gidx] = xl[gidx] + beta[ch]*v + out[gidx];
        }
    }
}

// ---------------------------------------------------------------------------
// K3: T_t[n][h][w][c] = highpass(x_r), bf16 (unchanged, validated).
// ---------------------------------------------------------------------------
__global__ __launch_bounds__(256) void k_hipass(
    const float* __restrict__ xr, u16* __restrict__ Tt)
{
    __shared__ u16 Ts[64*256];             // 32 KB
    const int bid = blockIdx.x;
    const int blk = (bid & 7)*128 + (bid >> 3);   // XCD chunk: 128 rows/XCD
    const int n = blk >> 7, h = blk & 127;
    const int tid = threadIdx.x;
    const int lane = tid & 63, wv = tid >> 6;
    const float* rowp = xr + (size_t)n*CHW_ + (size_t)h*W_ + lane*4;

    #pragma unroll
    for (int ci = 0; ci < 16; ++ci) {
        const int c = wv*16 + ci;
        const float* pc = rowp + (size_t)c*HW_;
        float ctr0=0.f, ctr1=0.f, ctr2=0.f, ctr3=0.f;
        float s0=0.f, s1=0.f, s2=0.f, s3=0.f;
        #pragma unroll
        for (int dy = -1; dy <= 1; ++dy) {
            const int hh = h + dy;
            float4 v = {0.f,0.f,0.f,0.f};
            if (hh >= 0 && hh < 128) v = *(const float4*)(pc + dy*W_);
            float lft = __shfl_up(v.w, 1);
            float rgt = __shfl_down(v.x, 1);
            if (lane == 0)  lft = 0.f;
            if (lane == 63) rgt = 0.f;
            s0 += lft + v.x + v.y;
            s1 += v.x + v.y + v.z;
            s2 += v.y + v.z + v.w;
            s3 += v.z + v.w + rgt;
            if (dy == 0) { ctr0=v.x; ctr1=v.y; ctr2=v.z; ctr3=v.w; }
        }
        uint2 pv;
        pv.x = pack2(ctr0 - s0*(1.f/9.f), ctr1 - s1*(1.f/9.f));
        pv.y = pack2(ctr2 - s2*(1.f/9.f), ctr3 - s3*(1.f/9.f));
        const int swz = (c >> 3) << 3;                 // chunk<<3
        *(uint2*)&Ts[c*256 + ((lane*4) ^ swz)] = pv;
    }
    __syncthreads();
    uint4* gout = (uint4*)(Tt + (size_t)blk*256*64);
    #pragma unroll
    for (int iter = 0; iter < 8; ++iter) {
        const int lin = iter*256 + tid;
        const int px = lin >> 3, chunk = lin & 7;
        const int pxs = px ^ (chunk << 3);
        u32 w4[4];
        #pragma unroll
        for (int tp = 0; tp < 4; ++tp) {
            const int c0 = chunk*8 + tp*2;
            u16 a = Ts[(c0    )*256 + pxs];
            u16 b = Ts[(c0 + 1)*256 + pxs];
            w4[tp] = (u32)a | ((u32)b << 16);
        }
        uint4 v; v.x=w4[0]; v.y=w4[1]; v.z=w4[2]; v.w=w4[3];
        gout[lin] = v;
    }
}

// ---------------------------------------------------------------------------
// K4: conv3x3 as MFMA GEMM (unchanged, validated).
// ---------------------------------------------------------------------------
__device__ __forceinline__ void conv_tile(
    const uint4* __restrict__ buf, const bf16x8* A,
    const float* gv, const float* bv,
    int n, int h, int w0, int mt, int l15, int kg,
    float* __restrict__ out)
{
    f32x4 acc[4] = {{0,0,0,0},{0,0,0,0},{0,0,0,0},{0,0,0,0}};
    #pragma unroll
    for (int s = 0; s < 18; ++s) {
        const int q  = s >> 1;
        const int dy = q / 3, dx = q % 3;
        const int c0 = (s & 1)*4 + kg;
        #pragma unroll
        for (int nt = 0; nt < 4; ++nt) {
            const int wt = nt*16 + l15 + dx;
            bf16x8 b = *(const bf16x8*)&buf[(dy*66 + wt)*8 + (c0 ^ (wt & 7))];
            acc[nt] = __builtin_amdgcn_mfma_f32_16x16x32_bf16(A[s], b, acc[nt], 0, 0, 0);
        }
    }
    #pragma unroll
    for (int nt = 0; nt < 4; ++nt) {
        const int px = w0 + nt*16 + l15;
        #pragma unroll
        for (int r = 0; r < 4; ++r) {
            const int oo = mt*16 + kg*4 + r;
            size_t idx = (size_t)(n*64 + oo)*HW_ + (size_t)h*W_ + px;
            out[idx] = gv[r]*(acc[nt][r] + bv[r]);
        }
    }
}

__global__ __launch_bounds__(256) void k_conv(
    const u16* __restrict__ Tt, const float* __restrict__ Whf,
    const float* __restrict__ bhf, const float* __restrict__ gam,
    float* __restrict__ out)
{
    __shared__ uint4 Xs[2][1584];          // 2 x 25344 B double buffer
    const int tid  = threadIdx.x;
    const int lane = tid & 63;
    const int mt   = tid >> 6;
    const int l15  = lane & 15;
    const int kg   = lane >> 4;
    const int bid  = blockIdx.x;
    const int blk2 = (bid & 7)*256 + (bid >> 3);   // XCD chunk swizzle (2048 wgs)
    const int row  = blk2 >> 1, half = blk2 & 1;
    const int n = row >> 7, h = row & 127;
    const int w00 = half*128;
    const int w01 = w00 + 64;

    const int oa = mt*16 + l15;
    bf16x8 A[18];
    #pragma unroll
    for (int s = 0; s < 18; ++s) {
        const int q  = s >> 1;
        const int ib = (s & 1)*32 + kg*8;
        bf16x8 a;
        #pragma unroll
        for (int j = 0; j < 8; ++j) {
            float wv = Whf[(size_t)(oa*64 + ib + j)*9 + q];
            a[j] = (short)f2bf(wv);
        }
        A[s] = a;
    }
    float gv[4], bv[4];
    #pragma unroll
    for (int r = 0; r < 4; ++r) {
        int oo = mt*16 + kg*4 + r;
        gv[r] = gam[oo];
        bv[r] = bhf[oo];
    }

    for (int it = tid; it < 1584; it += 256) {
        int dy    = it / 528;
        int rem   = it - dy*528;
        int wt    = rem >> 3;
        int chunk = rem & 7;
        int hh = h + dy - 1;
        int wg = w00 + wt - 1;
        uint4 v = {0,0,0,0};
        if (hh >= 0 && hh < 128 && wg >= 0 && wg < 256)
            v = *(const uint4*)(Tt + (((size_t)(n*128 + hh)*256 + wg)*64 + chunk*8));
        Xs[0][(dy*66 + wt)*8 + (chunk ^ (wt & 7))] = v;
    }
    __syncthreads();

    uint4 rr[7];
    #pragma unroll
    for (int k = 0; k < 7; ++k) {
        const int it = k*256 + tid;
        if (it < 1584) {
            int dy    = it / 528;
            int rem   = it - dy*528;
            int wt    = rem >> 3;
            int chunk = rem & 7;
            int hh = h + dy - 1;
            int wg = w01 + wt - 1;
            uint4 v = {0,0,0,0};
            if (hh >= 0 && hh < 128 && wg >= 0 && wg < 256)
                v = *(const uint4*)(Tt + (((size_t)(n*128 + hh)*256 + wg)*64 + chunk*8));
            rr[k] = v;
        }
    }

    conv_tile(&Xs[0][0], A, gv, bv, n, h, w00, mt, l15, kg, out);

    #pragma unroll
    for (int k = 0; k < 7; ++k) {
        const int it = k*256 + tid;
        if (it < 1584) {
            int dy    = it / 528;
            int rem   = it - dy*528;
            int wt    = rem >> 3;
            int chunk = rem & 7;
            Xs[1][(dy*66 + wt)*8 + (chunk ^ (wt & 7))] = rr[k];
        }
    }
    __syncthreads();
    conv_tile(&Xs[1][0], A, gv, bv, n, h, w01, mt, l15, kg, out);
}

extern "C" void kernel_launch(void* const* d_in, const int* in_sizes, int n_in,
                              void* d_out, int out_size, void* d_ws, size_t ws_size,
                              hipStream_t stream)
{
    const float* xl   = (const float*)d_in[0];
    const float* xr   = (const float*)d_in[1];
    const float* nlw  = (const float*)d_in[2];
    const float* nlb  = (const float*)d_in[3];
    const float* nrw  = (const float*)d_in[4];
    const float* nrb  = (const float*)d_in[5];
    const float* Wql  = (const float*)d_in[6];
    const float* bql  = (const float*)d_in[7];
    const float* Wqr  = (const float*)d_in[8];
    const float* bqr  = (const float*)d_in[9];
    const float* Wvr  = (const float*)d_in[10];
    const float* bvr  = (const float*)d_in[11];
    const float* beta = (const float*)d_in[12];
    const float* gam  = (const float*)d_in[13];
    const float* Whf  = (const float*)d_in[14];
    const float* bhf  = (const float*)d_in[15];
    float* out = (float*)d_out;

    u16* Tt = (u16*)d_ws;    // 33 MB; Q/K/V never touch HBM

    k_hipass<<<1024, 256, 0, stream>>>(xr, Tt);
    k_conv<<<2048, 256, 0, stream>>>(Tt, Whf, bhf, gam, out);
    k_fused<<<1024, 512, 0, stream>>>(xl, xr, nlw, nlb, nrw, nrb,
                                      Wql, bql, Wqr, bqr, Wvr, bvr,
                                      beta, out);
}